// Round 3
// baseline (692.001 us; speedup 1.0000x reference)
//
#include <hip/hip_runtime.h>
#include <cstdint>
#include <cmath>

typedef __bf16 bf16;
typedef __attribute__((ext_vector_type(8))) __bf16 bf16x8;
typedef __attribute__((ext_vector_type(4))) __bf16 bf16x4;
typedef __attribute__((ext_vector_type(4))) float f32x4;

constexpr int B_ = 2, T_ = 2048, C_ = 1024, H_ = 16, HD_ = 64;
constexpr int M_ = B_ * T_;   // 4096

// =============  GEMM: C = A @ Bw^T (+bias)(+residual), A bf16 / Bw fp32  =============
// A: M x lda row-major bf16.  Bw: N x K row-major fp32 (cast to bf16 during staging).
// MODE bit0: += R (fp32, stride N)   MODE bit1: += bias (fp32)
// OutT: __bf16 or float
template <int MODE, typename OutT>
__global__ __launch_bounds__(256) void gemm_bt(const bf16* __restrict__ A,
                                               const float* __restrict__ Bw,
                                               OutT* __restrict__ Cmat,
                                               const float* __restrict__ bias,
                                               const float* __restrict__ R,
                                               int M, int N, int K, int lda) {
  __shared__ __align__(16) bf16 Als[128 * 32];
  __shared__ __align__(16) bf16 Bls[128 * 32];
  const int tid  = threadIdx.x;
  const int wave = tid >> 6;
  const int lane = tid & 63;
  const int quad = lane >> 4;
  const int l16  = lane & 15;
  const int bm = blockIdx.x * 128;
  const int bn = blockIdx.y * 128;
  const int wm = (wave & 1) * 64;
  const int wn = (wave >> 1) * 64;
  const int srow   = lane >> 2;  // 0..15
  const int schunk = lane & 3;   // 0..3 (8-element chunks of a 32-element k-row)

  f32x4 acc[4][4];
#pragma unroll
  for (int i = 0; i < 4; i++)
#pragma unroll
    for (int j = 0; j < 4; j++) acc[i][j] = f32x4{0.f, 0.f, 0.f, 0.f};

  const bf16*  Ag = A  + (size_t)(bm + wave * 32 + srow) * lda + schunk * 8;
  const float* Bg = Bw + (size_t)(bn + wave * 32 + srow) * K   + schunk * 8;
  bf16* AlsL = &Als[(wave * 32) * 32 + lane * 8];
  bf16* BlsL = &Bls[(wave * 32) * 32 + lane * 8];

  for (int k0 = 0; k0 < K; k0 += 32) {
    bf16x8 va0 = *(const bf16x8*)(Ag + k0);
    bf16x8 va1 = *(const bf16x8*)(Ag + k0 + (size_t)16 * lda);
    f32x4 f0 = *(const f32x4*)(Bg + k0);
    f32x4 f1 = *(const f32x4*)(Bg + k0 + 4);
    f32x4 f2 = *(const f32x4*)(Bg + k0 + (size_t)16 * K);
    f32x4 f3 = *(const f32x4*)(Bg + k0 + (size_t)16 * K + 4);
    bf16x8 vb0, vb1;
#pragma unroll
    for (int i = 0; i < 4; i++) { vb0[i] = (bf16)f0[i]; vb0[i + 4] = (bf16)f1[i]; }
#pragma unroll
    for (int i = 0; i < 4; i++) { vb1[i] = (bf16)f2[i]; vb1[i + 4] = (bf16)f3[i]; }
    __syncthreads();   // previous iteration's LDS reads complete
    *(bf16x8*)AlsL            = va0;
    *(bf16x8*)(AlsL + 16*32)  = va1;
    *(bf16x8*)BlsL            = vb0;
    *(bf16x8*)(BlsL + 16*32)  = vb1;
    __syncthreads();   // staging visible to all waves

    bf16x8 af[4], bfr[4];
#pragma unroll
    for (int mt = 0; mt < 4; mt++)
      af[mt] = *(const bf16x8*)&Als[(wm + mt * 16 + l16) * 32 + quad * 8];
#pragma unroll
    for (int nt = 0; nt < 4; nt++)
      bfr[nt] = *(const bf16x8*)&Bls[(wn + nt * 16 + l16) * 32 + quad * 8];
#pragma unroll
    for (int mt = 0; mt < 4; mt++)
#pragma unroll
      for (int nt = 0; nt < 4; nt++)
        acc[mt][nt] = __builtin_amdgcn_mfma_f32_16x16x32_bf16(af[mt], bfr[nt], acc[mt][nt], 0, 0, 0);
  }

  // epilogue: D row = wm+mt*16+quad*4+r, col = wn+nt*16+l16
#pragma unroll
  for (int mt = 0; mt < 4; mt++) {
    const int row = bm + wm + mt * 16 + quad * 4;
#pragma unroll
    for (int nt = 0; nt < 4; nt++) {
      const int col = bn + wn + nt * 16 + l16;
      float bval = 0.f;
      if (MODE & 2) bval = bias[col];
#pragma unroll
      for (int r = 0; r < 4; r++) {
        float v = acc[mt][nt][r] + bval;
        if (MODE & 1) v += R[(size_t)(row + r) * N + col];
        Cmat[(size_t)(row + r) * N + col] = (OutT)v;
      }
    }
  }
}

// =====================  RMSNorm: fp32 in -> bf16 out (row = 1024)  =====================
__global__ __launch_bounds__(256) void rmsnorm_kernel(const float* __restrict__ X,
                                                      bf16* __restrict__ O) {
  const int row = blockIdx.x;
  const int tid = threadIdx.x;
  const int wave = tid >> 6;
  f32x4 v = *(const f32x4*)(X + (size_t)row * C_ + tid * 4);
  float s = v[0] * v[0] + v[1] * v[1] + v[2] * v[2] + v[3] * v[3];
#pragma unroll
  for (int off = 32; off >= 1; off >>= 1) s += __shfl_xor(s, off);
  __shared__ float wsum[4];
  __shared__ float scale_sh;
  if ((tid & 63) == 0) wsum[wave] = s;
  __syncthreads();
  if (tid == 0)
    scale_sh = rsqrtf((wsum[0] + wsum[1] + wsum[2] + wsum[3]) * (1.f / (float)C_) + 1e-6f);
  __syncthreads();
  const float sc = scale_sh;
  bf16x4 o;
  o[0] = (bf16)(v[0] * sc); o[1] = (bf16)(v[1] * sc);
  o[2] = (bf16)(v[2] * sc); o[3] = (bf16)(v[3] * sc);
  *(bf16x4*)(O + (size_t)row * C_ + tid * 4) = o;
}

// ==========  Rotary on q,k (bf16, in-place) + q0/k0 = sqrt(kc + |.|^2)  ==========
__global__ __launch_bounds__(256) void rotary_kernel(bf16* __restrict__ qkv,
                                                     const float* __restrict__ kcb,
                                                     float* __restrict__ q0b,
                                                     float* __restrict__ k0b) {
  const int wid  = blockIdx.x * 4 + (threadIdx.x >> 6);  // one wave per (b,t,h)
  const int lane = threadIdx.x & 63;
  const int b = wid >> 15;          // T_*H_ = 32768
  const int rem = wid & 32767;
  const int t = rem >> 4;
  const int h = rem & 15;
  const int i = lane & 31;
  // inv_freq = 10000^(-(2i)/64);  angle = t * inv_freq
  const float invf = expf(-((float)i / 32.f) * 9.210340371976184f);  // ln(10000)
  const float ang = (float)t * invf;
  const float cx = cosf(ang), sx = sinf(ang);
  const float kc = kcb[h];
  bf16* qp = qkv + (size_t)(b * T_ + t) * 3072 + h * 64;

#pragma unroll
  for (int which = 0; which < 2; which++) {
    bf16* p = qp + which * 1024;   // q then k
    float x1 = (float)p[i];
    float x2 = (float)p[i + 32];
    float o = (lane < 32) ? (x1 * cx + x2 * sx) : (x2 * cx - x1 * sx);
    float ss = o * o;
#pragma unroll
    for (int off = 32; off >= 1; off >>= 1) ss += __shfl_xor(ss, off);
    p[lane] = (bf16)o;
    if (lane == 0) {
      float* dst = which == 0 ? q0b : k0b;
      dst[(size_t)(b * H_ + h) * T_ + t] = sqrtf(kc + ss);
    }
  }
}

// =====================  Hyperbolic flash attention  =====================
// grid: (B*H, T/64); block 256 = 4 waves; wave w owns q-rows t0+16w .. +15
__global__ __launch_bounds__(256) void attn_kernel(const bf16* __restrict__ qkv,
                                                   const float* __restrict__ q0b,
                                                   const float* __restrict__ k0b,
                                                   const float* __restrict__ kcb,
                                                   bf16* __restrict__ outp) {
  __shared__ __align__(16) bf16 Kls[32][72];     // K tile [s][d], padded
  __shared__ __align__(16) bf16 Vt[64][40];      // V tile transposed [d][s], padded
  __shared__ __align__(16) bf16 Pls[4][16 * 40]; // per-wave P round-trip, row stride 40
  __shared__ float k0s[32];

  const int tid = threadIdx.x;
  const int wave = tid >> 6, lane = tid & 63;
  const int quad = lane >> 4, l16 = lane & 15;
  const int bh = blockIdx.x;
  const int b = bh >> 4, h = bh & 15;
  const int t0 = blockIdx.y * 64;
  const int tb = t0 + wave * 16;

  const float kc = kcb[h];
  const float inv_kc = 1.f / kc;
  const float sqkc = sqrtf(kc);

  // q A-frags in registers for the whole block: A[m=l16][k=quad*8+j]
  bf16x8 aq0, aq1;
  {
    const bf16* qrow = qkv + (size_t)(b * T_ + tb + l16) * 3072 + h * 64;
    aq0 = *(const bf16x8*)(qrow + quad * 8);
    aq1 = *(const bf16x8*)(qrow + 32 + quad * 8);
  }
  float q0r[4];
#pragma unroll
  for (int r = 0; r < 4; r++)
    q0r[r] = q0b[(size_t)(b * H_ + h) * T_ + tb + quad * 4 + r];

  f32x4 o[4];
#pragma unroll
  for (int dt = 0; dt < 4; dt++) o[dt] = f32x4{0.f, 0.f, 0.f, 0.f};
  float mrow[4], lrow[4];
#pragma unroll
  for (int r = 0; r < 4; r++) { mrow[r] = -1e30f; lrow[r] = 0.f; }

  const int ss = tid >> 3, dg = tid & 7;
  bf16* Pl = Pls[wave];

  for (int s0 = 0; s0 < t0 + 64; s0 += 32) {
    // ---- stage K (row-major) and V (transposed) ----
    const bf16* krow = qkv + (size_t)(b * T_ + s0 + ss) * 3072 + 1024 + h * 64 + dg * 8;
    bf16x8 kv = *(const bf16x8*)krow;
    *(bf16x8*)&Kls[ss][dg * 8] = kv;
    bf16x8 vv = *(const bf16x8*)(krow + 1024);
#pragma unroll
    for (int i2 = 0; i2 < 8; i2++) Vt[dg * 8 + i2][ss] = vv[i2];
    if (tid < 32) k0s[tid] = k0b[(size_t)(b * H_ + h) * T_ + s0 + tid];
    __syncthreads();

    // ---- S = q @ K^T  (two 16-col n-tiles) ----
    f32x4 sc[2];
    sc[0] = f32x4{0.f, 0.f, 0.f, 0.f};
    sc[1] = f32x4{0.f, 0.f, 0.f, 0.f};
#pragma unroll
    for (int nt = 0; nt < 2; nt++) {
      bf16x8 b0 = *(const bf16x8*)&Kls[nt * 16 + l16][quad * 8];
      bf16x8 b1 = *(const bf16x8*)&Kls[nt * 16 + l16][32 + quad * 8];
      sc[nt] = __builtin_amdgcn_mfma_f32_16x16x32_bf16(aq0, b0, sc[nt], 0, 0, 0);
      sc[nt] = __builtin_amdgcn_mfma_f32_16x16x32_bf16(aq1, b1, sc[nt], 0, 0, 0);
    }

    // ---- hyperbolic distance + causal mask + online softmax ----
    float pv[2][4];
    float tmax[4] = {-1e30f, -1e30f, -1e30f, -1e30f};
#pragma unroll
    for (int nt = 0; nt < 2; nt++) {
      const float k0c = k0s[nt * 16 + l16];
      const int s = s0 + nt * 16 + l16;
#pragma unroll
      for (int r = 0; r < 4; r++) {
        const int t = tb + quad * 4 + r;
        float lor = sc[nt][r] - q0r[r] * k0c;
        float ratio = fminf(fmaxf(-lor * inv_kc, 1.f + 1e-6f), 1e18f);
        float dis = sqkc * __logf(ratio + sqrtf(ratio * ratio - 1.f));
        float scv = (s <= t) ? -dis : -1e30f;
        pv[nt][r] = scv;
        tmax[r] = fmaxf(tmax[r], scv);
      }
    }
#pragma unroll
    for (int r = 0; r < 4; r++) {
#pragma unroll
      for (int off = 1; off <= 8; off <<= 1)
        tmax[r] = fmaxf(tmax[r], __shfl_xor(tmax[r], off));
    }
    float alpha[4], rsum[4];
#pragma unroll
    for (int r = 0; r < 4; r++) {
      float mn = fmaxf(mrow[r], tmax[r]);
      alpha[r] = __expf(mrow[r] - mn);   // first tile: exp(-huge)=0
      mrow[r] = mn;
    }
#pragma unroll
    for (int nt = 0; nt < 2; nt++)
#pragma unroll
      for (int r = 0; r < 4; r++) pv[nt][r] = __expf(pv[nt][r] - mrow[r]);
#pragma unroll
    for (int r = 0; r < 4; r++) {
      rsum[r] = pv[0][r] + pv[1][r];
#pragma unroll
      for (int off = 1; off <= 8; off <<= 1) rsum[r] += __shfl_xor(rsum[r], off);
      lrow[r] = lrow[r] * alpha[r] + rsum[r];
    }
#pragma unroll
    for (int dt = 0; dt < 4; dt++)
#pragma unroll
      for (int r = 0; r < 4; r++) o[dt][r] *= alpha[r];

    // ---- P: C-layout -> A-layout via per-wave LDS (barrier for ordering) ----
#pragma unroll
    for (int nt = 0; nt < 2; nt++)
#pragma unroll
      for (int r = 0; r < 4; r++)
        Pl[(quad * 4 + r) * 40 + nt * 16 + l16] = (bf16)pv[nt][r];
    __syncthreads();   // order P-writes before P-reads (uniform trip count)
    bf16x8 ap = *(const bf16x8*)&Pl[l16 * 40 + quad * 8];
#pragma unroll
    for (int dt = 0; dt < 4; dt++) {
      bf16x8 bv = *(const bf16x8*)&Vt[dt * 16 + l16][quad * 8];
      o[dt] = __builtin_amdgcn_mfma_f32_16x16x32_bf16(ap, bv, o[dt], 0, 0, 0);
    }
    __syncthreads();
  }

  // ---- write O / l ----
#pragma unroll
  for (int r = 0; r < 4; r++) {
    const float invl = lrow[r] > 0.f ? 1.f / lrow[r] : 0.f;
    const int t = tb + quad * 4 + r;
#pragma unroll
    for (int dt = 0; dt < 4; dt++) {
      float val = o[dt][r] * invl;
      outp[(size_t)(b * T_ + t) * C_ + h * 64 + dt * 16 + l16] = (bf16)val;
    }
  }
}

// ==============  SwiGLU in-place (bf16): uv[m][0..4096) = u * silu(v)  ==============
__global__ __launch_bounds__(256) void swiglu_kernel(bf16* __restrict__ uv) {
  const size_t gid = (size_t)blockIdx.x * 256 + threadIdx.x;
  const size_t e0 = gid * 4;
  const size_t m = e0 >> 12;      // / 4096
  const size_t j = e0 & 4095;
  bf16* up = uv + m * 8192 + j;
  bf16x4 u4 = *(const bf16x4*)up;
  bf16x4 v4 = *(const bf16x4*)(up + 4096);
  bf16x4 o;
#pragma unroll
  for (int i = 0; i < 4; i++) {
    float uu = (float)u4[i];
    float vvv = (float)v4[i];
    float vc = fminf(fmaxf(vvv, -80.f), 80.f);
    float sig = 1.f / (1.f + __expf(-vc));
    o[i] = (bf16)(uu * vvv * sig);
  }
  *(bf16x4*)up = o;
}

// =====================  host-side launch  =====================
extern "C" void kernel_launch(void* const* d_in, const int* in_sizes, int n_in,
                              void* d_out, int out_size, void* d_ws, size_t ws_size,
                              hipStream_t stream) {
  const float* x      = (const float*)d_in[0];
  const float* w_qkv  = (const float*)d_in[1];
  const float* w_out  = (const float*)d_in[2];
  const float* kcb    = (const float*)d_in[3];
  const float* w_uv   = (const float*)d_in[4];
  const float* b_uv   = (const float*)d_in[5];
  const float* w_mlp  = (const float*)d_in[6];
  const float* b_mlp  = (const float*)d_in[7];
  float* out = (float*)d_out;

  const size_t MB = 1024ull * 1024ull;
  char* w = (char*)d_ws;
  bf16*  hbuf    = (bf16*)(w + 0);          //  8 MB (h, then h2)
  bf16*  qkvbuf  = (bf16*)(w + 8 * MB);     // 24 MB (dead after attn)
  bf16*  attnbuf = (bf16*)(w + 32 * MB);    //  8 MB (dead after step 5)
  bf16*  uvbuf   = (bf16*)(w + 8 * MB);     // 64 MB (over qkv+attn), 8..72
  float* x2buf   = (float*)(w + 72 * MB);   // 16 MB fp32
  float* q0b     = (float*)(w + 88 * MB);              // 256 KB
  float* k0b     = (float*)(w + 88 * MB + 256 * 1024); // 256 KB
  // total: 88.5 MB

  // 1) h = rmsnorm(x)                                  fp32 -> bf16
  rmsnorm_kernel<<<M_, 256, 0, stream>>>(x, hbuf);
  // 2) qkv = h @ w_qkv^T                               bf16 x fp32w -> bf16
  gemm_bt<0, bf16><<<dim3(M_ / 128, 3072 / 128), 256, 0, stream>>>(
      hbuf, w_qkv, qkvbuf, nullptr, nullptr, M_, 3072, 1024, 1024);
  // 3) rotary(q,k) in-place + q0/k0
  rotary_kernel<<<(B_ * T_ * H_) / 4, 256, 0, stream>>>(qkvbuf, kcb, q0b, k0b);
  // 4) hyperbolic flash attention                      -> bf16
  attn_kernel<<<dim3(B_ * H_, T_ / 64), 256, 0, stream>>>(qkvbuf, q0b, k0b, kcb, attnbuf);
  // 5) x2 = x + attn @ w_out^T                         -> fp32
  gemm_bt<1, float><<<dim3(M_ / 128, 1024 / 128), 256, 0, stream>>>(
      attnbuf, w_out, x2buf, nullptr, x, M_, 1024, 1024, 1024);
  // 6) h2 = rmsnorm(x2)                                fp32 -> bf16
  rmsnorm_kernel<<<M_, 256, 0, stream>>>(x2buf, hbuf);
  // 7) uv = h2 @ w_uv^T + b_uv                         -> bf16
  gemm_bt<2, bf16><<<dim3(M_ / 128, 8192 / 128), 256, 0, stream>>>(
      hbuf, w_uv, uvbuf, b_uv, nullptr, M_, 8192, 1024, 1024);
  // 8) g = u * silu(v), in place over u-half (row stride 8192)
  swiglu_kernel<<<(M_ * 4096) / (4 * 256), 256, 0, stream>>>(uvbuf);
  // 9) out = x2 + g @ w_mlp^T + b_mlp                  -> fp32
  gemm_bt<3, float><<<dim3(M_ / 128, 1024 / 128), 256, 0, stream>>>(
      uvbuf, w_mlp, out, b_mlp, x2buf, M_, 1024, 4096, 8192);
}

// Round 5
// 532.724 us; speedup vs baseline: 1.2990x; 1.2990x over previous
//
#include <hip/hip_runtime.h>
#include <cstdint>
#include <cmath>

typedef __bf16 bf16;
typedef __attribute__((ext_vector_type(8))) __bf16 bf16x8;
typedef __attribute__((ext_vector_type(4))) __bf16 bf16x4;
typedef __attribute__((ext_vector_type(4))) float f32x4;

constexpr int B_ = 2, T_ = 2048, C_ = 1024, H_ = 16, HD_ = 64;
constexpr int M_ = B_ * T_;   // 4096

// native 2^x and log2(x) (v_exp_f32 / v_log_f32)
#define EXP2F(x) __builtin_amdgcn_exp2f(x)
#define LOG2F(x) __builtin_amdgcn_logf(x)

// ---- async global->LDS, 16B per lane; LDS dest = wave-uniform base + lane*16 ----
__device__ __forceinline__ void gld16(const void* g, void* l) {
  __builtin_amdgcn_global_load_lds((const __attribute__((address_space(1))) void*)g,
                                   (__attribute__((address_space(3))) void*)l, 16, 0, 0);
}

// =====================  weight cast: fp32 -> bf16, 4 elems/thread  =====================
__global__ __launch_bounds__(256) void cast_kernel(const float* __restrict__ src,
                                                   bf16* __restrict__ dst, int n4) {
  const int gid = blockIdx.x * 256 + threadIdx.x;
  if (gid >= n4) return;
  f32x4 v = *(const f32x4*)(src + (size_t)gid * 4);
  bf16x4 o;
  o[0] = (bf16)v[0]; o[1] = (bf16)v[1]; o[2] = (bf16)v[2]; o[3] = (bf16)v[3];
  *(bf16x4*)(dst + (size_t)gid * 4) = o;
}

// =============  GEMM: C = A @ Bw^T (+bias)(+residual), all-bf16 operands  =============
// A: M x lda row-major bf16.  Bw: N x K row-major bf16 (pre-cast weights).
// MODE bit0: += R (fp32, stride N)   MODE bit1: += bias (fp32).  OutT: __bf16 or float.
template <int MODE, typename OutT>
__global__ __launch_bounds__(256) void gemm_bt(const bf16* __restrict__ A,
                                               const bf16* __restrict__ Bw,
                                               OutT* __restrict__ Cmat,
                                               const float* __restrict__ bias,
                                               const float* __restrict__ R,
                                               int M, int N, int K, int lda) {
  __shared__ __align__(16) bf16 Als[128 * 32];
  __shared__ __align__(16) bf16 Bls[128 * 32];
  const int tid  = threadIdx.x;
  const int wave = tid >> 6;
  const int lane = tid & 63;
  const int quad = lane >> 4;
  const int l16  = lane & 15;
  const int bm = blockIdx.x * 128;
  const int bn = blockIdx.y * 128;
  const int wm = (wave & 1) * 64;
  const int wn = (wave >> 1) * 64;
  const int srow   = lane >> 2;  // 0..15
  const int schunk = lane & 3;   // 0..3 (16B chunks of a 64B k-row)

  f32x4 acc[4][4];
#pragma unroll
  for (int i = 0; i < 4; i++)
#pragma unroll
    for (int j = 0; j < 4; j++) acc[i][j] = f32x4{0.f, 0.f, 0.f, 0.f};

  const bf16* Ag = A  + (size_t)(bm + wave * 32 + srow) * lda + schunk * 8;
  const bf16* Bg = Bw + (size_t)(bn + wave * 32 + srow) * K   + schunk * 8;
  bf16* AlsW = &Als[(wave * 32) * 32];   // wave-uniform LDS base (HW scatters lane*16B)
  bf16* BlsW = &Bls[(wave * 32) * 32];

  for (int k0 = 0; k0 < K; k0 += 32) {
    gld16(Ag + k0,                    AlsW);
    gld16(Ag + k0 + (size_t)16 * lda, AlsW + 16 * 32);
    gld16(Bg + k0,                    BlsW);
    gld16(Bg + k0 + (size_t)16 * K,   BlsW + 16 * 32);
    __syncthreads();   // drains vmcnt before barrier

    bf16x8 af[4], bfr[4];
#pragma unroll
    for (int mt = 0; mt < 4; mt++)
      af[mt] = *(const bf16x8*)&Als[(wm + mt * 16 + l16) * 32 + quad * 8];
#pragma unroll
    for (int nt = 0; nt < 4; nt++)
      bfr[nt] = *(const bf16x8*)&Bls[(wn + nt * 16 + l16) * 32 + quad * 8];
#pragma unroll
    for (int mt = 0; mt < 4; mt++)
#pragma unroll
      for (int nt = 0; nt < 4; nt++)
        acc[mt][nt] = __builtin_amdgcn_mfma_f32_16x16x32_bf16(af[mt], bfr[nt], acc[mt][nt], 0, 0, 0);
    __syncthreads();
  }

  // epilogue: D row = wm+mt*16+quad*4+r, col = wn+nt*16+l16
#pragma unroll
  for (int mt = 0; mt < 4; mt++) {
    const int row = bm + wm + mt * 16 + quad * 4;
#pragma unroll
    for (int nt = 0; nt < 4; nt++) {
      const int col = bn + wn + nt * 16 + l16;
      float bval = 0.f;
      if (MODE & 2) bval = bias[col];
#pragma unroll
      for (int r = 0; r < 4; r++) {
        float v = acc[mt][nt][r] + bval;
        if (MODE & 1) v += R[(size_t)(row + r) * N + col];
        Cmat[(size_t)(row + r) * N + col] = (OutT)v;
      }
    }
  }
}

// =====================  RMSNorm: fp32 in -> bf16 out (row = 1024)  =====================
__global__ __launch_bounds__(256) void rmsnorm_kernel(const float* __restrict__ X,
                                                      bf16* __restrict__ O) {
  const int row = blockIdx.x;
  const int tid = threadIdx.x;
  const int wave = tid >> 6;
  f32x4 v = *(const f32x4*)(X + (size_t)row * C_ + tid * 4);
  float s = v[0] * v[0] + v[1] * v[1] + v[2] * v[2] + v[3] * v[3];
#pragma unroll
  for (int off = 32; off >= 1; off >>= 1) s += __shfl_xor(s, off);
  __shared__ float wsum[4];
  __shared__ float scale_sh;
  if ((tid & 63) == 0) wsum[wave] = s;
  __syncthreads();
  if (tid == 0)
    scale_sh = rsqrtf((wsum[0] + wsum[1] + wsum[2] + wsum[3]) * (1.f / (float)C_) + 1e-6f);
  __syncthreads();
  const float sc = scale_sh;
  bf16x4 o;
  o[0] = (bf16)(v[0] * sc); o[1] = (bf16)(v[1] * sc);
  o[2] = (bf16)(v[2] * sc); o[3] = (bf16)(v[3] * sc);
  *(bf16x4*)(O + (size_t)row * C_ + tid * 4) = o;
}

// ==========  Rotary on q,k (bf16, in-place) + q0/k0 = sqrt(kc + |.|^2)  ==========
__global__ __launch_bounds__(256) void rotary_kernel(bf16* __restrict__ qkv,
                                                     const float* __restrict__ kcb,
                                                     float* __restrict__ q0b,
                                                     float* __restrict__ k0b) {
  const int wid  = blockIdx.x * 4 + (threadIdx.x >> 6);  // one wave per (b,t,h)
  const int lane = threadIdx.x & 63;
  const int b = wid >> 15;          // T_*H_ = 32768
  const int rem = wid & 32767;
  const int t = rem >> 4;
  const int h = rem & 15;
  const int i = lane & 31;
  const float invf = expf(-((float)i / 32.f) * 9.210340371976184f);  // 10000^(-i/32)
  const float ang = (float)t * invf;
  const float cx = cosf(ang), sx = sinf(ang);
  const float kc = kcb[h];
  bf16* qp = qkv + (size_t)(b * T_ + t) * 3072 + h * 64;

#pragma unroll
  for (int which = 0; which < 2; which++) {
    bf16* p = qp + which * 1024;   // q then k
    float x1 = (float)p[i];
    float x2 = (float)p[i + 32];
    float o = (lane < 32) ? (x1 * cx + x2 * sx) : (x2 * cx - x1 * sx);
    float ss = o * o;
#pragma unroll
    for (int off = 32; off >= 1; off >>= 1) ss += __shfl_xor(ss, off);
    p[lane] = (bf16)o;
    if (lane == 0) {
      float* dst = which == 0 ? q0b : k0b;
      dst[(size_t)(b * H_ + h) * T_ + t] = sqrtf(kc + ss);
    }
  }
}

// =====================  Hyperbolic flash attention (v2)  =====================
// Scores are -dis <= 0 and the causal diagonal gives dis = 0, so exp(score) is in
// (0,1] and every row-sum >= 1: NO online max needed, NO per-tile reductions.
// Work balance: block (bh, y) handles q-tiles y and 31-y (uniform 68 tile-units).
// grid: (B*H, 16); block 256 = 4 waves; wave w owns 16 q-rows of the current tile.
__global__ __launch_bounds__(256) void attn_kernel(const bf16* __restrict__ qkv,
                                                   const float* __restrict__ q0b,
                                                   const float* __restrict__ k0b,
                                                   const float* __restrict__ kcb,
                                                   bf16* __restrict__ outp) {
  __shared__ __align__(16) bf16 Kls[32][72];     // K tile [s][d]
  __shared__ __align__(16) bf16 Vt[64][34];      // V^T [d][s]; 17-dw stride: 16->4-way wr conflicts
  __shared__ __align__(16) bf16 Pls[4][16 * 36]; // per-wave P roundtrip; 18-dw stride: 2-way (free)
  __shared__ float k0s[32];

  const int tid = threadIdx.x;
  const int wave = tid >> 6, lane = tid & 63;
  const int quad = lane >> 4, l16 = lane & 15;
  const int bh = blockIdx.x;
  const int b = bh >> 4, h = bh & 15;

  const float kc = kcb[h];
  const float inv_kc = 1.f / kc;
  const float sqkc = sqrtf(kc);
  const int ss = tid >> 3, dg = tid & 7;
  bf16* Pl = Pls[wave];
  const float* q0base = q0b + (size_t)(b * H_ + h) * T_;
  const float* k0base = k0b + (size_t)(b * H_ + h) * T_;

  for (int pass = 0; pass < 2; ++pass) {
    const int ty = pass ? (31 - (int)blockIdx.y) : (int)blockIdx.y;
    const int t0 = ty * 64;
    const int tb = t0 + wave * 16;

    // q A-frags: A[m=l16][k=quad*8+j]
    const bf16* qrow = qkv + (size_t)(b * T_ + tb + l16) * 3072 + h * 64;
    bf16x8 aq0 = *(const bf16x8*)(qrow + quad * 8);
    bf16x8 aq1 = *(const bf16x8*)(qrow + 32 + quad * 8);
    float q0r[4];
#pragma unroll
    for (int r = 0; r < 4; r++) q0r[r] = q0base[tb + quad * 4 + r];

    f32x4 o[4];
#pragma unroll
    for (int dt = 0; dt < 4; dt++) o[dt] = f32x4{0.f, 0.f, 0.f, 0.f};
    float lrow[4] = {0.f, 0.f, 0.f, 0.f};   // per-lane partial row sums

    for (int s0 = 0; s0 < t0 + 64; s0 += 32) {
      // ---- stage K (row-major) and V (transposed) ----
      const bf16* krow = qkv + (size_t)(b * T_ + s0 + ss) * 3072 + 1024 + h * 64 + dg * 8;
      bf16x8 kv = *(const bf16x8*)krow;
      bf16x8 vv = *(const bf16x8*)(krow + 1024);
      *(bf16x8*)&Kls[ss][dg * 8] = kv;
#pragma unroll
      for (int i2 = 0; i2 < 8; i2++) Vt[dg * 8 + i2][ss] = vv[i2];
      if (tid < 32) k0s[tid] = k0base[s0 + tid];
      __syncthreads();

      // ---- S = q @ K^T (two 16-col n-tiles) ----
      f32x4 sc[2];
      sc[0] = f32x4{0.f, 0.f, 0.f, 0.f};
      sc[1] = f32x4{0.f, 0.f, 0.f, 0.f};
#pragma unroll
      for (int nt = 0; nt < 2; nt++) {
        bf16x8 b0 = *(const bf16x8*)&Kls[nt * 16 + l16][quad * 8];
        bf16x8 b1 = *(const bf16x8*)&Kls[nt * 16 + l16][32 + quad * 8];
        sc[nt] = __builtin_amdgcn_mfma_f32_16x16x32_bf16(aq0, b0, sc[nt], 0, 0, 0);
        sc[nt] = __builtin_amdgcn_mfma_f32_16x16x32_bf16(aq1, b1, sc[nt], 0, 0, 0);
      }

      // ---- p = exp(-dis), causal-masked; exp(-s*ln w) == exp2(-s*log2 w) ----
#pragma unroll
      for (int nt = 0; nt < 2; nt++) {
        const float k0c = k0s[nt * 16 + l16];
        const int s = s0 + nt * 16 + l16;
#pragma unroll
        for (int r = 0; r < 4; r++) {
          const int t = tb + quad * 4 + r;
          float lor = sc[nt][r] - q0r[r] * k0c;
          float ratio = fminf(fmaxf(-lor * inv_kc, 1.f + 1e-6f), 1e18f);
          float wv = ratio + sqrtf(ratio * ratio - 1.f);
          float p = EXP2F(-sqkc * LOG2F(wv));
          p = (s <= t) ? p : 0.f;
          lrow[r] += p;
          Pl[(quad * 4 + r) * 36 + nt * 16 + l16] = (bf16)p;
        }
      }
      // wave-private LDS roundtrip: DS ops complete in order within a wave
      bf16x8 ap = *(const bf16x8*)&Pl[l16 * 36 + quad * 8];
#pragma unroll
      for (int dt = 0; dt < 4; dt++) {
        bf16x8 bv = *(const bf16x8*)&Vt[dt * 16 + l16][quad * 8];
        o[dt] = __builtin_amdgcn_mfma_f32_16x16x32_bf16(ap, bv, o[dt], 0, 0, 0);
      }
      __syncthreads();
    }

    // ---- one deferred l-reduction over the 16 l16 lanes, then write O ----
#pragma unroll
    for (int r = 0; r < 4; r++) {
#pragma unroll
      for (int off = 1; off <= 8; off <<= 1) lrow[r] += __shfl_xor(lrow[r], off);
    }
#pragma unroll
    for (int r = 0; r < 4; r++) {
      const float invl = 1.f / lrow[r];   // lrow >= 1 (diagonal term)
      const int t = tb + quad * 4 + r;
#pragma unroll
      for (int dt = 0; dt < 4; dt++) {
        float val = o[dt][r] * invl;
        outp[(size_t)(b * T_ + t) * C_ + h * 64 + dt * 16 + l16] = (bf16)val;
      }
    }
  }
}

// ==============  SwiGLU in-place (bf16): uv[m][0..4096) = u * silu(v)  ==============
__global__ __launch_bounds__(256) void swiglu_kernel(bf16* __restrict__ uv) {
  const size_t gid = (size_t)blockIdx.x * 256 + threadIdx.x;
  const size_t e0 = gid * 4;
  const size_t m = e0 >> 12;      // / 4096
  const size_t j = e0 & 4095;
  bf16* up = uv + m * 8192 + j;
  bf16x4 u4 = *(const bf16x4*)up;
  bf16x4 v4 = *(const bf16x4*)(up + 4096);
  bf16x4 o;
#pragma unroll
  for (int i = 0; i < 4; i++) {
    float uu = (float)u4[i];
    float vvv = (float)v4[i];
    float vc = fminf(fmaxf(vvv, -80.f), 80.f);
    float sig = 1.f / (1.f + __expf(-vc));
    o[i] = (bf16)(uu * vvv * sig);
  }
  *(bf16x4*)up = o;
}

// =====================  host-side launch  =====================
extern "C" void kernel_launch(void* const* d_in, const int* in_sizes, int n_in,
                              void* d_out, int out_size, void* d_ws, size_t ws_size,
                              hipStream_t stream) {
  const float* x      = (const float*)d_in[0];
  const float* w_qkv  = (const float*)d_in[1];
  const float* w_out  = (const float*)d_in[2];
  const float* kcb    = (const float*)d_in[3];
  const float* w_uv   = (const float*)d_in[4];
  const float* b_uv   = (const float*)d_in[5];
  const float* w_mlp  = (const float*)d_in[6];
  const float* b_mlp  = (const float*)d_in[7];
  float* out = (float*)d_out;

  const size_t MB = 1024ull * 1024ull;
  char* w = (char*)d_ws;
  bf16*  wqkv_b  = (bf16*)(w + 0);          //  6 MB   [0,6)
  bf16*  wout_b  = (bf16*)(w + 6 * MB);     //  2 MB   [6,8)
  bf16*  wuv_b   = (bf16*)(w + 8 * MB);     // 16 MB   [8,24)
  bf16*  wmlp_b  = (bf16*)(w + 24 * MB);    //  8 MB   [24,32)
  bf16*  hbuf    = (bf16*)(w + 32 * MB);    //  8 MB   [32,40)
  bf16*  qkvbuf  = (bf16*)(w + 40 * MB);    // 24 MB   [40,64) dead after attn
  bf16*  attnbuf = (bf16*)(w + 64 * MB);    //  8 MB   [64,72) dead after step 5
  bf16*  uvbuf   = (bf16*)(w + 40 * MB);    // 64 MB   [40,104) over qkv+attn
  float* x2buf   = (float*)(w + 104 * MB);  // 16 MB   [104,120) fp32
  float* q0b     = (float*)(w + 120 * MB);               // 256 KB
  float* k0b     = (float*)(w + 120 * MB + 256 * 1024);  // 256 KB
  // total: 120.5 MB

  // 0) one-time weight casts fp32 -> bf16
  cast_kernel<<<(3072 * 1024 / 4 + 255) / 256, 256, 0, stream>>>(w_qkv, wqkv_b, 3072 * 1024 / 4);
  cast_kernel<<<(1024 * 1024 / 4 + 255) / 256, 256, 0, stream>>>(w_out, wout_b, 1024 * 1024 / 4);
  cast_kernel<<<(8192 * 1024 / 4 + 255) / 256, 256, 0, stream>>>(w_uv,  wuv_b,  8192 * 1024 / 4);
  cast_kernel<<<(4096 * 1024 / 4 + 255) / 256, 256, 0, stream>>>(w_mlp, wmlp_b, 4096 * 1024 / 4);

  // 1) h = rmsnorm(x)                                  fp32 -> bf16
  rmsnorm_kernel<<<M_, 256, 0, stream>>>(x, hbuf);
  // 2) qkv = h @ w_qkv^T                               bf16 -> bf16
  gemm_bt<0, bf16><<<dim3(M_ / 128, 3072 / 128), 256, 0, stream>>>(
      hbuf, wqkv_b, qkvbuf, nullptr, nullptr, M_, 3072, 1024, 1024);
  // 3) rotary(q,k) in-place + q0/k0
  rotary_kernel<<<(B_ * T_ * H_) / 4, 256, 0, stream>>>(qkvbuf, kcb, q0b, k0b);
  // 4) hyperbolic flash attention                      -> bf16
  attn_kernel<<<dim3(B_ * H_, 16), 256, 0, stream>>>(qkvbuf, q0b, k0b, kcb, attnbuf);
  // 5) x2 = x + attn @ w_out^T                         -> fp32
  gemm_bt<1, float><<<dim3(M_ / 128, 1024 / 128), 256, 0, stream>>>(
      attnbuf, wout_b, x2buf, nullptr, x, M_, 1024, 1024, 1024);
  // 6) h2 = rmsnorm(x2)                                fp32 -> bf16
  rmsnorm_kernel<<<M_, 256, 0, stream>>>(x2buf, hbuf);
  // 7) uv = h2 @ w_uv^T + b_uv                         -> bf16
  gemm_bt<2, bf16><<<dim3(M_ / 128, 8192 / 128), 256, 0, stream>>>(
      hbuf, wuv_b, uvbuf, b_uv, nullptr, M_, 8192, 1024, 1024);
  // 8) g = u * silu(v), in place over u-half (row stride 8192)
  swiglu_kernel<<<(M_ * 4096) / (4 * 256), 256, 0, stream>>>(uvbuf);
  // 9) out = x2 + g @ w_mlp^T + b_mlp                  -> fp32
  gemm_bt<3, float><<<dim3(M_ / 128, 1024 / 128), 256, 0, stream>>>(
      uvbuf, wmlp_b, out, b_mlp, x2buf, M_, 1024, 4096, 8192);
}

// Round 6
// 517.411 us; speedup vs baseline: 1.3374x; 1.0296x over previous
//
#include <hip/hip_runtime.h>
#include <cstdint>
#include <cmath>

typedef __bf16 bf16;
typedef __attribute__((ext_vector_type(8))) __bf16 bf16x8;
typedef __attribute__((ext_vector_type(4))) __bf16 bf16x4;
typedef __attribute__((ext_vector_type(4))) float f32x4;

constexpr int B_ = 2, T_ = 2048, C_ = 1024, H_ = 16, HD_ = 64;
constexpr int M_ = B_ * T_;   // 4096

// native 2^x and log2(x) (v_exp_f32 / v_log_f32)
#define EXP2F(x) __builtin_amdgcn_exp2f(x)
#define LOG2F(x) __builtin_amdgcn_logf(x)

// ---- async global->LDS, 16B per lane; LDS dest = wave-uniform base + lane*16 ----
__device__ __forceinline__ void gld16(const void* g, void* l) {
  __builtin_amdgcn_global_load_lds((const __attribute__((address_space(1))) void*)g,
                                   (__attribute__((address_space(3))) void*)l, 16, 0, 0);
}

// ============  fused weight cast: fp32 -> bf16 for all four weight tensors  ============
// segments (in units of 4 floats): qkv 786432 | wout 262144 | wuv 2097152 | wmlp 1048576
__global__ __launch_bounds__(256) void cast_all_kernel(const float* __restrict__ s0,
                                                       const float* __restrict__ s1,
                                                       const float* __restrict__ s2,
                                                       const float* __restrict__ s3,
                                                       bf16* __restrict__ d0,
                                                       bf16* __restrict__ d1,
                                                       bf16* __restrict__ d2,
                                                       bf16* __restrict__ d3) {
  size_t gid = (size_t)blockIdx.x * 256 + threadIdx.x;
  const float* src;
  bf16* dst;
  if (gid < 786432) { src = s0; dst = d0; }
  else if (gid < 786432 + 262144) { gid -= 786432; src = s1; dst = d1; }
  else if (gid < 786432 + 262144 + 2097152) { gid -= 786432 + 262144; src = s2; dst = d2; }
  else { gid -= 786432 + 262144 + 2097152; src = s3; dst = d3; }
  f32x4 v = *(const f32x4*)(src + gid * 4);
  bf16x4 o;
  o[0] = (bf16)v[0]; o[1] = (bf16)v[1]; o[2] = (bf16)v[2]; o[3] = (bf16)v[3];
  *(bf16x4*)(dst + gid * 4) = o;
}

// =============  GEMM: C = A @ Bw^T (+bias)(+residual), all-bf16 operands  =============
// A: M x lda row-major bf16.  Bw: N x K row-major bf16 (pre-cast weights).
// MODE bit0: += R (fp32, stride N)   MODE bit1: += bias (fp32).  OutT: __bf16 or float.
template <int MODE, typename OutT>
__global__ __launch_bounds__(256) void gemm_bt(const bf16* __restrict__ A,
                                               const bf16* __restrict__ Bw,
                                               OutT* __restrict__ Cmat,
                                               const float* __restrict__ bias,
                                               const float* __restrict__ R,
                                               int M, int N, int K, int lda) {
  __shared__ __align__(16) bf16 Als[128 * 32];
  __shared__ __align__(16) bf16 Bls[128 * 32];
  const int tid  = threadIdx.x;
  const int wave = tid >> 6;
  const int lane = tid & 63;
  const int quad = lane >> 4;
  const int l16  = lane & 15;
  const int bm = blockIdx.x * 128;
  const int bn = blockIdx.y * 128;
  const int wm = (wave & 1) * 64;
  const int wn = (wave >> 1) * 64;
  const int srow   = lane >> 2;  // 0..15
  const int schunk = lane & 3;   // 0..3 (16B chunks of a 64B k-row)

  f32x4 acc[4][4];
#pragma unroll
  for (int i = 0; i < 4; i++)
#pragma unroll
    for (int j = 0; j < 4; j++) acc[i][j] = f32x4{0.f, 0.f, 0.f, 0.f};

  const bf16* Ag = A  + (size_t)(bm + wave * 32 + srow) * lda + schunk * 8;
  const bf16* Bg = Bw + (size_t)(bn + wave * 32 + srow) * K   + schunk * 8;
  bf16* AlsW = &Als[(wave * 32) * 32];   // wave-uniform LDS base (HW scatters lane*16B)
  bf16* BlsW = &Bls[(wave * 32) * 32];

  for (int k0 = 0; k0 < K; k0 += 32) {
    gld16(Ag + k0,                    AlsW);
    gld16(Ag + k0 + (size_t)16 * lda, AlsW + 16 * 32);
    gld16(Bg + k0,                    BlsW);
    gld16(Bg + k0 + (size_t)16 * K,   BlsW + 16 * 32);
    __syncthreads();   // drains vmcnt before barrier

    bf16x8 af[4], bfr[4];
#pragma unroll
    for (int mt = 0; mt < 4; mt++)
      af[mt] = *(const bf16x8*)&Als[(wm + mt * 16 + l16) * 32 + quad * 8];
#pragma unroll
    for (int nt = 0; nt < 4; nt++)
      bfr[nt] = *(const bf16x8*)&Bls[(wn + nt * 16 + l16) * 32 + quad * 8];
#pragma unroll
    for (int mt = 0; mt < 4; mt++)
#pragma unroll
      for (int nt = 0; nt < 4; nt++)
        acc[mt][nt] = __builtin_amdgcn_mfma_f32_16x16x32_bf16(af[mt], bfr[nt], acc[mt][nt], 0, 0, 0);
    __syncthreads();
  }

  // epilogue: D row = wm+mt*16+quad*4+r, col = wn+nt*16+l16
#pragma unroll
  for (int mt = 0; mt < 4; mt++) {
    const int row = bm + wm + mt * 16 + quad * 4;
#pragma unroll
    for (int nt = 0; nt < 4; nt++) {
      const int col = bn + wn + nt * 16 + l16;
      float bval = 0.f;
      if (MODE & 2) bval = bias[col];
#pragma unroll
      for (int r = 0; r < 4; r++) {
        float v = acc[mt][nt][r] + bval;
        if (MODE & 1) v += R[(size_t)(row + r) * N + col];
        Cmat[(size_t)(row + r) * N + col] = (OutT)v;
      }
    }
  }
}

// =====================  RMSNorm: fp32 in -> bf16 out (row = 1024)  =====================
__global__ __launch_bounds__(256) void rmsnorm_kernel(const float* __restrict__ X,
                                                      bf16* __restrict__ O) {
  const int row = blockIdx.x;
  const int tid = threadIdx.x;
  const int wave = tid >> 6;
  f32x4 v = *(const f32x4*)(X + (size_t)row * C_ + tid * 4);
  float s = v[0] * v[0] + v[1] * v[1] + v[2] * v[2] + v[3] * v[3];
#pragma unroll
  for (int off = 32; off >= 1; off >>= 1) s += __shfl_xor(s, off);
  __shared__ float wsum[4];
  __shared__ float scale_sh;
  if ((tid & 63) == 0) wsum[wave] = s;
  __syncthreads();
  if (tid == 0)
    scale_sh = rsqrtf((wsum[0] + wsum[1] + wsum[2] + wsum[3]) * (1.f / (float)C_) + 1e-6f);
  __syncthreads();
  const float sc = scale_sh;
  bf16x4 o;
  o[0] = (bf16)(v[0] * sc); o[1] = (bf16)(v[1] * sc);
  o[2] = (bf16)(v[2] * sc); o[3] = (bf16)(v[3] * sc);
  *(bf16x4*)(O + (size_t)row * C_ + tid * 4) = o;
}

// ==========  Rotary on q,k (bf16, in-place) + q0/k0 = sqrt(kc + |.|^2)  ==========
__global__ __launch_bounds__(256) void rotary_kernel(bf16* __restrict__ qkv,
                                                     const float* __restrict__ kcb,
                                                     float* __restrict__ q0b,
                                                     float* __restrict__ k0b) {
  const int wid  = blockIdx.x * 4 + (threadIdx.x >> 6);  // one wave per (b,t,h)
  const int lane = threadIdx.x & 63;
  const int b = wid >> 15;          // T_*H_ = 32768
  const int rem = wid & 32767;
  const int t = rem >> 4;
  const int h = rem & 15;
  const int i = lane & 31;
  const float invf = expf(-((float)i / 32.f) * 9.210340371976184f);  // 10000^(-i/32)
  const float ang = (float)t * invf;
  const float cx = cosf(ang), sx = sinf(ang);
  const float kc = kcb[h];
  bf16* qp = qkv + (size_t)(b * T_ + t) * 3072 + h * 64;

#pragma unroll
  for (int which = 0; which < 2; which++) {
    bf16* p = qp + which * 1024;   // q then k
    float x1 = (float)p[i];
    float x2 = (float)p[i + 32];
    float o = (lane < 32) ? (x1 * cx + x2 * sx) : (x2 * cx - x1 * sx);
    float ss = o * o;
#pragma unroll
    for (int off = 32; off >= 1; off >>= 1) ss += __shfl_xor(ss, off);
    p[lane] = (bf16)o;
    if (lane == 0) {
      float* dst = which == 0 ? q0b : k0b;
      dst[(size_t)(b * H_ + h) * T_ + t] = sqrtf(kc + ss);
    }
  }
}

// =====================  Hyperbolic flash attention (v3)  =====================
// Scores are -dis <= 0 and the causal diagonal gives dis = 0, so exp(score) is in
// (0,1] and every row-sum >= 1: no online max, no per-tile reductions.
// grid (B*H, 32): ONE 64-row q-tile per block -> 1024 blocks = 4 blocks/CU (2x R5
// occupancy). Heaviest-first: ty = 31 - blockIdx.y (LPT; light tiles pack the tail).
__global__ __launch_bounds__(256) void attn_kernel(const bf16* __restrict__ qkv,
                                                   const float* __restrict__ q0b,
                                                   const float* __restrict__ k0b,
                                                   const float* __restrict__ kcb,
                                                   bf16* __restrict__ outp) {
  __shared__ __align__(16) bf16 Kls[32][72];     // K tile [s][d]
  __shared__ __align__(16) bf16 Vt[64][34];      // V^T [d][s]; 17-dw stride: 4-way wr conflicts
  __shared__ __align__(16) bf16 Pls[4][16 * 36]; // per-wave P roundtrip; 18-dw stride: 2-way (free)
  __shared__ float k0s[32];

  const int tid = threadIdx.x;
  const int wave = tid >> 6, lane = tid & 63;
  const int quad = lane >> 4, l16 = lane & 15;
  const int bh = blockIdx.x;
  const int b = bh >> 4, h = bh & 15;

  const float kc = kcb[h];
  const float inv_kc = 1.f / kc;
  const float sqkc = sqrtf(kc);
  const int ss = tid >> 3, dg = tid & 7;
  bf16* Pl = Pls[wave];
  const float* q0base = q0b + (size_t)(b * H_ + h) * T_;
  const float* k0base = k0b + (size_t)(b * H_ + h) * T_;

  const int ty = 31 - (int)blockIdx.y;   // heaviest blocks dispatch first
  const int t0 = ty * 64;
  const int tb = t0 + wave * 16;

  // q A-frags: A[m=l16][k=quad*8+j]
  const bf16* qrow = qkv + (size_t)(b * T_ + tb + l16) * 3072 + h * 64;
  bf16x8 aq0 = *(const bf16x8*)(qrow + quad * 8);
  bf16x8 aq1 = *(const bf16x8*)(qrow + 32 + quad * 8);
  float q0r[4];
#pragma unroll
  for (int r = 0; r < 4; r++) q0r[r] = q0base[tb + quad * 4 + r];

  f32x4 o[4];
#pragma unroll
  for (int dt = 0; dt < 4; dt++) o[dt] = f32x4{0.f, 0.f, 0.f, 0.f};
  float lrow[4] = {0.f, 0.f, 0.f, 0.f};   // per-lane partial row sums

  for (int s0 = 0; s0 < t0 + 64; s0 += 32) {
    // ---- stage K (row-major) and V (transposed) ----
    const bf16* krow = qkv + (size_t)(b * T_ + s0 + ss) * 3072 + 1024 + h * 64 + dg * 8;
    bf16x8 kv = *(const bf16x8*)krow;
    bf16x8 vv = *(const bf16x8*)(krow + 1024);
    *(bf16x8*)&Kls[ss][dg * 8] = kv;
#pragma unroll
    for (int i2 = 0; i2 < 8; i2++) Vt[dg * 8 + i2][ss] = vv[i2];
    if (tid < 32) k0s[tid] = k0base[s0 + tid];
    __syncthreads();

    // ---- S = q @ K^T (two 16-col n-tiles) ----
    f32x4 sc[2];
    sc[0] = f32x4{0.f, 0.f, 0.f, 0.f};
    sc[1] = f32x4{0.f, 0.f, 0.f, 0.f};
#pragma unroll
    for (int nt = 0; nt < 2; nt++) {
      bf16x8 b0 = *(const bf16x8*)&Kls[nt * 16 + l16][quad * 8];
      bf16x8 b1 = *(const bf16x8*)&Kls[nt * 16 + l16][32 + quad * 8];
      sc[nt] = __builtin_amdgcn_mfma_f32_16x16x32_bf16(aq0, b0, sc[nt], 0, 0, 0);
      sc[nt] = __builtin_amdgcn_mfma_f32_16x16x32_bf16(aq1, b1, sc[nt], 0, 0, 0);
    }

    // ---- p = exp(-dis), causal-masked; exp(-s*ln w) == exp2(-s*log2 w) ----
#pragma unroll
    for (int nt = 0; nt < 2; nt++) {
      const float k0c = k0s[nt * 16 + l16];
      const int s = s0 + nt * 16 + l16;
#pragma unroll
      for (int r = 0; r < 4; r++) {
        const int t = tb + quad * 4 + r;
        float lor = sc[nt][r] - q0r[r] * k0c;
        float ratio = fminf(fmaxf(-lor * inv_kc, 1.f + 1e-6f), 1e18f);
        float wv = ratio + sqrtf(ratio * ratio - 1.f);
        float p = EXP2F(-sqkc * LOG2F(wv));
        p = (s <= t) ? p : 0.f;
        lrow[r] += p;
        Pl[(quad * 4 + r) * 36 + nt * 16 + l16] = (bf16)p;
      }
    }
    // wave-private LDS roundtrip: DS ops complete in order within a wave
    bf16x8 ap = *(const bf16x8*)&Pl[l16 * 36 + quad * 8];
#pragma unroll
    for (int dt = 0; dt < 4; dt++) {
      bf16x8 bv = *(const bf16x8*)&Vt[dt * 16 + l16][quad * 8];
      o[dt] = __builtin_amdgcn_mfma_f32_16x16x32_bf16(ap, bv, o[dt], 0, 0, 0);
    }
    __syncthreads();
  }

  // ---- one deferred l-reduction over the 16 l16 lanes, then write O ----
#pragma unroll
  for (int r = 0; r < 4; r++) {
#pragma unroll
    for (int off = 1; off <= 8; off <<= 1) lrow[r] += __shfl_xor(lrow[r], off);
  }
#pragma unroll
  for (int r = 0; r < 4; r++) {
    const float invl = 1.f / lrow[r];   // lrow >= 1 (diagonal term)
    const int t = tb + quad * 4 + r;
#pragma unroll
    for (int dt = 0; dt < 4; dt++) {
      float val = o[dt][r] * invl;
      outp[(size_t)(b * T_ + t) * C_ + h * 64 + dt * 16 + l16] = (bf16)val;
    }
  }
}

// ==============  SwiGLU in-place (bf16): uv[m][0..4096) = u * silu(v)  ==============
__global__ __launch_bounds__(256) void swiglu_kernel(bf16* __restrict__ uv) {
  const size_t gid = (size_t)blockIdx.x * 256 + threadIdx.x;
  const size_t e0 = gid * 4;
  const size_t m = e0 >> 12;      // / 4096
  const size_t j = e0 & 4095;
  bf16* up = uv + m * 8192 + j;
  bf16x4 u4 = *(const bf16x4*)up;
  bf16x4 v4 = *(const bf16x4*)(up + 4096);
  bf16x4 o;
#pragma unroll
  for (int i = 0; i < 4; i++) {
    float uu = (float)u4[i];
    float vvv = (float)v4[i];
    float vc = fminf(fmaxf(vvv, -80.f), 80.f);
    float sig = 1.f / (1.f + __expf(-vc));
    o[i] = (bf16)(uu * vvv * sig);
  }
  *(bf16x4*)up = o;
}

// =====================  host-side launch  =====================
extern "C" void kernel_launch(void* const* d_in, const int* in_sizes, int n_in,
                              void* d_out, int out_size, void* d_ws, size_t ws_size,
                              hipStream_t stream) {
  const float* x      = (const float*)d_in[0];
  const float* w_qkv  = (const float*)d_in[1];
  const float* w_out  = (const float*)d_in[2];
  const float* kcb    = (const float*)d_in[3];
  const float* w_uv   = (const float*)d_in[4];
  const float* b_uv   = (const float*)d_in[5];
  const float* w_mlp  = (const float*)d_in[6];
  const float* b_mlp  = (const float*)d_in[7];
  float* out = (float*)d_out;

  const size_t MB = 1024ull * 1024ull;
  char* w = (char*)d_ws;
  bf16*  wqkv_b  = (bf16*)(w + 0);          //  6 MB   [0,6)
  bf16*  wout_b  = (bf16*)(w + 6 * MB);     //  2 MB   [6,8)
  bf16*  wuv_b   = (bf16*)(w + 8 * MB);     // 16 MB   [8,24)
  bf16*  wmlp_b  = (bf16*)(w + 24 * MB);    //  8 MB   [24,32)
  bf16*  hbuf    = (bf16*)(w + 32 * MB);    //  8 MB   [32,40)
  bf16*  qkvbuf  = (bf16*)(w + 40 * MB);    // 24 MB   [40,64) dead after attn
  bf16*  attnbuf = (bf16*)(w + 64 * MB);    //  8 MB   [64,72) dead after step 5
  bf16*  uvbuf   = (bf16*)(w + 40 * MB);    // 64 MB   [40,104) over qkv+attn
  float* x2buf   = (float*)(w + 104 * MB);  // 16 MB   [104,120) fp32
  float* q0b     = (float*)(w + 120 * MB);               // 256 KB
  float* k0b     = (float*)(w + 120 * MB + 256 * 1024);  // 256 KB
  // total: 120.5 MB

  // 0) one-time weight casts fp32 -> bf16 (single fused launch; 4.19M quad-groups)
  cast_all_kernel<<<(786432 + 262144 + 2097152 + 1048576) / 256, 256, 0, stream>>>(
      w_qkv, w_out, w_uv, w_mlp, wqkv_b, wout_b, wuv_b, wmlp_b);

  // 1) h = rmsnorm(x)                                  fp32 -> bf16
  rmsnorm_kernel<<<M_, 256, 0, stream>>>(x, hbuf);
  // 2) qkv = h @ w_qkv^T                               bf16 -> bf16
  gemm_bt<0, bf16><<<dim3(M_ / 128, 3072 / 128), 256, 0, stream>>>(
      hbuf, wqkv_b, qkvbuf, nullptr, nullptr, M_, 3072, 1024, 1024);
  // 3) rotary(q,k) in-place + q0/k0
  rotary_kernel<<<(B_ * T_ * H_) / 4, 256, 0, stream>>>(qkvbuf, kcb, q0b, k0b);
  // 4) hyperbolic flash attention                      -> bf16
  attn_kernel<<<dim3(B_ * H_, 32), 256, 0, stream>>>(qkvbuf, q0b, k0b, kcb, attnbuf);
  // 5) x2 = x + attn @ w_out^T                         -> fp32
  gemm_bt<1, float><<<dim3(M_ / 128, 1024 / 128), 256, 0, stream>>>(
      attnbuf, wout_b, x2buf, nullptr, x, M_, 1024, 1024, 1024);
  // 6) h2 = rmsnorm(x2)                                fp32 -> bf16
  rmsnorm_kernel<<<M_, 256, 0, stream>>>(x2buf, hbuf);
  // 7) uv = h2 @ w_uv^T + b_uv                         -> bf16
  gemm_bt<2, bf16><<<dim3(M_ / 128, 8192 / 128), 256, 0, stream>>>(
      hbuf, wuv_b, uvbuf, b_uv, nullptr, M_, 8192, 1024, 1024);
  // 8) g = u * silu(v), in place over u-half (row stride 8192)
  swiglu_kernel<<<(M_ * 4096) / (4 * 256), 256, 0, stream>>>(uvbuf);
  // 9) out = x2 + g @ w_mlp^T + b_mlp                  -> fp32
  gemm_bt<3, float><<<dim3(M_ / 128, 1024 / 128), 256, 0, stream>>>(
      uvbuf, wmlp_b, out, b_mlp, x2buf, M_, 1024, 4096, 8192);
}

// Round 7
// 502.788 us; speedup vs baseline: 1.3763x; 1.0291x over previous
//
#include <hip/hip_runtime.h>
#include <cstdint>
#include <cmath>

typedef __bf16 bf16;
typedef __attribute__((ext_vector_type(8))) __bf16 bf16x8;
typedef __attribute__((ext_vector_type(4))) __bf16 bf16x4;
typedef __attribute__((ext_vector_type(4))) float f32x4;

constexpr int B_ = 2, T_ = 2048, C_ = 1024, H_ = 16, HD_ = 64;
constexpr int M_ = B_ * T_;   // 4096

// native 2^x and log2(x) (v_exp_f32 / v_log_f32)
#define EXP2F(x) __builtin_amdgcn_exp2f(x)
#define LOG2F(x) __builtin_amdgcn_logf(x)

// ---- async global->LDS, 16B per lane; LDS dest = wave-uniform base + lane*16 ----
__device__ __forceinline__ void gld16(const void* g, void* l) {
  __builtin_amdgcn_global_load_lds((const __attribute__((address_space(1))) void*)g,
                                   (__attribute__((address_space(3))) void*)l, 16, 0, 0);
}

// ============  fused weight cast: fp32 -> bf16 for all four weight tensors  ============
// segments (in units of 4 floats): qkv 786432 | wout 262144 | wuv 2097152 | wmlp 1048576
__global__ __launch_bounds__(256) void cast_all_kernel(const float* __restrict__ s0,
                                                       const float* __restrict__ s1,
                                                       const float* __restrict__ s2,
                                                       const float* __restrict__ s3,
                                                       bf16* __restrict__ d0,
                                                       bf16* __restrict__ d1,
                                                       bf16* __restrict__ d2,
                                                       bf16* __restrict__ d3) {
  size_t gid = (size_t)blockIdx.x * 256 + threadIdx.x;
  const float* src;
  bf16* dst;
  if (gid < 786432) { src = s0; dst = d0; }
  else if (gid < 786432 + 262144) { gid -= 786432; src = s1; dst = d1; }
  else if (gid < 786432 + 262144 + 2097152) { gid -= 786432 + 262144; src = s2; dst = d2; }
  else { gid -= 786432 + 262144 + 2097152; src = s3; dst = d3; }
  f32x4 v = *(const f32x4*)(src + gid * 4);
  bf16x4 o;
  o[0] = (bf16)v[0]; o[1] = (bf16)v[1]; o[2] = (bf16)v[2]; o[3] = (bf16)v[3];
  *(bf16x4*)(dst + gid * 4) = o;
}

// =============  GEMM: C = A @ Bw^T (+bias)(+residual), all-bf16 operands  =============
// A: M x lda row-major bf16.  Bw: N x K row-major bf16 (pre-cast weights).
// MODE bit0: += R (fp32, stride N)   MODE bit1: += bias (fp32).  OutT: __bf16 or float.
template <int MODE, typename OutT>
__global__ __launch_bounds__(256) void gemm_bt(const bf16* __restrict__ A,
                                               const bf16* __restrict__ Bw,
                                               OutT* __restrict__ Cmat,
                                               const float* __restrict__ bias,
                                               const float* __restrict__ R,
                                               int M, int N, int K, int lda) {
  __shared__ __align__(16) bf16 Als[128 * 32];
  __shared__ __align__(16) bf16 Bls[128 * 32];
  const int tid  = threadIdx.x;
  const int wave = tid >> 6;
  const int lane = tid & 63;
  const int quad = lane >> 4;
  const int l16  = lane & 15;
  const int bm = blockIdx.x * 128;
  const int bn = blockIdx.y * 128;
  const int wm = (wave & 1) * 64;
  const int wn = (wave >> 1) * 64;
  const int srow   = lane >> 2;  // 0..15
  const int schunk = lane & 3;   // 0..3 (16B chunks of a 64B k-row)

  f32x4 acc[4][4];
#pragma unroll
  for (int i = 0; i < 4; i++)
#pragma unroll
    for (int j = 0; j < 4; j++) acc[i][j] = f32x4{0.f, 0.f, 0.f, 0.f};

  const bf16* Ag = A  + (size_t)(bm + wave * 32 + srow) * lda + schunk * 8;
  const bf16* Bg = Bw + (size_t)(bn + wave * 32 + srow) * K   + schunk * 8;
  bf16* AlsW = &Als[(wave * 32) * 32];   // wave-uniform LDS base (HW scatters lane*16B)
  bf16* BlsW = &Bls[(wave * 32) * 32];

  for (int k0 = 0; k0 < K; k0 += 32) {
    gld16(Ag + k0,                    AlsW);
    gld16(Ag + k0 + (size_t)16 * lda, AlsW + 16 * 32);
    gld16(Bg + k0,                    BlsW);
    gld16(Bg + k0 + (size_t)16 * K,   BlsW + 16 * 32);
    __syncthreads();   // drains vmcnt before barrier

    bf16x8 af[4], bfr[4];
#pragma unroll
    for (int mt = 0; mt < 4; mt++)
      af[mt] = *(const bf16x8*)&Als[(wm + mt * 16 + l16) * 32 + quad * 8];
#pragma unroll
    for (int nt = 0; nt < 4; nt++)
      bfr[nt] = *(const bf16x8*)&Bls[(wn + nt * 16 + l16) * 32 + quad * 8];
#pragma unroll
    for (int mt = 0; mt < 4; mt++)
#pragma unroll
      for (int nt = 0; nt < 4; nt++)
        acc[mt][nt] = __builtin_amdgcn_mfma_f32_16x16x32_bf16(af[mt], bfr[nt], acc[mt][nt], 0, 0, 0);
    __syncthreads();
  }

  // epilogue: D row = wm+mt*16+quad*4+r, col = wn+nt*16+l16
#pragma unroll
  for (int mt = 0; mt < 4; mt++) {
    const int row = bm + wm + mt * 16 + quad * 4;
#pragma unroll
    for (int nt = 0; nt < 4; nt++) {
      const int col = bn + wn + nt * 16 + l16;
      float bval = 0.f;
      if (MODE & 2) bval = bias[col];
#pragma unroll
      for (int r = 0; r < 4; r++) {
        float v = acc[mt][nt][r] + bval;
        if (MODE & 1) v += R[(size_t)(row + r) * N + col];
        Cmat[(size_t)(row + r) * N + col] = (OutT)v;
      }
    }
  }
}

// =====================  RMSNorm: fp32 in -> bf16 out (row = 1024)  =====================
__global__ __launch_bounds__(256) void rmsnorm_kernel(const float* __restrict__ X,
                                                      bf16* __restrict__ O) {
  const int row = blockIdx.x;
  const int tid = threadIdx.x;
  const int wave = tid >> 6;
  f32x4 v = *(const f32x4*)(X + (size_t)row * C_ + tid * 4);
  float s = v[0] * v[0] + v[1] * v[1] + v[2] * v[2] + v[3] * v[3];
#pragma unroll
  for (int off = 32; off >= 1; off >>= 1) s += __shfl_xor(s, off);
  __shared__ float wsum[4];
  __shared__ float scale_sh;
  if ((tid & 63) == 0) wsum[wave] = s;
  __syncthreads();
  if (tid == 0)
    scale_sh = rsqrtf((wsum[0] + wsum[1] + wsum[2] + wsum[3]) * (1.f / (float)C_) + 1e-6f);
  __syncthreads();
  const float sc = scale_sh;
  bf16x4 o;
  o[0] = (bf16)(v[0] * sc); o[1] = (bf16)(v[1] * sc);
  o[2] = (bf16)(v[2] * sc); o[3] = (bf16)(v[3] * sc);
  *(bf16x4*)(O + (size_t)row * C_ + tid * 4) = o;
}

// ==========  Rotary on q,k (bf16, in-place) + q0/k0 = sqrt(kc + |.|^2)  ==========
__global__ __launch_bounds__(256) void rotary_kernel(bf16* __restrict__ qkv,
                                                     const float* __restrict__ kcb,
                                                     float* __restrict__ q0b,
                                                     float* __restrict__ k0b) {
  const int wid  = blockIdx.x * 4 + (threadIdx.x >> 6);  // one wave per (b,t,h)
  const int lane = threadIdx.x & 63;
  const int b = wid >> 15;          // T_*H_ = 32768
  const int rem = wid & 32767;
  const int t = rem >> 4;
  const int h = rem & 15;
  const int i = lane & 31;
  const float invf = expf(-((float)i / 32.f) * 9.210340371976184f);  // 10000^(-i/32)
  const float ang = (float)t * invf;
  const float cx = cosf(ang), sx = sinf(ang);
  const float kc = kcb[h];
  bf16* qp = qkv + (size_t)(b * T_ + t) * 3072 + h * 64;

#pragma unroll
  for (int which = 0; which < 2; which++) {
    bf16* p = qp + which * 1024;   // q then k
    float x1 = (float)p[i];
    float x2 = (float)p[i + 32];
    float o = (lane < 32) ? (x1 * cx + x2 * sx) : (x2 * cx - x1 * sx);
    float ss = o * o;
#pragma unroll
    for (int off = 32; off >= 1; off >>= 1) ss += __shfl_xor(ss, off);
    p[lane] = (bf16)o;
    if (lane == 0) {
      float* dst = which == 0 ? q0b : k0b;
      dst[(size_t)(b * H_ + h) * T_ + t] = sqrtf(kc + ss);
    }
  }
}

// =====================  Hyperbolic flash attention (v4)  =====================
// v3 + REGISTER PREFETCH: tile k+1's K/V/k0 global loads are issued right after
// tile k's stage-barrier, so their ~200-900 cyc latency overlaps tile k's ~450 cyc
// of score/MFMA work instead of serializing in front of it (R6 counters: VALUBusy
// 53% with loads exposed at iteration top).
// grid (B*H, 32), heaviest-first (LPT). Scores in (0,1], row-sum >= 1: no online max.
__global__ __launch_bounds__(256) void attn_kernel(const bf16* __restrict__ qkv,
                                                   const float* __restrict__ q0b,
                                                   const float* __restrict__ k0b,
                                                   const float* __restrict__ kcb,
                                                   bf16* __restrict__ outp) {
  __shared__ __align__(16) bf16 Kls[32][72];     // K tile [s][d]
  __shared__ __align__(16) bf16 Vt[64][34];      // V^T [d][s]; 17-dw stride: 4-way wr conflicts
  __shared__ __align__(16) bf16 Pls[4][16 * 36]; // per-wave P roundtrip; 18-dw stride: 2-way (free)
  __shared__ float k0s[32];

  const int tid = threadIdx.x;
  const int wave = tid >> 6, lane = tid & 63;
  const int quad = lane >> 4, l16 = lane & 15;
  const int bh = blockIdx.x;
  const int b = bh >> 4, h = bh & 15;

  const float kc = kcb[h];
  const float inv_kc = 1.f / kc;
  const float sqkc = sqrtf(kc);
  const int ss = tid >> 3, dg = tid & 7;
  bf16* Pl = Pls[wave];
  const float* q0base = q0b + (size_t)(b * H_ + h) * T_;
  const float* k0base = k0b + (size_t)(b * H_ + h) * T_;

  const int ty = 31 - (int)blockIdx.y;   // heaviest blocks dispatch first
  const int t0 = ty * 64;
  const int tb = t0 + wave * 16;

  // q A-frags: A[m=l16][k=quad*8+j]
  const bf16* qrow = qkv + (size_t)(b * T_ + tb + l16) * 3072 + h * 64;
  bf16x8 aq0 = *(const bf16x8*)(qrow + quad * 8);
  bf16x8 aq1 = *(const bf16x8*)(qrow + 32 + quad * 8);
  float q0r[4];
#pragma unroll
  for (int r = 0; r < 4; r++) q0r[r] = q0base[tb + quad * 4 + r];

  f32x4 o[4];
#pragma unroll
  for (int dt = 0; dt < 4; dt++) o[dt] = f32x4{0.f, 0.f, 0.f, 0.f};
  float lrow[4] = {0.f, 0.f, 0.f, 0.f};   // per-lane partial row sums

  // ---- prologue: prefetch tile 0 into registers ----
  const bf16* kbase = qkv + (size_t)b * T_ * 3072 + 1024 + h * 64 + dg * 8;
  bf16x8 kv = *(const bf16x8*)(kbase + (size_t)ss * 3072);
  bf16x8 vv = *(const bf16x8*)(kbase + (size_t)ss * 3072 + 1024);
  float k0v = (tid < 32) ? k0base[tid] : 0.f;

  for (int s0 = 0; s0 < t0 + 64; s0 += 32) {
    // ---- commit prefetched tile to LDS ----
    *(bf16x8*)&Kls[ss][dg * 8] = kv;
#pragma unroll
    for (int i2 = 0; i2 < 8; i2++) Vt[dg * 8 + i2][ss] = vv[i2];
    if (tid < 32) k0s[tid] = k0v;
    __syncthreads();

    // ---- prefetch NEXT tile (clamped re-read on last iter; latency overlaps below) ----
    const int s0n = (s0 + 32 < t0 + 64) ? s0 + 32 : s0;
    kv = *(const bf16x8*)(kbase + (size_t)(s0n + ss) * 3072);
    vv = *(const bf16x8*)(kbase + (size_t)(s0n + ss) * 3072 + 1024);
    if (tid < 32) k0v = k0base[s0n + tid];

    // ---- S = q @ K^T (two 16-col n-tiles) ----
    f32x4 sc[2];
    sc[0] = f32x4{0.f, 0.f, 0.f, 0.f};
    sc[1] = f32x4{0.f, 0.f, 0.f, 0.f};
#pragma unroll
    for (int nt = 0; nt < 2; nt++) {
      bf16x8 b0 = *(const bf16x8*)&Kls[nt * 16 + l16][quad * 8];
      bf16x8 b1 = *(const bf16x8*)&Kls[nt * 16 + l16][32 + quad * 8];
      sc[nt] = __builtin_amdgcn_mfma_f32_16x16x32_bf16(aq0, b0, sc[nt], 0, 0, 0);
      sc[nt] = __builtin_amdgcn_mfma_f32_16x16x32_bf16(aq1, b1, sc[nt], 0, 0, 0);
    }

    // ---- p = exp(-dis), causal-masked; exp(-s*ln w) == exp2(-s*log2 w) ----
#pragma unroll
    for (int nt = 0; nt < 2; nt++) {
      const float k0c = k0s[nt * 16 + l16];
      const int s = s0 + nt * 16 + l16;
#pragma unroll
      for (int r = 0; r < 4; r++) {
        const int t = tb + quad * 4 + r;
        float lor = sc[nt][r] - q0r[r] * k0c;
        float ratio = fminf(fmaxf(-lor * inv_kc, 1.f + 1e-6f), 1e18f);
        float wv = ratio + sqrtf(ratio * ratio - 1.f);
        float p = EXP2F(-sqkc * LOG2F(wv));
        p = (s <= t) ? p : 0.f;
        lrow[r] += p;
        Pl[(quad * 4 + r) * 36 + nt * 16 + l16] = (bf16)p;
      }
    }
    // wave-private LDS roundtrip: DS ops complete in order within a wave
    bf16x8 ap = *(const bf16x8*)&Pl[l16 * 36 + quad * 8];
#pragma unroll
    for (int dt = 0; dt < 4; dt++) {
      bf16x8 bv = *(const bf16x8*)&Vt[dt * 16 + l16][quad * 8];
      o[dt] = __builtin_amdgcn_mfma_f32_16x16x32_bf16(ap, bv, o[dt], 0, 0, 0);
    }
    __syncthreads();
  }

  // ---- one deferred l-reduction over the 16 l16 lanes, then write O ----
#pragma unroll
  for (int r = 0; r < 4; r++) {
#pragma unroll
    for (int off = 1; off <= 8; off <<= 1) lrow[r] += __shfl_xor(lrow[r], off);
  }
#pragma unroll
  for (int r = 0; r < 4; r++) {
    const float invl = 1.f / lrow[r];   // lrow >= 1 (diagonal term)
    const int t = tb + quad * 4 + r;
#pragma unroll
    for (int dt = 0; dt < 4; dt++) {
      float val = o[dt][r] * invl;
      outp[(size_t)(b * T_ + t) * C_ + h * 64 + dt * 16 + l16] = (bf16)val;
    }
  }
}

// ==============  SwiGLU in-place (bf16): uv[m][0..4096) = u * silu(v)  ==============
__global__ __launch_bounds__(256) void swiglu_kernel(bf16* __restrict__ uv) {
  const size_t gid = (size_t)blockIdx.x * 256 + threadIdx.x;
  const size_t e0 = gid * 4;
  const size_t m = e0 >> 12;      // / 4096
  const size_t j = e0 & 4095;
  bf16* up = uv + m * 8192 + j;
  bf16x4 u4 = *(const bf16x4*)up;
  bf16x4 v4 = *(const bf16x4*)(up + 4096);
  bf16x4 o;
#pragma unroll
  for (int i = 0; i < 4; i++) {
    float uu = (float)u4[i];
    float vvv = (float)v4[i];
    float vc = fminf(fmaxf(vvv, -80.f), 80.f);
    float sig = 1.f / (1.f + __expf(-vc));
    o[i] = (bf16)(uu * vvv * sig);
  }
  *(bf16x4*)up = o;
}

// =====================  host-side launch  =====================
extern "C" void kernel_launch(void* const* d_in, const int* in_sizes, int n_in,
                              void* d_out, int out_size, void* d_ws, size_t ws_size,
                              hipStream_t stream) {
  const float* x      = (const float*)d_in[0];
  const float* w_qkv  = (const float*)d_in[1];
  const float* w_out  = (const float*)d_in[2];
  const float* kcb    = (const float*)d_in[3];
  const float* w_uv   = (const float*)d_in[4];
  const float* b_uv   = (const float*)d_in[5];
  const float* w_mlp  = (const float*)d_in[6];
  const float* b_mlp  = (const float*)d_in[7];
  float* out = (float*)d_out;

  const size_t MB = 1024ull * 1024ull;
  char* w = (char*)d_ws;
  bf16*  wqkv_b  = (bf16*)(w + 0);          //  6 MB   [0,6)
  bf16*  wout_b  = (bf16*)(w + 6 * MB);     //  2 MB   [6,8)
  bf16*  wuv_b   = (bf16*)(w + 8 * MB);     // 16 MB   [8,24)
  bf16*  wmlp_b  = (bf16*)(w + 24 * MB);    //  8 MB   [24,32)
  bf16*  hbuf    = (bf16*)(w + 32 * MB);    //  8 MB   [32,40)
  bf16*  qkvbuf  = (bf16*)(w + 40 * MB);    // 24 MB   [40,64) dead after attn
  bf16*  attnbuf = (bf16*)(w + 64 * MB);    //  8 MB   [64,72) dead after step 5
  bf16*  uvbuf   = (bf16*)(w + 40 * MB);    // 64 MB   [40,104) over qkv+attn
  float* x2buf   = (float*)(w + 104 * MB);  // 16 MB   [104,120) fp32
  float* q0b     = (float*)(w + 120 * MB);               // 256 KB
  float* k0b     = (float*)(w + 120 * MB + 256 * 1024);  // 256 KB
  // total: 120.5 MB

  // 0) one-time weight casts fp32 -> bf16 (single fused launch; 4.19M quad-groups)
  cast_all_kernel<<<(786432 + 262144 + 2097152 + 1048576) / 256, 256, 0, stream>>>(
      w_qkv, w_out, w_uv, w_mlp, wqkv_b, wout_b, wuv_b, wmlp_b);

  // 1) h = rmsnorm(x)                                  fp32 -> bf16
  rmsnorm_kernel<<<M_, 256, 0, stream>>>(x, hbuf);
  // 2) qkv = h @ w_qkv^T                               bf16 -> bf16
  gemm_bt<0, bf16><<<dim3(M_ / 128, 3072 / 128), 256, 0, stream>>>(
      hbuf, wqkv_b, qkvbuf, nullptr, nullptr, M_, 3072, 1024, 1024);
  // 3) rotary(q,k) in-place + q0/k0
  rotary_kernel<<<(B_ * T_ * H_) / 4, 256, 0, stream>>>(qkvbuf, kcb, q0b, k0b);
  // 4) hyperbolic flash attention                      -> bf16
  attn_kernel<<<dim3(B_ * H_, 32), 256, 0, stream>>>(qkvbuf, q0b, k0b, kcb, attnbuf);
  // 5) x2 = x + attn @ w_out^T                         -> fp32
  gemm_bt<1, float><<<dim3(M_ / 128, 1024 / 128), 256, 0, stream>>>(
      attnbuf, wout_b, x2buf, nullptr, x, M_, 1024, 1024, 1024);
  // 6) h2 = rmsnorm(x2)                                fp32 -> bf16
  rmsnorm_kernel<<<M_, 256, 0, stream>>>(x2buf, hbuf);
  // 7) uv = h2 @ w_uv^T + b_uv                         -> bf16
  gemm_bt<2, bf16><<<dim3(M_ / 128, 8192 / 128), 256, 0, stream>>>(
      hbuf, wuv_b, uvbuf, b_uv, nullptr, M_, 8192, 1024, 1024);
  // 8) g = u * silu(v), in place over u-half (row stride 8192)
  swiglu_kernel<<<(M_ * 4096) / (4 * 256), 256, 0, stream>>>(uvbuf);
  // 9) out = x2 + g @ w_mlp^T + b_mlp                  -> fp32
  gemm_bt<3, float><<<dim3(M_ / 128, 1024 / 128), 256, 0, stream>>>(
      uvbuf, wmlp_b, out, b_mlp, x2buf, M_, 1024, 4096, 8192);
}

// Round 8
// 492.377 us; speedup vs baseline: 1.4054x; 1.0211x over previous
//
#include <hip/hip_runtime.h>
#include <cstdint>
#include <cmath>

typedef __bf16 bf16;
typedef __attribute__((ext_vector_type(8))) __bf16 bf16x8;
typedef __attribute__((ext_vector_type(4))) __bf16 bf16x4;
typedef __attribute__((ext_vector_type(4))) float f32x4;

constexpr int B_ = 2, T_ = 2048, C_ = 1024, H_ = 16, HD_ = 64;
constexpr int M_ = B_ * T_;   // 4096

// native 2^x and log2(x) (v_exp_f32 / v_log_f32)
#define EXP2F(x) __builtin_amdgcn_exp2f(x)
#define LOG2F(x) __builtin_amdgcn_logf(x)

// ---- async global->LDS, 16B per lane; LDS dest = wave-uniform base + lane*16 ----
__device__ __forceinline__ void gld16(const void* g, void* l) {
  __builtin_amdgcn_global_load_lds((const __attribute__((address_space(1))) void*)g,
                                   (__attribute__((address_space(3))) void*)l, 16, 0, 0);
}

// ============  fused weight cast: fp32 -> bf16 for all four weight tensors  ============
__global__ __launch_bounds__(256) void cast_all_kernel(const float* __restrict__ s0,
                                                       const float* __restrict__ s1,
                                                       const float* __restrict__ s2,
                                                       const float* __restrict__ s3,
                                                       bf16* __restrict__ d0,
                                                       bf16* __restrict__ d1,
                                                       bf16* __restrict__ d2,
                                                       bf16* __restrict__ d3) {
  size_t gid = (size_t)blockIdx.x * 256 + threadIdx.x;
  const float* src;
  bf16* dst;
  if (gid < 786432) { src = s0; dst = d0; }
  else if (gid < 786432 + 262144) { gid -= 786432; src = s1; dst = d1; }
  else if (gid < 786432 + 262144 + 2097152) { gid -= 786432 + 262144; src = s2; dst = d2; }
  else { gid -= 786432 + 262144 + 2097152; src = s3; dst = d3; }
  f32x4 v = *(const f32x4*)(src + gid * 4);
  bf16x4 o;
  o[0] = (bf16)v[0]; o[1] = (bf16)v[1]; o[2] = (bf16)v[2]; o[3] = (bf16)v[3];
  *(bf16x4*)(dst + gid * 4) = o;
}

// =============  GEMM: C = A @ Bw^T (+bias)(+residual), all-bf16 operands  =============
// BK=64 as TWO stacked [128][32] half-tiles (keeps global_load_lds lane-contiguous
// layout legal) -> barrier pairs per K halved vs BK=32; LDS 32 KB still above the
// 3-block/CU AGPR occupancy cap.
// MODE bit0: += R (fp32, stride N)   MODE bit1: += bias (fp32).  OutT: __bf16 or float.
template <int MODE, typename OutT>
__global__ __launch_bounds__(256) void gemm_bt(const bf16* __restrict__ A,
                                               const bf16* __restrict__ Bw,
                                               OutT* __restrict__ Cmat,
                                               const float* __restrict__ bias,
                                               const float* __restrict__ R,
                                               int M, int N, int K, int lda) {
  __shared__ __align__(16) bf16 Als[2][128 * 32];
  __shared__ __align__(16) bf16 Bls[2][128 * 32];
  const int tid  = threadIdx.x;
  const int wave = tid >> 6;
  const int lane = tid & 63;
  const int quad = lane >> 4;
  const int l16  = lane & 15;
  const int bm = blockIdx.x * 128;
  const int bn = blockIdx.y * 128;
  const int wm = (wave & 1) * 64;
  const int wn = (wave >> 1) * 64;
  const int srow   = lane >> 2;  // 0..15
  const int schunk = lane & 3;   // 0..3 (16B chunks of a 64B half-k-row)

  f32x4 acc[4][4];
#pragma unroll
  for (int i = 0; i < 4; i++)
#pragma unroll
    for (int j = 0; j < 4; j++) acc[i][j] = f32x4{0.f, 0.f, 0.f, 0.f};

  const bf16* Ag = A  + (size_t)(bm + wave * 32 + srow) * lda + schunk * 8;
  const bf16* Bg = Bw + (size_t)(bn + wave * 32 + srow) * K   + schunk * 8;
  bf16* AlsW0 = &Als[0][(wave * 32) * 32];
  bf16* AlsW1 = &Als[1][(wave * 32) * 32];
  bf16* BlsW0 = &Bls[0][(wave * 32) * 32];
  bf16* BlsW1 = &Bls[1][(wave * 32) * 32];

  for (int k0 = 0; k0 < K; k0 += 64) {
    gld16(Ag + k0,                         AlsW0);
    gld16(Ag + k0 + (size_t)16 * lda,      AlsW0 + 16 * 32);
    gld16(Ag + k0 + 32,                    AlsW1);
    gld16(Ag + k0 + 32 + (size_t)16 * lda, AlsW1 + 16 * 32);
    gld16(Bg + k0,                         BlsW0);
    gld16(Bg + k0 + (size_t)16 * K,        BlsW0 + 16 * 32);
    gld16(Bg + k0 + 32,                    BlsW1);
    gld16(Bg + k0 + 32 + (size_t)16 * K,   BlsW1 + 16 * 32);
    __syncthreads();   // drains vmcnt before barrier

#pragma unroll
    for (int hh = 0; hh < 2; hh++) {
      bf16x8 af[4], bfr[4];
#pragma unroll
      for (int mt = 0; mt < 4; mt++)
        af[mt] = *(const bf16x8*)&Als[hh][(wm + mt * 16 + l16) * 32 + quad * 8];
#pragma unroll
      for (int nt = 0; nt < 4; nt++)
        bfr[nt] = *(const bf16x8*)&Bls[hh][(wn + nt * 16 + l16) * 32 + quad * 8];
#pragma unroll
      for (int mt = 0; mt < 4; mt++)
#pragma unroll
        for (int nt = 0; nt < 4; nt++)
          acc[mt][nt] = __builtin_amdgcn_mfma_f32_16x16x32_bf16(af[mt], bfr[nt], acc[mt][nt], 0, 0, 0);
    }
    __syncthreads();
  }

  // epilogue: D row = wm+mt*16+quad*4+r, col = wn+nt*16+l16
#pragma unroll
  for (int mt = 0; mt < 4; mt++) {
    const int row = bm + wm + mt * 16 + quad * 4;
#pragma unroll
    for (int nt = 0; nt < 4; nt++) {
      const int col = bn + wn + nt * 16 + l16;
      float bval = 0.f;
      if (MODE & 2) bval = bias[col];
#pragma unroll
      for (int r = 0; r < 4; r++) {
        float v = acc[mt][nt][r] + bval;
        if (MODE & 1) v += R[(size_t)(row + r) * N + col];
        Cmat[(size_t)(row + r) * N + col] = (OutT)v;
      }
    }
  }
}

// =====================  RMSNorm: fp32 in -> bf16 out (row = 1024)  =====================
__global__ __launch_bounds__(256) void rmsnorm_kernel(const float* __restrict__ X,
                                                      bf16* __restrict__ O) {
  const int row = blockIdx.x;
  const int tid = threadIdx.x;
  const int wave = tid >> 6;
  f32x4 v = *(const f32x4*)(X + (size_t)row * C_ + tid * 4);
  float s = v[0] * v[0] + v[1] * v[1] + v[2] * v[2] + v[3] * v[3];
#pragma unroll
  for (int off = 32; off >= 1; off >>= 1) s += __shfl_xor(s, off);
  __shared__ float wsum[4];
  __shared__ float scale_sh;
  if ((tid & 63) == 0) wsum[wave] = s;
  __syncthreads();
  if (tid == 0)
    scale_sh = rsqrtf((wsum[0] + wsum[1] + wsum[2] + wsum[3]) * (1.f / (float)C_) + 1e-6f);
  __syncthreads();
  const float sc = scale_sh;
  bf16x4 o;
  o[0] = (bf16)(v[0] * sc); o[1] = (bf16)(v[1] * sc);
  o[2] = (bf16)(v[2] * sc); o[3] = (bf16)(v[3] * sc);
  *(bf16x4*)(O + (size_t)row * C_ + tid * 4) = o;
}

// ==========  Rotary on q,k (bf16, in-place) + q0/k0 = sqrt(kc + |.|^2)  ==========
__global__ __launch_bounds__(256) void rotary_kernel(bf16* __restrict__ qkv,
                                                     const float* __restrict__ kcb,
                                                     float* __restrict__ q0b,
                                                     float* __restrict__ k0b) {
  const int wid  = blockIdx.x * 4 + (threadIdx.x >> 6);  // one wave per (b,t,h)
  const int lane = threadIdx.x & 63;
  const int b = wid >> 15;          // T_*H_ = 32768
  const int rem = wid & 32767;
  const int t = rem >> 4;
  const int h = rem & 15;
  const int i = lane & 31;
  const float invf = expf(-((float)i / 32.f) * 9.210340371976184f);  // 10000^(-i/32)
  const float ang = (float)t * invf;
  const float cx = cosf(ang), sx = sinf(ang);
  const float kc = kcb[h];
  bf16* qp = qkv + (size_t)(b * T_ + t) * 3072 + h * 64;

#pragma unroll
  for (int which = 0; which < 2; which++) {
    bf16* p = qp + which * 1024;   // q then k
    float x1 = (float)p[i];
    float x2 = (float)p[i + 32];
    float o = (lane < 32) ? (x1 * cx + x2 * sx) : (x2 * cx - x1 * sx);
    float ss = o * o;
#pragma unroll
    for (int off = 32; off >= 1; off >>= 1) ss += __shfl_xor(ss, off);
    p[lane] = (bf16)o;
    if (lane == 0) {
      float* dst = which == 0 ? q0b : k0b;
      dst[(size_t)(b * H_ + h) * T_ + t] = sqrtf(kc + ss);
    }
  }
}

// =====================  Hyperbolic flash attention (v5)  =====================
// v4 + 64-WIDE S-TILES: one barrier pair per 64 s-cols (was two), 16 independent
// score chains per iter (2x trans ILP), 8 S-MFMA + 8 PV-MFMA per iter.
// Register prefetch of next tile unchanged. grid (B*H, 32), heaviest-first (LPT).
// s-range per block = (ty+1)*64: always a multiple of 64.
__global__ __launch_bounds__(256) void attn_kernel(const bf16* __restrict__ qkv,
                                                   const float* __restrict__ q0b,
                                                   const float* __restrict__ k0b,
                                                   const float* __restrict__ kcb,
                                                   bf16* __restrict__ outp) {
  __shared__ __align__(16) bf16 Kls[64][72];     // K tile [s][d]
  __shared__ __align__(16) bf16 Vt[64][68];      // V^T [d][s]; 34-dw stride: 4-way wr
  __shared__ __align__(16) bf16 Pls[4][16 * 68]; // per-wave P; 34-dw stride: rd-free
  __shared__ float k0s[64];

  const int tid = threadIdx.x;
  const int wave = tid >> 6, lane = tid & 63;
  const int quad = lane >> 4, l16 = lane & 15;
  const int bh = blockIdx.x;
  const int b = bh >> 4, h = bh & 15;

  const float kc = kcb[h];
  const float inv_kc = 1.f / kc;
  const float sqkc = sqrtf(kc);
  const int ss = tid >> 3, dg = tid & 7;   // ss 0..31, dg 0..7
  bf16* Pl = Pls[wave];
  const float* q0base = q0b + (size_t)(b * H_ + h) * T_;
  const float* k0base = k0b + (size_t)(b * H_ + h) * T_;

  const int ty = 31 - (int)blockIdx.y;   // heaviest blocks dispatch first
  const int t0 = ty * 64;
  const int tb = t0 + wave * 16;

  // q A-frags: A[m=l16][k=quad*8+j]
  const bf16* qrow = qkv + (size_t)(b * T_ + tb + l16) * 3072 + h * 64;
  bf16x8 aq0 = *(const bf16x8*)(qrow + quad * 8);
  bf16x8 aq1 = *(const bf16x8*)(qrow + 32 + quad * 8);
  float q0r[4];
#pragma unroll
  for (int r = 0; r < 4; r++) q0r[r] = q0base[tb + quad * 4 + r];

  f32x4 o[4];
#pragma unroll
  for (int dt = 0; dt < 4; dt++) o[dt] = f32x4{0.f, 0.f, 0.f, 0.f};
  float lrow[4] = {0.f, 0.f, 0.f, 0.f};   // per-lane partial row sums

  // ---- prologue: prefetch tile 0 (64 s-rows) into registers ----
  const bf16* kbase = qkv + (size_t)b * T_ * 3072 + 1024 + h * 64 + dg * 8;
  bf16x8 kv0 = *(const bf16x8*)(kbase + (size_t)ss * 3072);
  bf16x8 vv0 = *(const bf16x8*)(kbase + (size_t)ss * 3072 + 1024);
  bf16x8 kv1 = *(const bf16x8*)(kbase + (size_t)(32 + ss) * 3072);
  bf16x8 vv1 = *(const bf16x8*)(kbase + (size_t)(32 + ss) * 3072 + 1024);
  float k0v = (tid < 64) ? k0base[tid] : 0.f;

  for (int s0 = 0; s0 < t0 + 64; s0 += 64) {
    // ---- commit prefetched 64-row tile to LDS ----
    *(bf16x8*)&Kls[ss][dg * 8]      = kv0;
    *(bf16x8*)&Kls[32 + ss][dg * 8] = kv1;
#pragma unroll
    for (int i2 = 0; i2 < 8; i2++) {
      Vt[dg * 8 + i2][ss]      = vv0[i2];
      Vt[dg * 8 + i2][32 + ss] = vv1[i2];
    }
    if (tid < 64) k0s[tid] = k0v;
    __syncthreads();

    // ---- prefetch NEXT tile (clamped; latency overlaps compute below) ----
    const int s0n = (s0 + 64 < t0 + 64) ? s0 + 64 : s0;
    kv0 = *(const bf16x8*)(kbase + (size_t)(s0n + ss) * 3072);
    vv0 = *(const bf16x8*)(kbase + (size_t)(s0n + ss) * 3072 + 1024);
    kv1 = *(const bf16x8*)(kbase + (size_t)(s0n + 32 + ss) * 3072);
    vv1 = *(const bf16x8*)(kbase + (size_t)(s0n + 32 + ss) * 3072 + 1024);
    if (tid < 64) k0v = k0base[s0n + tid];

    // ---- S = q @ K^T (four 16-col n-tiles) ----
    f32x4 sc[4];
#pragma unroll
    for (int nt = 0; nt < 4; nt++) {
      sc[nt] = f32x4{0.f, 0.f, 0.f, 0.f};
      bf16x8 b0 = *(const bf16x8*)&Kls[nt * 16 + l16][quad * 8];
      bf16x8 b1 = *(const bf16x8*)&Kls[nt * 16 + l16][32 + quad * 8];
      sc[nt] = __builtin_amdgcn_mfma_f32_16x16x32_bf16(aq0, b0, sc[nt], 0, 0, 0);
      sc[nt] = __builtin_amdgcn_mfma_f32_16x16x32_bf16(aq1, b1, sc[nt], 0, 0, 0);
    }

    // ---- p = exp(-dis): 16 independent chains (trans-pipe ILP) ----
#pragma unroll
    for (int nt = 0; nt < 4; nt++) {
      const float k0c = k0s[nt * 16 + l16];
      const int s = s0 + nt * 16 + l16;
#pragma unroll
      for (int r = 0; r < 4; r++) {
        const int t = tb + quad * 4 + r;
        float lor = sc[nt][r] - q0r[r] * k0c;
        float ratio = fmaxf(-lor * inv_kc, 1.f + 1e-6f);
        float wv = ratio + sqrtf(ratio * ratio - 1.f);  // inf-safe: p -> 0
        float p = EXP2F(-sqkc * LOG2F(wv));
        p = (s <= t) ? p : 0.f;
        lrow[r] += p;
        Pl[(quad * 4 + r) * 68 + nt * 16 + l16] = (bf16)p;
      }
    }
    // wave-private LDS roundtrip: DS ops complete in order within a wave
    bf16x8 ap0 = *(const bf16x8*)&Pl[l16 * 68 + quad * 8];
    bf16x8 ap1 = *(const bf16x8*)&Pl[l16 * 68 + 32 + quad * 8];
#pragma unroll
    for (int dt = 0; dt < 4; dt++) {
      bf16x8 bv0 = *(const bf16x8*)&Vt[dt * 16 + l16][quad * 8];
      bf16x8 bv1 = *(const bf16x8*)&Vt[dt * 16 + l16][32 + quad * 8];
      o[dt] = __builtin_amdgcn_mfma_f32_16x16x32_bf16(ap0, bv0, o[dt], 0, 0, 0);
      o[dt] = __builtin_amdgcn_mfma_f32_16x16x32_bf16(ap1, bv1, o[dt], 0, 0, 0);
    }
    __syncthreads();
  }

  // ---- one deferred l-reduction over the 16 l16 lanes, then write O ----
#pragma unroll
  for (int r = 0; r < 4; r++) {
#pragma unroll
    for (int off = 1; off <= 8; off <<= 1) lrow[r] += __shfl_xor(lrow[r], off);
  }
#pragma unroll
  for (int r = 0; r < 4; r++) {
    const float invl = 1.f / lrow[r];   // lrow >= 1 (diagonal term)
    const int t = tb + quad * 4 + r;
#pragma unroll
    for (int dt = 0; dt < 4; dt++) {
      float val = o[dt][r] * invl;
      outp[(size_t)(b * T_ + t) * C_ + h * 64 + dt * 16 + l16] = (bf16)val;
    }
  }
}

// ==============  SwiGLU in-place (bf16): uv[m][0..4096) = u * silu(v)  ==============
__global__ __launch_bounds__(256) void swiglu_kernel(bf16* __restrict__ uv) {
  const size_t gid = (size_t)blockIdx.x * 256 + threadIdx.x;
  const size_t e0 = gid * 4;
  const size_t m = e0 >> 12;      // / 4096
  const size_t j = e0 & 4095;
  bf16* up = uv + m * 8192 + j;
  bf16x4 u4 = *(const bf16x4*)up;
  bf16x4 v4 = *(const bf16x4*)(up + 4096);
  bf16x4 o;
#pragma unroll
  for (int i = 0; i < 4; i++) {
    float uu = (float)u4[i];
    float vvv = (float)v4[i];
    float vc = fminf(fmaxf(vvv, -80.f), 80.f);
    float sig = 1.f / (1.f + __expf(-vc));
    o[i] = (bf16)(uu * vvv * sig);
  }
  *(bf16x4*)up = o;
}

// =====================  host-side launch  =====================
extern "C" void kernel_launch(void* const* d_in, const int* in_sizes, int n_in,
                              void* d_out, int out_size, void* d_ws, size_t ws_size,
                              hipStream_t stream) {
  const float* x      = (const float*)d_in[0];
  const float* w_qkv  = (const float*)d_in[1];
  const float* w_out  = (const float*)d_in[2];
  const float* kcb    = (const float*)d_in[3];
  const float* w_uv   = (const float*)d_in[4];
  const float* b_uv   = (const float*)d_in[5];
  const float* w_mlp  = (const float*)d_in[6];
  const float* b_mlp  = (const float*)d_in[7];
  float* out = (float*)d_out;

  const size_t MB = 1024ull * 1024ull;
  char* w = (char*)d_ws;
  bf16*  wqkv_b  = (bf16*)(w + 0);          //  6 MB   [0,6)
  bf16*  wout_b  = (bf16*)(w + 6 * MB);     //  2 MB   [6,8)
  bf16*  wuv_b   = (bf16*)(w + 8 * MB);     // 16 MB   [8,24)
  bf16*  wmlp_b  = (bf16*)(w + 24 * MB);    //  8 MB   [24,32)
  bf16*  hbuf    = (bf16*)(w + 32 * MB);    //  8 MB   [32,40)
  bf16*  qkvbuf  = (bf16*)(w + 40 * MB);    // 24 MB   [40,64) dead after attn
  bf16*  attnbuf = (bf16*)(w + 64 * MB);    //  8 MB   [64,72) dead after step 5
  bf16*  uvbuf   = (bf16*)(w + 40 * MB);    // 64 MB   [40,104) over qkv+attn
  float* x2buf   = (float*)(w + 104 * MB);  // 16 MB   [104,120) fp32
  float* q0b     = (float*)(w + 120 * MB);               // 256 KB
  float* k0b     = (float*)(w + 120 * MB + 256 * 1024);  // 256 KB
  // total: 120.5 MB

  // 0) one-time weight casts fp32 -> bf16 (single fused launch)
  cast_all_kernel<<<(786432 + 262144 + 2097152 + 1048576) / 256, 256, 0, stream>>>(
      w_qkv, w_out, w_uv, w_mlp, wqkv_b, wout_b, wuv_b, wmlp_b);

  // 1) h = rmsnorm(x)                                  fp32 -> bf16
  rmsnorm_kernel<<<M_, 256, 0, stream>>>(x, hbuf);
  // 2) qkv = h @ w_qkv^T                               bf16 -> bf16
  gemm_bt<0, bf16><<<dim3(M_ / 128, 3072 / 128), 256, 0, stream>>>(
      hbuf, wqkv_b, qkvbuf, nullptr, nullptr, M_, 3072, 1024, 1024);
  // 3) rotary(q,k) in-place + q0/k0
  rotary_kernel<<<(B_ * T_ * H_) / 4, 256, 0, stream>>>(qkvbuf, kcb, q0b, k0b);
  // 4) hyperbolic flash attention                      -> bf16
  attn_kernel<<<dim3(B_ * H_, 32), 256, 0, stream>>>(qkvbuf, q0b, k0b, kcb, attnbuf);
  // 5) x2 = x + attn @ w_out^T                         -> fp32
  gemm_bt<1, float><<<dim3(M_ / 128, 1024 / 128), 256, 0, stream>>>(
      attnbuf, wout_b, x2buf, nullptr, x, M_, 1024, 1024, 1024);
  // 6) h2 = rmsnorm(x2)                                fp32 -> bf16
  rmsnorm_kernel<<<M_, 256, 0, stream>>>(x2buf, hbuf);
  // 7) uv = h2 @ w_uv^T + b_uv                         -> bf16
  gemm_bt<2, bf16><<<dim3(M_ / 128, 8192 / 128), 256, 0, stream>>>(
      hbuf, wuv_b, uvbuf, b_uv, nullptr, M_, 8192, 1024, 1024);
  // 8) g = u * silu(v), in place over u-half (row stride 8192)
  swiglu_kernel<<<(M_ * 4096) / (4 * 256), 256, 0, stream>>>(uvbuf);
  // 9) out = x2 + g @ w_mlp^T + b_mlp                  -> fp32
  gemm_bt<3, float><<<dim3(M_ / 128, 1024 / 128), 256, 0, stream>>>(
      uvbuf, wmlp_b, out, b_mlp, x2buf, M_, 1024, 4096, 8192);
}

// Round 9
// 456.013 us; speedup vs baseline: 1.5175x; 1.0797x over previous
//
#include <hip/hip_runtime.h>
#include <cstdint>
#include <cmath>

typedef __bf16 bf16;
typedef __attribute__((ext_vector_type(8))) __bf16 bf16x8;
typedef __attribute__((ext_vector_type(4))) __bf16 bf16x4;
typedef __attribute__((ext_vector_type(4))) float f32x4;

constexpr int B_ = 2, T_ = 2048, C_ = 1024, H_ = 16, HD_ = 64;
constexpr int M_ = B_ * T_;   // 4096

// native 2^x, log2(x), sqrt, rcp (v_exp_f32 / v_log_f32 / v_sqrt_f32 / v_rcp_f32)
#define EXP2F(x) __builtin_amdgcn_exp2f(x)
#define LOG2F(x) __builtin_amdgcn_logf(x)
#define SQRTF(x) __builtin_amdgcn_sqrtf(x)
#define RCPF(x)  __builtin_amdgcn_rcpf(x)

// ---- async global->LDS, 16B per lane; LDS dest = wave-uniform base + lane*16 ----
__device__ __forceinline__ void gld16(const void* g, void* l) {
  __builtin_amdgcn_global_load_lds((const __attribute__((address_space(1))) void*)g,
                                   (__attribute__((address_space(3))) void*)l, 16, 0, 0);
}

// ============  fused weight cast: fp32 -> bf16 for all four weight tensors  ============
__global__ __launch_bounds__(256) void cast_all_kernel(const float* __restrict__ s0,
                                                       const float* __restrict__ s1,
                                                       const float* __restrict__ s2,
                                                       const float* __restrict__ s3,
                                                       bf16* __restrict__ d0,
                                                       bf16* __restrict__ d1,
                                                       bf16* __restrict__ d2,
                                                       bf16* __restrict__ d3) {
  size_t gid = (size_t)blockIdx.x * 256 + threadIdx.x;
  const float* src;
  bf16* dst;
  if (gid < 786432) { src = s0; dst = d0; }
  else if (gid < 786432 + 262144) { gid -= 786432; src = s1; dst = d1; }
  else if (gid < 786432 + 262144 + 2097152) { gid -= 786432 + 262144; src = s2; dst = d2; }
  else { gid -= 786432 + 262144 + 2097152; src = s3; dst = d3; }
  f32x4 v = *(const f32x4*)(src + gid * 4);
  bf16x4 o;
  o[0] = (bf16)v[0]; o[1] = (bf16)v[1]; o[2] = (bf16)v[2]; o[3] = (bf16)v[3];
  *(bf16x4*)(dst + gid * 4) = o;
}

// =============  GEMM: C = A @ Bw^T (+bias)(+residual), all-bf16 operands  =============
// BK=64 as two stacked [128][32] half-tiles; one barrier pair per 64 K.
// MODE bit0: += R (fp32, stride N)   MODE bit1: += bias (fp32).  OutT: __bf16 or float.
template <int MODE, typename OutT>
__global__ __launch_bounds__(256) void gemm_bt(const bf16* __restrict__ A,
                                               const bf16* __restrict__ Bw,
                                               OutT* __restrict__ Cmat,
                                               const float* __restrict__ bias,
                                               const float* __restrict__ R,
                                               int M, int N, int K, int lda) {
  __shared__ __align__(16) bf16 Als[2][128 * 32];
  __shared__ __align__(16) bf16 Bls[2][128 * 32];
  const int tid  = threadIdx.x;
  const int wave = tid >> 6;
  const int lane = tid & 63;
  const int quad = lane >> 4;
  const int l16  = lane & 15;
  const int bm = blockIdx.x * 128;
  const int bn = blockIdx.y * 128;
  const int wm = (wave & 1) * 64;
  const int wn = (wave >> 1) * 64;
  const int srow   = lane >> 2;  // 0..15
  const int schunk = lane & 3;   // 0..3 (16B chunks of a 64B half-k-row)

  f32x4 acc[4][4];
#pragma unroll
  for (int i = 0; i < 4; i++)
#pragma unroll
    for (int j = 0; j < 4; j++) acc[i][j] = f32x4{0.f, 0.f, 0.f, 0.f};

  const bf16* Ag = A  + (size_t)(bm + wave * 32 + srow) * lda + schunk * 8;
  const bf16* Bg = Bw + (size_t)(bn + wave * 32 + srow) * K   + schunk * 8;
  bf16* AlsW0 = &Als[0][(wave * 32) * 32];
  bf16* AlsW1 = &Als[1][(wave * 32) * 32];
  bf16* BlsW0 = &Bls[0][(wave * 32) * 32];
  bf16* BlsW1 = &Bls[1][(wave * 32) * 32];

  for (int k0 = 0; k0 < K; k0 += 64) {
    gld16(Ag + k0,                         AlsW0);
    gld16(Ag + k0 + (size_t)16 * lda,      AlsW0 + 16 * 32);
    gld16(Ag + k0 + 32,                    AlsW1);
    gld16(Ag + k0 + 32 + (size_t)16 * lda, AlsW1 + 16 * 32);
    gld16(Bg + k0,                         BlsW0);
    gld16(Bg + k0 + (size_t)16 * K,        BlsW0 + 16 * 32);
    gld16(Bg + k0 + 32,                    BlsW1);
    gld16(Bg + k0 + 32 + (size_t)16 * K,   BlsW1 + 16 * 32);
    __syncthreads();   // drains vmcnt before barrier

#pragma unroll
    for (int hh = 0; hh < 2; hh++) {
      bf16x8 af[4], bfr[4];
#pragma unroll
      for (int mt = 0; mt < 4; mt++)
        af[mt] = *(const bf16x8*)&Als[hh][(wm + mt * 16 + l16) * 32 + quad * 8];
#pragma unroll
      for (int nt = 0; nt < 4; nt++)
        bfr[nt] = *(const bf16x8*)&Bls[hh][(wn + nt * 16 + l16) * 32 + quad * 8];
#pragma unroll
      for (int mt = 0; mt < 4; mt++)
#pragma unroll
        for (int nt = 0; nt < 4; nt++)
          acc[mt][nt] = __builtin_amdgcn_mfma_f32_16x16x32_bf16(af[mt], bfr[nt], acc[mt][nt], 0, 0, 0);
    }
    __syncthreads();
  }

  // epilogue: D row = wm+mt*16+quad*4+r, col = wn+nt*16+l16
#pragma unroll
  for (int mt = 0; mt < 4; mt++) {
    const int row = bm + wm + mt * 16 + quad * 4;
#pragma unroll
    for (int nt = 0; nt < 4; nt++) {
      const int col = bn + wn + nt * 16 + l16;
      float bval = 0.f;
      if (MODE & 2) bval = bias[col];
#pragma unroll
      for (int r = 0; r < 4; r++) {
        float v = acc[mt][nt][r] + bval;
        if (MODE & 1) v += R[(size_t)(row + r) * N + col];
        Cmat[(size_t)(row + r) * N + col] = (OutT)v;
      }
    }
  }
}

// =====================  RMSNorm: fp32 in -> bf16 out (row = 1024)  =====================
__global__ __launch_bounds__(256) void rmsnorm_kernel(const float* __restrict__ X,
                                                      bf16* __restrict__ O) {
  const int row = blockIdx.x;
  const int tid = threadIdx.x;
  const int wave = tid >> 6;
  f32x4 v = *(const f32x4*)(X + (size_t)row * C_ + tid * 4);
  float s = v[0] * v[0] + v[1] * v[1] + v[2] * v[2] + v[3] * v[3];
#pragma unroll
  for (int off = 32; off >= 1; off >>= 1) s += __shfl_xor(s, off);
  __shared__ float wsum[4];
  __shared__ float scale_sh;
  if ((tid & 63) == 0) wsum[wave] = s;
  __syncthreads();
  if (tid == 0)
    scale_sh = rsqrtf((wsum[0] + wsum[1] + wsum[2] + wsum[3]) * (1.f / (float)C_) + 1e-6f);
  __syncthreads();
  const float sc = scale_sh;
  bf16x4 o;
  o[0] = (bf16)(v[0] * sc); o[1] = (bf16)(v[1] * sc);
  o[2] = (bf16)(v[2] * sc); o[3] = (bf16)(v[3] * sc);
  *(bf16x4*)(O + (size_t)row * C_ + tid * 4) = o;
}

// ==========  Rotary on q,k (bf16, in-place) + q0/k0 = sqrt(kc + |.|^2)  ==========
__global__ __launch_bounds__(256) void rotary_kernel(bf16* __restrict__ qkv,
                                                     const float* __restrict__ kcb,
                                                     float* __restrict__ q0b,
                                                     float* __restrict__ k0b) {
  const int wid  = blockIdx.x * 4 + (threadIdx.x >> 6);  // one wave per (b,t,h)
  const int lane = threadIdx.x & 63;
  const int b = wid >> 15;          // T_*H_ = 32768
  const int rem = wid & 32767;
  const int t = rem >> 4;
  const int h = rem & 15;
  const int i = lane & 31;
  const float invf = expf(-((float)i / 32.f) * 9.210340371976184f);  // 10000^(-i/32)
  const float ang = (float)t * invf;
  const float cx = cosf(ang), sx = sinf(ang);
  const float kc = kcb[h];
  bf16* qp = qkv + (size_t)(b * T_ + t) * 3072 + h * 64;

#pragma unroll
  for (int which = 0; which < 2; which++) {
    bf16* p = qp + which * 1024;   // q then k
    float x1 = (float)p[i];
    float x2 = (float)p[i + 32];
    float o = (lane < 32) ? (x1 * cx + x2 * sx) : (x2 * cx - x1 * sx);
    float ss = o * o;
#pragma unroll
    for (int off = 32; off >= 1; off >>= 1) ss += __shfl_xor(ss, off);
    p[lane] = (bf16)o;
    if (lane == 0) {
      float* dst = which == 0 ? q0b : k0b;
      dst[(size_t)(b * H_ + h) * T_ + t] = SQRTF(kc + ss);
    }
  }
}

// =====================  Hyperbolic flash attention (v6)  =====================
// v5 + LDS DOUBLE-BUFFER of K/V/k0 -> ONE barrier per 64-tile (was two); raw
// v_sqrt/v_rcp builtins; P roundtrip through a 16x36 per-wave buffer in two
// 32-col chunks (wave-private, DS in-order). LDS = 40960 B exactly -> 4 blk/CU.
// grid (B*H, 32), heaviest-first (LPT). Scores in (0,1], row-sum >= 1: no online max.
__global__ __launch_bounds__(256) void attn_kernel(const bf16* __restrict__ qkv,
                                                   const float* __restrict__ q0b,
                                                   const float* __restrict__ k0b,
                                                   const float* __restrict__ kcb,
                                                   bf16* __restrict__ outp) {
  __shared__ __align__(16) bf16 Kls[2][64][72];  // K tile [s][d]; 36-dw stride (b128-aligned)
  __shared__ __align__(16) bf16 Vt[2][64][68];   // V^T [d][s]; 34-dw stride
  __shared__ __align__(16) bf16 Pls[4][16 * 36]; // per-wave P chunk buffer (32 cols + pad)
  __shared__ float k0s[2][64];

  const int tid = threadIdx.x;
  const int wave = tid >> 6, lane = tid & 63;
  const int quad = lane >> 4, l16 = lane & 15;
  const int bh = blockIdx.x;
  const int b = bh >> 4, h = bh & 15;

  const float kc = kcb[h];
  const float inv_kc = 1.f / kc;
  const float sqkc = SQRTF(kc);
  const int ss = tid >> 3, dg = tid & 7;   // ss 0..31, dg 0..7
  bf16* Pl = Pls[wave];
  const float* q0base = q0b + (size_t)(b * H_ + h) * T_;
  const float* k0base = k0b + (size_t)(b * H_ + h) * T_;

  const int ty = 31 - (int)blockIdx.y;   // heaviest blocks dispatch first
  const int t0 = ty * 64;
  const int tb = t0 + wave * 16;
  const int nIter = ty + 1;

  // q A-frags: A[m=l16][k=quad*8+j]
  const bf16* qrow = qkv + (size_t)(b * T_ + tb + l16) * 3072 + h * 64;
  bf16x8 aq0 = *(const bf16x8*)(qrow + quad * 8);
  bf16x8 aq1 = *(const bf16x8*)(qrow + 32 + quad * 8);
  float q0r[4];
#pragma unroll
  for (int r = 0; r < 4; r++) q0r[r] = q0base[tb + quad * 4 + r];

  f32x4 o[4];
#pragma unroll
  for (int dt = 0; dt < 4; dt++) o[dt] = f32x4{0.f, 0.f, 0.f, 0.f};
  float lrow[4] = {0.f, 0.f, 0.f, 0.f};   // per-lane partial row sums

  // ---- prologue: prefetch tile 0 (64 s-rows) into registers ----
  const bf16* kbase = qkv + (size_t)b * T_ * 3072 + 1024 + h * 64 + dg * 8;
  bf16x8 kv0 = *(const bf16x8*)(kbase + (size_t)ss * 3072);
  bf16x8 vv0 = *(const bf16x8*)(kbase + (size_t)ss * 3072 + 1024);
  bf16x8 kv1 = *(const bf16x8*)(kbase + (size_t)(32 + ss) * 3072);
  bf16x8 vv1 = *(const bf16x8*)(kbase + (size_t)(32 + ss) * 3072 + 1024);
  float k0v = (tid < 64) ? k0base[tid] : 0.f;

  for (int it = 0; it < nIter; ++it) {
    const int s0 = it * 64;
    const int buf = it & 1;
    // ---- commit prefetched tile to LDS buffer `buf` (single barrier per iter:
    // buf was last READ in iter it-2, fenced by the barrier of iter it-1) ----
    *(bf16x8*)&Kls[buf][ss][dg * 8]      = kv0;
    *(bf16x8*)&Kls[buf][32 + ss][dg * 8] = kv1;
#pragma unroll
    for (int i2 = 0; i2 < 8; i2++) {
      Vt[buf][dg * 8 + i2][ss]      = vv0[i2];
      Vt[buf][dg * 8 + i2][32 + ss] = vv1[i2];
    }
    if (tid < 64) k0s[buf][tid] = k0v;
    __syncthreads();

    // ---- prefetch NEXT tile (clamped; latency overlaps compute below) ----
    const int s0n = (it + 1 < nIter) ? s0 + 64 : s0;
    kv0 = *(const bf16x8*)(kbase + (size_t)(s0n + ss) * 3072);
    vv0 = *(const bf16x8*)(kbase + (size_t)(s0n + ss) * 3072 + 1024);
    kv1 = *(const bf16x8*)(kbase + (size_t)(s0n + 32 + ss) * 3072);
    vv1 = *(const bf16x8*)(kbase + (size_t)(s0n + 32 + ss) * 3072 + 1024);
    if (tid < 64) k0v = k0base[s0n + tid];

    // ---- S = q @ K^T (four 16-col n-tiles) ----
    f32x4 sc[4];
#pragma unroll
    for (int nt = 0; nt < 4; nt++) {
      sc[nt] = f32x4{0.f, 0.f, 0.f, 0.f};
      bf16x8 b0 = *(const bf16x8*)&Kls[buf][nt * 16 + l16][quad * 8];
      bf16x8 b1 = *(const bf16x8*)&Kls[buf][nt * 16 + l16][32 + quad * 8];
      sc[nt] = __builtin_amdgcn_mfma_f32_16x16x32_bf16(aq0, b0, sc[nt], 0, 0, 0);
      sc[nt] = __builtin_amdgcn_mfma_f32_16x16x32_bf16(aq1, b1, sc[nt], 0, 0, 0);
    }

    // ---- p = exp(-dis) in two 32-col chunks; P roundtrip per chunk ----
    bf16x8 ap[2];
#pragma unroll
    for (int ck = 0; ck < 2; ck++) {
#pragma unroll
      for (int ntl = 0; ntl < 2; ntl++) {
        const int nt = ck * 2 + ntl;
        const float k0c = k0s[buf][nt * 16 + l16];
        const int s = s0 + nt * 16 + l16;
#pragma unroll
        for (int r = 0; r < 4; r++) {
          const int t = tb + quad * 4 + r;
          float lor = sc[nt][r] - q0r[r] * k0c;
          float ratio = fmaxf(-lor * inv_kc, 1.f + 1e-6f);
          float wv = ratio + SQRTF(ratio * ratio - 1.f);
          float p = EXP2F(-sqkc * LOG2F(wv));
          p = (s <= t) ? p : 0.f;
          lrow[r] += p;
          Pl[(quad * 4 + r) * 36 + ntl * 16 + l16] = (bf16)p;
        }
      }
      // wave-private read-back (DS in-order within wave; buffer reused next chunk)
      ap[ck] = *(const bf16x8*)&Pl[l16 * 36 + quad * 8];
    }
#pragma unroll
    for (int dt = 0; dt < 4; dt++) {
      bf16x8 bv0 = *(const bf16x8*)&Vt[buf][dt * 16 + l16][quad * 8];
      bf16x8 bv1 = *(const bf16x8*)&Vt[buf][dt * 16 + l16][32 + quad * 8];
      o[dt] = __builtin_amdgcn_mfma_f32_16x16x32_bf16(ap[0], bv0, o[dt], 0, 0, 0);
      o[dt] = __builtin_amdgcn_mfma_f32_16x16x32_bf16(ap[1], bv1, o[dt], 0, 0, 0);
    }
    // no second barrier: next iter writes the OTHER buffer
  }

  // ---- one deferred l-reduction over the 16 l16 lanes, then write O ----
#pragma unroll
  for (int r = 0; r < 4; r++) {
#pragma unroll
    for (int off = 1; off <= 8; off <<= 1) lrow[r] += __shfl_xor(lrow[r], off);
  }
#pragma unroll
  for (int r = 0; r < 4; r++) {
    const float invl = RCPF(lrow[r]);   // lrow >= 1 (diagonal term)
    const int t = tb + quad * 4 + r;
#pragma unroll
    for (int dt = 0; dt < 4; dt++) {
      float val = o[dt][r] * invl;
      outp[(size_t)(b * T_ + t) * C_ + h * 64 + dt * 16 + l16] = (bf16)val;
    }
  }
}

// ==============  SwiGLU in-place (bf16): uv[m][0..4096) = u * silu(v)  ==============
__global__ __launch_bounds__(256) void swiglu_kernel(bf16* __restrict__ uv) {
  const size_t gid = (size_t)blockIdx.x * 256 + threadIdx.x;
  const size_t e0 = gid * 4;
  const size_t m = e0 >> 12;      // / 4096
  const size_t j = e0 & 4095;
  bf16* up = uv + m * 8192 + j;
  bf16x4 u4 = *(const bf16x4*)up;
  bf16x4 v4 = *(const bf16x4*)(up + 4096);
  bf16x4 o;
#pragma unroll
  for (int i = 0; i < 4; i++) {
    float uu = (float)u4[i];
    float vvv = (float)v4[i];
    float vc = fminf(fmaxf(vvv, -80.f), 80.f);
    float sig = 1.f / (1.f + __expf(-vc));
    o[i] = (bf16)(uu * vvv * sig);
  }
  *(bf16x4*)up = o;
}

// =====================  host-side launch  =====================
extern "C" void kernel_launch(void* const* d_in, const int* in_sizes, int n_in,
                              void* d_out, int out_size, void* d_ws, size_t ws_size,
                              hipStream_t stream) {
  const float* x      = (const float*)d_in[0];
  const float* w_qkv  = (const float*)d_in[1];
  const float* w_out  = (const float*)d_in[2];
  const float* kcb    = (const float*)d_in[3];
  const float* w_uv   = (const float*)d_in[4];
  const float* b_uv   = (const float*)d_in[5];
  const float* w_mlp  = (const float*)d_in[6];
  const float* b_mlp  = (const float*)d_in[7];
  float* out = (float*)d_out;

  const size_t MB = 1024ull * 1024ull;
  char* w = (char*)d_ws;
  bf16*  wqkv_b  = (bf16*)(w + 0);          //  6 MB   [0,6)
  bf16*  wout_b  = (bf16*)(w + 6 * MB);     //  2 MB   [6,8)
  bf16*  wuv_b   = (bf16*)(w + 8 * MB);     // 16 MB   [8,24)
  bf16*  wmlp_b  = (bf16*)(w + 24 * MB);    //  8 MB   [24,32)
  bf16*  hbuf    = (bf16*)(w + 32 * MB);    //  8 MB   [32,40)
  bf16*  qkvbuf  = (bf16*)(w + 40 * MB);    // 24 MB   [40,64) dead after attn
  bf16*  attnbuf = (bf16*)(w + 64 * MB);    //  8 MB   [64,72) dead after step 5
  bf16*  uvbuf   = (bf16*)(w + 40 * MB);    // 64 MB   [40,104) over qkv+attn
  float* x2buf   = (float*)(w + 104 * MB);  // 16 MB   [104,120) fp32
  float* q0b     = (float*)(w + 120 * MB);               // 256 KB
  float* k0b     = (float*)(w + 120 * MB + 256 * 1024);  // 256 KB
  // total: 120.5 MB

  // 0) one-time weight casts fp32 -> bf16 (single fused launch)
  cast_all_kernel<<<(786432 + 262144 + 2097152 + 1048576) / 256, 256, 0, stream>>>(
      w_qkv, w_out, w_uv, w_mlp, wqkv_b, wout_b, wuv_b, wmlp_b);

  // 1) h = rmsnorm(x)                                  fp32 -> bf16
  rmsnorm_kernel<<<M_, 256, 0, stream>>>(x, hbuf);
  // 2) qkv = h @ w_qkv^T                               bf16 -> bf16
  gemm_bt<0, bf16><<<dim3(M_ / 128, 3072 / 128), 256, 0, stream>>>(
      hbuf, wqkv_b, qkvbuf, nullptr, nullptr, M_, 3072, 1024, 1024);
  // 3) rotary(q,k) in-place + q0/k0
  rotary_kernel<<<(B_ * T_ * H_) / 4, 256, 0, stream>>>(qkvbuf, kcb, q0b, k0b);
  // 4) hyperbolic flash attention                      -> bf16
  attn_kernel<<<dim3(B_ * H_, 32), 256, 0, stream>>>(qkvbuf, q0b, k0b, kcb, attnbuf);
  // 5) x2 = x + attn @ w_out^T                         -> fp32
  gemm_bt<1, float><<<dim3(M_ / 128, 1024 / 128), 256, 0, stream>>>(
      attnbuf, wout_b, x2buf, nullptr, x, M_, 1024, 1024, 1024);
  // 6) h2 = rmsnorm(x2)                                fp32 -> bf16
  rmsnorm_kernel<<<M_, 256, 0, stream>>>(x2buf, hbuf);
  // 7) uv = h2 @ w_uv^T + b_uv                         -> bf16
  gemm_bt<2, bf16><<<dim3(M_ / 128, 8192 / 128), 256, 0, stream>>>(
      hbuf, wuv_b, uvbuf, b_uv, nullptr, M_, 8192, 1024, 1024);
  // 8) g = u * silu(v), in place over u-half (row stride 8192)
  swiglu_kernel<<<(M_ * 4096) / (4 * 256), 256, 0, stream>>>(uvbuf);
  // 9) out = x2 + g @ w_mlp^T + b_mlp                  -> fp32
  gemm_bt<3, float><<<dim3(M_ / 128, 1024 / 128), 256, 0, stream>>>(
      uvbuf, wmlp_b, out, b_mlp, x2buf, M_, 1024, 4096, 8192);
}

// Round 10
// 455.870 us; speedup vs baseline: 1.5180x; 1.0003x over previous
//
#include <hip/hip_runtime.h>
#include <cstdint>
#include <cmath>

typedef __bf16 bf16;
typedef __attribute__((ext_vector_type(8))) __bf16 bf16x8;
typedef __attribute__((ext_vector_type(4))) __bf16 bf16x4;
typedef __attribute__((ext_vector_type(2))) __bf16 bf16x2;
typedef __attribute__((ext_vector_type(4))) float f32x4;

constexpr int B_ = 2, T_ = 2048, C_ = 1024, H_ = 16, HD_ = 64;
constexpr int M_ = B_ * T_;   // 4096

// native 2^x, log2(x), sqrt, rcp
#define EXP2F(x) __builtin_amdgcn_exp2f(x)
#define LOG2F(x) __builtin_amdgcn_logf(x)
#define SQRTF(x) __builtin_amdgcn_sqrtf(x)
#define RCPF(x)  __builtin_amdgcn_rcpf(x)

// ---- async global->LDS, 16B per lane; LDS dest = wave-uniform base + lane*16 ----
__device__ __forceinline__ void gld16(const void* g, void* l) {
  __builtin_amdgcn_global_load_lds((const __attribute__((address_space(1))) void*)g,
                                   (__attribute__((address_space(3))) void*)l, 16, 0, 0);
}

// ============  fused weight cast fp32 -> bf16 (w_uv/b_uv row-PERMUTED)  ============
// Permutation: dst block 128b rows [0,64) = u rows 64b..64b+63, [64,128) = v rows.
// segments (float4 units): qkv 786432 | wout 262144 | wuv 2097152 | wmlp 1048576 | b_uv 2048
__global__ __launch_bounds__(256) void cast_all_kernel(const float* __restrict__ s0,
                                                       const float* __restrict__ s1,
                                                       const float* __restrict__ s2,
                                                       const float* __restrict__ s3,
                                                       const float* __restrict__ s4,
                                                       bf16* __restrict__ d0,
                                                       bf16* __restrict__ d1,
                                                       bf16* __restrict__ d2,
                                                       bf16* __restrict__ d3,
                                                       float* __restrict__ d4) {
  size_t gid = (size_t)blockIdx.x * 256 + threadIdx.x;
  if (gid >= 786432 + 262144 + 2097152 + 1048576) {
    // b_uv permute (fp32 -> fp32), 4 consecutive rows stay contiguous
    size_t g4 = gid - (786432 + 262144 + 2097152 + 1048576);
    if (g4 >= 2048) return;
    int r = (int)(g4 * 4);
    int dr;
    if (r < 4096) { int blk = r >> 6, i = r & 63; dr = blk * 128 + i; }
    else { int j = r - 4096; int blk = j >> 6, i = j & 63; dr = blk * 128 + 64 + i; }
    *(f32x4*)(d4 + dr) = *(const f32x4*)(s4 + r);
    return;
  }
  const float* src;
  bf16* dst;
  size_t dstoff;
  if (gid < 786432) { src = s0; dst = d0; dstoff = gid * 4; }
  else if (gid < 786432 + 262144) { gid -= 786432; src = s1; dst = d1; dstoff = gid * 4; }
  else if (gid < 786432 + 262144 + 2097152) {
    gid -= 786432 + 262144; src = s2; dst = d2;
    // permute w_uv rows
    size_t elem = gid * 4;
    int r = (int)(elem >> 10), c = (int)(elem & 1023);
    int dr;
    if (r < 4096) { int blk = r >> 6, i = r & 63; dr = blk * 128 + i; }
    else { int j = r - 4096; int blk = j >> 6, i = j & 63; dr = blk * 128 + 64 + i; }
    dstoff = ((size_t)dr << 10) | (size_t)c;
  }
  else { gid -= 786432 + 262144 + 2097152; src = s3; dst = d3; dstoff = gid * 4; }
  f32x4 v = *(const f32x4*)(src + gid * 4);
  bf16x4 o;
  o[0] = (bf16)v[0]; o[1] = (bf16)v[1]; o[2] = (bf16)v[2]; o[3] = (bf16)v[3];
  *(bf16x4*)(dst + dstoff) = o;
}

// =============  GEMM: C = A @ Bw^T (+bias)(+residual)(+swiglu), bf16 operands  =============
// BK=64 as two stacked [128][32] half-tiles; one barrier pair per 64 K.
// MODE 0: C=AB   MODE 1: +R   MODE 2: +bias   MODE 3: +bias+R
// MODE 4: swiglu epilogue over permuted-uv output: block cols = [u0..63|v0..63];
//         writes g = u*v*sigmoid(v) to N(=4096)-col C at col (bn>>1)+nt*16+l16.
template <int MODE, typename OutT>
__global__ __launch_bounds__(256) void gemm_bt(const bf16* __restrict__ A,
                                               const bf16* __restrict__ Bw,
                                               OutT* __restrict__ Cmat,
                                               const float* __restrict__ bias,
                                               const float* __restrict__ R,
                                               int M, int N, int K, int lda) {
  __shared__ __align__(16) bf16 Als[2][128 * 32];
  __shared__ __align__(16) bf16 Bls[2][128 * 32];
  const int tid  = threadIdx.x;
  const int wave = tid >> 6;
  const int lane = tid & 63;
  const int quad = lane >> 4;
  const int l16  = lane & 15;
  const int bm = blockIdx.x * 128;
  const int bn = blockIdx.y * 128;
  const int wm = (wave & 1) * 64;
  const int wn = (wave >> 1) * 64;
  const int srow   = lane >> 2;  // 0..15
  const int schunk = lane & 3;   // 0..3

  f32x4 acc[4][4];
#pragma unroll
  for (int i = 0; i < 4; i++)
#pragma unroll
    for (int j = 0; j < 4; j++) acc[i][j] = f32x4{0.f, 0.f, 0.f, 0.f};

  const bf16* Ag = A  + (size_t)(bm + wave * 32 + srow) * lda + schunk * 8;
  const bf16* Bg = Bw + (size_t)(bn + wave * 32 + srow) * K   + schunk * 8;
  bf16* AlsW0 = &Als[0][(wave * 32) * 32];
  bf16* AlsW1 = &Als[1][(wave * 32) * 32];
  bf16* BlsW0 = &Bls[0][(wave * 32) * 32];
  bf16* BlsW1 = &Bls[1][(wave * 32) * 32];

  for (int k0 = 0; k0 < K; k0 += 64) {
    gld16(Ag + k0,                         AlsW0);
    gld16(Ag + k0 + (size_t)16 * lda,      AlsW0 + 16 * 32);
    gld16(Ag + k0 + 32,                    AlsW1);
    gld16(Ag + k0 + 32 + (size_t)16 * lda, AlsW1 + 16 * 32);
    gld16(Bg + k0,                         BlsW0);
    gld16(Bg + k0 + (size_t)16 * K,        BlsW0 + 16 * 32);
    gld16(Bg + k0 + 32,                    BlsW1);
    gld16(Bg + k0 + 32 + (size_t)16 * K,   BlsW1 + 16 * 32);
    __syncthreads();   // drains vmcnt before barrier

#pragma unroll
    for (int hh = 0; hh < 2; hh++) {
      bf16x8 af[4], bfr[4];
#pragma unroll
      for (int mt = 0; mt < 4; mt++)
        af[mt] = *(const bf16x8*)&Als[hh][(wm + mt * 16 + l16) * 32 + quad * 8];
#pragma unroll
      for (int nt = 0; nt < 4; nt++)
        bfr[nt] = *(const bf16x8*)&Bls[hh][(wn + nt * 16 + l16) * 32 + quad * 8];
#pragma unroll
      for (int mt = 0; mt < 4; mt++)
#pragma unroll
        for (int nt = 0; nt < 4; nt++)
          acc[mt][nt] = __builtin_amdgcn_mfma_f32_16x16x32_bf16(af[mt], bfr[nt], acc[mt][nt], 0, 0, 0);
    }
    __syncthreads();
  }

  // epilogue: D row = wm+mt*16+quad*4+r, col = wn+nt*16+l16
  if (MODE == 4) {
    // wn 0 or 64: waves 0/1 handle u-tiles (wn=0 -> nt 0..3 = u), waves 2/3 (wn=64) v.
    // Pair u=acc[..][nt] (wn=0) with v from the OTHER wave pair? No: each wave computed
    // nt over its own wn range. wn=0 waves hold u cols, wn=64 waves hold v cols.
    // Instead pair within lane across wn: not possible cross-wave -> use both wn halves
    // per wave: here each wave computed 4 nt tiles at cols wn+nt*16. For wn=0: u_j,
    // j = nt*16+l16; for wn=64: v_j. Cross-wave pairing is needed -> route via LDS reuse
    // of Als (safe: after last barrier).
    __shared__ float vstage[4 * 16 * 64];  // per v-wave: 16 rows x 64 cols (wave-major)
    float* vs = &vstage[(wave & 1) * 16 * 64 * 2];  // waves (0,2) share pair 0; (1,3) pair 1
    if (wave >= 2) {
      // v-wave: stash v = acc + bias_v into LDS rows (mt*? ) -> layout [mt][r within 16][col]
#pragma unroll
      for (int mt = 0; mt < 4; mt++)
#pragma unroll
        for (int nt = 0; nt < 4; nt++) {
          const float bv = bias[bn + 64 + nt * 16 + l16];
#pragma unroll
          for (int r = 0; r < 4; r++)
            vs[(mt * 16 + quad * 4 + r) * 4 + nt] = 0.f;  // placeholder (unused path)
        }
    }
    // NOTE: cross-wave pairing path not used; see host: MODE 4 launched with wn-free
    // mapping (wm covers 128 rows, wn covers 128 cols where cols 0..63=u, 64..127=v
    // for the SAME wave when wn==0/64 split is bypassed below).
  }
#pragma unroll
  for (int mt = 0; mt < 4; mt++) {
    const int row = bm + wm + mt * 16 + quad * 4;
    if (MODE == 4) continue;
#pragma unroll
    for (int nt = 0; nt < 4; nt++) {
      const int col = bn + wn + nt * 16 + l16;
      float bval = 0.f;
      if (MODE & 2) bval = bias[col];
#pragma unroll
      for (int r = 0; r < 4; r++) {
        float v = acc[mt][nt][r] + bval;
        if (MODE & 1) v += R[(size_t)(row + r) * N + col];
        Cmat[(size_t)(row + r) * N + col] = (OutT)v;
      }
    }
  }
  if (MODE == 4) {
    // u and v are in DIFFERENT waves (wn split). Exchange v-half via LDS (Als reuse).
    float* xbuf = (float*)&Als[0][0];  // 32 KB = 8192 floats; need 64 rows x 64 cols x2 pairs
    // wave pair p = wave & 1 handles rows wm..wm+63; u-wave (wave<2) wn=0, v-wave wn=64.
    float* xb = xbuf + (wave & 1) * 4096;   // 64x64 floats per row-half
    __syncthreads();
    if (wave >= 2) {
#pragma unroll
      for (int mt = 0; mt < 4; mt++)
#pragma unroll
        for (int nt = 0; nt < 4; nt++) {
          const float bv = bias[bn + 64 + nt * 16 + l16];
#pragma unroll
          for (int r = 0; r < 4; r++)
            xb[(mt * 16 + quad * 4 + r) * 64 + nt * 16 + l16] = acc[mt][nt][r] + bv;
        }
    }
    __syncthreads();
    if (wave < 2) {
      const int colg = (bn >> 1);
#pragma unroll
      for (int mt = 0; mt < 4; mt++) {
        const int row = bm + wm + mt * 16 + quad * 4;
#pragma unroll
        for (int nt = 0; nt < 4; nt++) {
          const float bu = bias[bn + nt * 16 + l16];
          const int col = colg + nt * 16 + l16;
#pragma unroll
          for (int r = 0; r < 4; r++) {
            float u = acc[mt][nt][r] + bu;
            float v = xb[(mt * 16 + quad * 4 + r) * 64 + nt * 16 + l16];
            float sig = RCPF(1.f + EXP2F(-v * 1.44269504f));
            Cmat[(size_t)(row + r) * N + col] = (OutT)(u * v * sig);
          }
        }
      }
    }
  }
}

// =====================  RMSNorm: fp32 in -> bf16 out (row = 1024)  =====================
__global__ __launch_bounds__(256) void rmsnorm_kernel(const float* __restrict__ X,
                                                      bf16* __restrict__ O) {
  const int row = blockIdx.x;
  const int tid = threadIdx.x;
  const int wave = tid >> 6;
  f32x4 v = *(const f32x4*)(X + (size_t)row * C_ + tid * 4);
  float s = v[0] * v[0] + v[1] * v[1] + v[2] * v[2] + v[3] * v[3];
#pragma unroll
  for (int off = 32; off >= 1; off >>= 1) s += __shfl_xor(s, off);
  __shared__ float wsum[4];
  __shared__ float scale_sh;
  if ((tid & 63) == 0) wsum[wave] = s;
  __syncthreads();
  if (tid == 0)
    scale_sh = rsqrtf((wsum[0] + wsum[1] + wsum[2] + wsum[3]) * (1.f / (float)C_) + 1e-6f);
  __syncthreads();
  const float sc = scale_sh;
  bf16x4 o;
  o[0] = (bf16)(v[0] * sc); o[1] = (bf16)(v[1] * sc);
  o[2] = (bf16)(v[2] * sc); o[3] = (bf16)(v[3] * sc);
  *(bf16x4*)(O + (size_t)row * C_ + tid * 4) = o;
}

// ==========  Rotary on q,k (bf16, in-place) + q0/k0 = sqrt(kc + |.|^2)  ==========
__global__ __launch_bounds__(256) void rotary_kernel(bf16* __restrict__ qkv,
                                                     const float* __restrict__ kcb,
                                                     float* __restrict__ q0b,
                                                     float* __restrict__ k0b) {
  const int wid  = blockIdx.x * 4 + (threadIdx.x >> 6);  // one wave per (b,t,h)
  const int lane = threadIdx.x & 63;
  const int b = wid >> 15;          // T_*H_ = 32768
  const int rem = wid & 32767;
  const int t = rem >> 4;
  const int h = rem & 15;
  const int i = lane & 31;
  const float invf = expf(-((float)i / 32.f) * 9.210340371976184f);  // 10000^(-i/32)
  const float ang = (float)t * invf;
  const float cx = cosf(ang), sx = sinf(ang);
  const float kc = kcb[h];
  bf16* qp = qkv + (size_t)(b * T_ + t) * 3072 + h * 64;

#pragma unroll
  for (int which = 0; which < 2; which++) {
    bf16* p = qp + which * 1024;   // q then k
    float x1 = (float)p[i];
    float x2 = (float)p[i + 32];
    float o = (lane < 32) ? (x1 * cx + x2 * sx) : (x2 * cx - x1 * sx);
    float ss = o * o;
#pragma unroll
    for (int off = 32; off >= 1; off >>= 1) ss += __shfl_xor(ss, off);
    p[lane] = (bf16)o;
    if (lane == 0) {
      float* dst = which == 0 ? q0b : k0b;
      dst[(size_t)(b * H_ + h) * T_ + t] = SQRTF(kc + ss);
    }
  }
}

// =====================  Hyperbolic flash attention (v7)  =====================
// v6 + Vt staged via PACKED ds_write_b32 (8 writes/thread, conflict-free banks)
// instead of 16 scalar b16 scatter writes. Thread map: sp = s-pair, dq = d-chunk.
// LDS double-buffer, single barrier per 64-tile, register prefetch, LPT order.
__global__ __launch_bounds__(256) void attn_kernel(const bf16* __restrict__ qkv,
                                                   const float* __restrict__ q0b,
                                                   const float* __restrict__ k0b,
                                                   const float* __restrict__ kcb,
                                                   bf16* __restrict__ outp) {
  __shared__ __align__(16) bf16 Kls[2][64][72];  // K tile [s][d]
  __shared__ __align__(16) bf16 Vt[2][64][68];   // V^T [d][s]
  __shared__ __align__(16) bf16 Pls[4][16 * 36]; // per-wave P chunk buffer
  __shared__ float k0s[2][64];

  const int tid = threadIdx.x;
  const int wave = tid >> 6, lane = tid & 63;
  const int quad = lane >> 4, l16 = lane & 15;
  const int bh = blockIdx.x;
  const int b = bh >> 4, h = bh & 15;

  const float kc = kcb[h];
  const float inv_kc = 1.f / kc;
  const float sqkc = SQRTF(kc);
  const int sp = tid & 31, dq = tid >> 5;   // sp 0..31 (s-pairs), dq 0..7 (d-chunks)
  bf16* Pl = Pls[wave];
  const float* q0base = q0b + (size_t)(b * H_ + h) * T_;
  const float* k0base = k0b + (size_t)(b * H_ + h) * T_;

  const int ty = 31 - (int)blockIdx.y;   // heaviest blocks dispatch first
  const int t0 = ty * 64;
  const int tb = t0 + wave * 16;
  const int nIter = ty + 1;

  // q A-frags: A[m=l16][k=quad*8+j]
  const bf16* qrow = qkv + (size_t)(b * T_ + tb + l16) * 3072 + h * 64;
  bf16x8 aq0 = *(const bf16x8*)(qrow + quad * 8);
  bf16x8 aq1 = *(const bf16x8*)(qrow + 32 + quad * 8);
  float q0r[4];
#pragma unroll
  for (int r = 0; r < 4; r++) q0r[r] = q0base[tb + quad * 4 + r];

  f32x4 o[4];
#pragma unroll
  for (int dt = 0; dt < 4; dt++) o[dt] = f32x4{0.f, 0.f, 0.f, 0.f};
  float lrow[4] = {0.f, 0.f, 0.f, 0.f};

  // ---- prologue: prefetch tile 0 (s-rows 2sp, 2sp+1 at d-chunk dq) ----
  const bf16* kvbase = qkv + (size_t)b * T_ * 3072 + 1024 + h * 64 + dq * 8;
  bf16x8 kv_a = *(const bf16x8*)(kvbase + (size_t)(2 * sp) * 3072);
  bf16x8 kv_b = *(const bf16x8*)(kvbase + (size_t)(2 * sp + 1) * 3072);
  bf16x8 vv_a = *(const bf16x8*)(kvbase + (size_t)(2 * sp) * 3072 + 1024);
  bf16x8 vv_b = *(const bf16x8*)(kvbase + (size_t)(2 * sp + 1) * 3072 + 1024);
  float k0v = (tid < 64) ? k0base[tid] : 0.f;

  for (int it = 0; it < nIter; ++it) {
    const int s0 = it * 64;
    const int buf = it & 1;
    // ---- commit prefetched tile (K: 2 b128; Vt: 8 packed b32, conflict-free) ----
    *(bf16x8*)&Kls[buf][2 * sp][dq * 8]     = kv_a;
    *(bf16x8*)&Kls[buf][2 * sp + 1][dq * 8] = kv_b;
#pragma unroll
    for (int i2 = 0; i2 < 8; i2++) {
      bf16x2 pr;
      pr[0] = vv_a[i2];
      pr[1] = vv_b[i2];
      *(bf16x2*)&Vt[buf][dq * 8 + i2][2 * sp] = pr;
    }
    if (tid < 64) k0s[buf][tid] = k0v;
    __syncthreads();

    // ---- prefetch NEXT tile (clamped; latency overlaps compute below) ----
    const int s0n = (it + 1 < nIter) ? s0 + 64 : s0;
    kv_a = *(const bf16x8*)(kvbase + (size_t)(s0n + 2 * sp) * 3072);
    kv_b = *(const bf16x8*)(kvbase + (size_t)(s0n + 2 * sp + 1) * 3072);
    vv_a = *(const bf16x8*)(kvbase + (size_t)(s0n + 2 * sp) * 3072 + 1024);
    vv_b = *(const bf16x8*)(kvbase + (size_t)(s0n + 2 * sp + 1) * 3072 + 1024);
    if (tid < 64) k0v = k0base[s0n + tid];

    // ---- S = q @ K^T (four 16-col n-tiles) ----
    f32x4 sc[4];
#pragma unroll
    for (int nt = 0; nt < 4; nt++) {
      sc[nt] = f32x4{0.f, 0.f, 0.f, 0.f};
      bf16x8 b0 = *(const bf16x8*)&Kls[buf][nt * 16 + l16][quad * 8];
      bf16x8 b1 = *(const bf16x8*)&Kls[buf][nt * 16 + l16][32 + quad * 8];
      sc[nt] = __builtin_amdgcn_mfma_f32_16x16x32_bf16(aq0, b0, sc[nt], 0, 0, 0);
      sc[nt] = __builtin_amdgcn_mfma_f32_16x16x32_bf16(aq1, b1, sc[nt], 0, 0, 0);
    }

    // ---- p = exp(-dis) in two 32-col chunks; P roundtrip per chunk ----
    bf16x8 ap[2];
#pragma unroll
    for (int ck = 0; ck < 2; ck++) {
#pragma unroll
      for (int ntl = 0; ntl < 2; ntl++) {
        const int nt = ck * 2 + ntl;
        const float k0c = k0s[buf][nt * 16 + l16];
        const int s = s0 + nt * 16 + l16;
#pragma unroll
        for (int r = 0; r < 4; r++) {
          const int t = tb + quad * 4 + r;
          float lor = sc[nt][r] - q0r[r] * k0c;
          float ratio = fmaxf(-lor * inv_kc, 1.f + 1e-6f);
          float wv = ratio + SQRTF(ratio * ratio - 1.f);
          float p = EXP2F(-sqkc * LOG2F(wv));
          p = (s <= t) ? p : 0.f;
          lrow[r] += p;
          Pl[(quad * 4 + r) * 36 + ntl * 16 + l16] = (bf16)p;
        }
      }
      ap[ck] = *(const bf16x8*)&Pl[l16 * 36 + quad * 8];
    }
#pragma unroll
    for (int dt = 0; dt < 4; dt++) {
      bf16x8 bv0 = *(const bf16x8*)&Vt[buf][dt * 16 + l16][quad * 8];
      bf16x8 bv1 = *(const bf16x8*)&Vt[buf][dt * 16 + l16][32 + quad * 8];
      o[dt] = __builtin_amdgcn_mfma_f32_16x16x32_bf16(ap[0], bv0, o[dt], 0, 0, 0);
      o[dt] = __builtin_amdgcn_mfma_f32_16x16x32_bf16(ap[1], bv1, o[dt], 0, 0, 0);
    }
  }

  // ---- one deferred l-reduction over the 16 l16 lanes, then write O ----
#pragma unroll
  for (int r = 0; r < 4; r++) {
#pragma unroll
    for (int off = 1; off <= 8; off <<= 1) lrow[r] += __shfl_xor(lrow[r], off);
  }
#pragma unroll
  for (int r = 0; r < 4; r++) {
    const float invl = RCPF(lrow[r]);
    const int t = tb + quad * 4 + r;
#pragma unroll
    for (int dt = 0; dt < 4; dt++) {
      float val = o[dt][r] * invl;
      outp[(size_t)(b * T_ + t) * C_ + h * 64 + dt * 16 + l16] = (bf16)val;
    }
  }
}

// =====================  host-side launch  =====================
extern "C" void kernel_launch(void* const* d_in, const int* in_sizes, int n_in,
                              void* d_out, int out_size, void* d_ws, size_t ws_size,
                              hipStream_t stream) {
  const float* x      = (const float*)d_in[0];
  const float* w_qkv  = (const float*)d_in[1];
  const float* w_out  = (const float*)d_in[2];
  const float* kcb    = (const float*)d_in[3];
  const float* w_uv   = (const float*)d_in[4];
  const float* b_uv   = (const float*)d_in[5];
  const float* w_mlp  = (const float*)d_in[6];
  const float* b_mlp  = (const float*)d_in[7];
  float* out = (float*)d_out;

  const size_t MB = 1024ull * 1024ull;
  char* w = (char*)d_ws;
  bf16*  wqkv_b  = (bf16*)(w + 0);          //  6 MB   [0,6)
  bf16*  wout_b  = (bf16*)(w + 6 * MB);     //  2 MB   [6,8)
  bf16*  wuv_p   = (bf16*)(w + 8 * MB);     // 16 MB   [8,24)  row-permuted
  bf16*  wmlp_b  = (bf16*)(w + 24 * MB);    //  8 MB   [24,32)
  bf16*  hbuf    = (bf16*)(w + 32 * MB);    //  8 MB   [32,40)
  bf16*  qkvbuf  = (bf16*)(w + 40 * MB);    // 24 MB   [40,64) dead after attn
  bf16*  attnbuf = (bf16*)(w + 64 * MB);    //  8 MB   [64,72) dead after wout GEMM
  bf16*  gbuf    = (bf16*)(w + 40 * MB);    // 32 MB   [40,72) over qkv+attn (step 7)
  float* x2buf   = (float*)(w + 72 * MB);   // 16 MB   [72,88) fp32
  float* q0b     = (float*)(w + 88 * MB);                 // 256 KB
  float* k0b     = (float*)(w + 88 * MB + 256 * 1024);    // 256 KB
  float* biasp   = (float*)(w + 88 * MB + 512 * 1024);    //  32 KB (permuted b_uv)
  // total: ~88.6 MB

  // 0) weight casts (+w_uv/b_uv row permutation), single launch
  const int total4 = 786432 + 262144 + 2097152 + 1048576 + 2048;
  cast_all_kernel<<<(total4 + 255) / 256, 256, 0, stream>>>(
      w_qkv, w_out, w_uv, w_mlp, b_uv, wqkv_b, wout_b, wuv_p, wmlp_b, biasp);

  // 1) h = rmsnorm(x)
  rmsnorm_kernel<<<M_, 256, 0, stream>>>(x, hbuf);
  // 2) qkv = h @ w_qkv^T
  gemm_bt<0, bf16><<<dim3(M_ / 128, 3072 / 128), 256, 0, stream>>>(
      hbuf, wqkv_b, qkvbuf, nullptr, nullptr, M_, 3072, 1024, 1024);
  // 3) rotary(q,k) in-place + q0/k0
  rotary_kernel<<<(B_ * T_ * H_) / 4, 256, 0, stream>>>(qkvbuf, kcb, q0b, k0b);
  // 4) hyperbolic flash attention
  attn_kernel<<<dim3(B_ * H_, 32), 256, 0, stream>>>(qkvbuf, q0b, k0b, kcb, attnbuf);
  // 5) x2 = x + attn @ w_out^T
  gemm_bt<1, float><<<dim3(M_ / 128, 1024 / 128), 256, 0, stream>>>(
      attnbuf, wout_b, x2buf, nullptr, x, M_, 1024, 1024, 1024);
  // 6) h2 = rmsnorm(x2)
  rmsnorm_kernel<<<M_, 256, 0, stream>>>(x2buf, hbuf);
  // 7) g = swiglu(h2 @ w_uv_p^T + b_uv_p)  -> 4096-col bf16 (fused epilogue)
  gemm_bt<4, bf16><<<dim3(M_ / 128, 8192 / 128), 256, 0, stream>>>(
      hbuf, wuv_p, gbuf, biasp, nullptr, M_, 4096, 1024, 1024);
  // 8) out = x2 + g @ w_mlp^T + b_mlp
  gemm_bt<3, float><<<dim3(M_ / 128, 1024 / 128), 256, 0, stream>>>(
      gbuf, wmlp_b, out, b_mlp, x2buf, M_, 1024, 4096, 4096);
}

// Round 11
// 449.618 us; speedup vs baseline: 1.5391x; 1.0139x over previous
//
#include <hip/hip_runtime.h>
#include <cstdint>
#include <cmath>

typedef __bf16 bf16;
typedef __attribute__((ext_vector_type(8))) __bf16 bf16x8;
typedef __attribute__((ext_vector_type(4))) __bf16 bf16x4;
typedef __attribute__((ext_vector_type(2))) __bf16 bf16x2;
typedef __attribute__((ext_vector_type(4))) float f32x4;

constexpr int B_ = 2, T_ = 2048, C_ = 1024, H_ = 16, HD_ = 64;
constexpr int M_ = B_ * T_;   // 4096

// native 2^x, log2(x), sqrt, rcp
#define EXP2F(x) __builtin_amdgcn_exp2f(x)
#define LOG2F(x) __builtin_amdgcn_logf(x)
#define SQRTF(x) __builtin_amdgcn_sqrtf(x)
#define RCPF(x)  __builtin_amdgcn_rcpf(x)

// ---- async global->LDS, 16B per lane; LDS dest = wave-uniform base + lane*16 ----
__device__ __forceinline__ void gld16(const void* g, void* l) {
  __builtin_amdgcn_global_load_lds((const __attribute__((address_space(1))) void*)g,
                                   (__attribute__((address_space(3))) void*)l, 16, 0, 0);
}

// ============  fused weight cast fp32 -> bf16 (w_uv/b_uv row-PERMUTED)  ============
// Permutation: dst block 128b rows [0,64) = u rows 64b..64b+63, [64,128) = v rows.
// segments (float4 units): qkv 786432 | wout 262144 | wuv 2097152 | wmlp 1048576 | b_uv 2048
__global__ __launch_bounds__(256) void cast_all_kernel(const float* __restrict__ s0,
                                                       const float* __restrict__ s1,
                                                       const float* __restrict__ s2,
                                                       const float* __restrict__ s3,
                                                       const float* __restrict__ s4,
                                                       bf16* __restrict__ d0,
                                                       bf16* __restrict__ d1,
                                                       bf16* __restrict__ d2,
                                                       bf16* __restrict__ d3,
                                                       float* __restrict__ d4) {
  size_t gid = (size_t)blockIdx.x * 256 + threadIdx.x;
  if (gid >= 786432 + 262144 + 2097152 + 1048576) {
    // b_uv permute (fp32 -> fp32), 4 consecutive rows stay contiguous
    size_t g4 = gid - (786432 + 262144 + 2097152 + 1048576);
    if (g4 >= 2048) return;
    int r = (int)(g4 * 4);
    int dr;
    if (r < 4096) { int blk = r >> 6, i = r & 63; dr = blk * 128 + i; }
    else { int j = r - 4096; int blk = j >> 6, i = j & 63; dr = blk * 128 + 64 + i; }
    *(f32x4*)(d4 + dr) = *(const f32x4*)(s4 + r);
    return;
  }
  const float* src;
  bf16* dst;
  size_t dstoff;
  if (gid < 786432) { src = s0; dst = d0; dstoff = gid * 4; }
  else if (gid < 786432 + 262144) { gid -= 786432; src = s1; dst = d1; dstoff = gid * 4; }
  else if (gid < 786432 + 262144 + 2097152) {
    gid -= 786432 + 262144; src = s2; dst = d2;
    // permute w_uv rows
    size_t elem = gid * 4;
    int r = (int)(elem >> 10), c = (int)(elem & 1023);
    int dr;
    if (r < 4096) { int blk = r >> 6, i = r & 63; dr = blk * 128 + i; }
    else { int j = r - 4096; int blk = j >> 6, i = j & 63; dr = blk * 128 + 64 + i; }
    dstoff = ((size_t)dr << 10) | (size_t)c;
  }
  else { gid -= 786432 + 262144 + 2097152; src = s3; dst = d3; dstoff = gid * 4; }
  f32x4 v = *(const f32x4*)(src + gid * 4);
  bf16x4 o;
  o[0] = (bf16)v[0]; o[1] = (bf16)v[1]; o[2] = (bf16)v[2]; o[3] = (bf16)v[3];
  *(bf16x4*)(dst + dstoff) = o;
}

// =============  GEMM: C = A @ Bw^T (+bias)(+residual)(+swiglu), bf16 operands  =============
// BK=64 as two stacked [128][32] half-tiles; one barrier pair per 64 K.
// All LDS in ONE contiguous shmem[4*4096] (32 KB): halves A0,A1,B0,B1. MODE 4's
// epilogue reuses the whole 32 KB as a float exchange buffer (legal, contiguous).
// MODE 0: C=AB   MODE 1: +R   MODE 2: +bias   MODE 3: +bias+R
// MODE 4: swiglu over permuted-uv: block cols = [u0..63|v0..63]; writes
//         g = u*v*sigmoid(v) to N(=4096)-col C at col (bn>>1)+nt*16+l16.
template <int MODE, typename OutT>
__global__ __launch_bounds__(256) void gemm_bt(const bf16* __restrict__ A,
                                               const bf16* __restrict__ Bw,
                                               OutT* __restrict__ Cmat,
                                               const float* __restrict__ bias,
                                               const float* __restrict__ R,
                                               int M, int N, int K, int lda) {
  __shared__ __align__(16) bf16 shmem[4 * 128 * 32];   // exactly 32768 B
  bf16* const AlsH[2] = { &shmem[0], &shmem[4096] };
  bf16* const BlsH[2] = { &shmem[2 * 4096], &shmem[3 * 4096] };
  const int tid  = threadIdx.x;
  const int wave = tid >> 6;
  const int lane = tid & 63;
  const int quad = lane >> 4;
  const int l16  = lane & 15;
  const int bm = blockIdx.x * 128;
  const int bn = blockIdx.y * 128;
  const int wm = (wave & 1) * 64;
  const int wn = (wave >> 1) * 64;
  const int srow   = lane >> 2;  // 0..15
  const int schunk = lane & 3;   // 0..3

  f32x4 acc[4][4];
#pragma unroll
  for (int i = 0; i < 4; i++)
#pragma unroll
    for (int j = 0; j < 4; j++) acc[i][j] = f32x4{0.f, 0.f, 0.f, 0.f};

  const bf16* Ag = A  + (size_t)(bm + wave * 32 + srow) * lda + schunk * 8;
  const bf16* Bg = Bw + (size_t)(bn + wave * 32 + srow) * K   + schunk * 8;
  bf16* AlsW0 = AlsH[0] + (wave * 32) * 32;
  bf16* AlsW1 = AlsH[1] + (wave * 32) * 32;
  bf16* BlsW0 = BlsH[0] + (wave * 32) * 32;
  bf16* BlsW1 = BlsH[1] + (wave * 32) * 32;

  for (int k0 = 0; k0 < K; k0 += 64) {
    gld16(Ag + k0,                         AlsW0);
    gld16(Ag + k0 + (size_t)16 * lda,      AlsW0 + 16 * 32);
    gld16(Ag + k0 + 32,                    AlsW1);
    gld16(Ag + k0 + 32 + (size_t)16 * lda, AlsW1 + 16 * 32);
    gld16(Bg + k0,                         BlsW0);
    gld16(Bg + k0 + (size_t)16 * K,        BlsW0 + 16 * 32);
    gld16(Bg + k0 + 32,                    BlsW1);
    gld16(Bg + k0 + 32 + (size_t)16 * K,   BlsW1 + 16 * 32);
    __syncthreads();   // drains vmcnt before barrier

#pragma unroll
    for (int hh = 0; hh < 2; hh++) {
      bf16x8 af[4], bfr[4];
#pragma unroll
      for (int mt = 0; mt < 4; mt++)
        af[mt] = *(const bf16x8*)&AlsH[hh][(wm + mt * 16 + l16) * 32 + quad * 8];
#pragma unroll
      for (int nt = 0; nt < 4; nt++)
        bfr[nt] = *(const bf16x8*)&BlsH[hh][(wn + nt * 16 + l16) * 32 + quad * 8];
#pragma unroll
      for (int mt = 0; mt < 4; mt++)
#pragma unroll
        for (int nt = 0; nt < 4; nt++)
          acc[mt][nt] = __builtin_amdgcn_mfma_f32_16x16x32_bf16(af[mt], bfr[nt], acc[mt][nt], 0, 0, 0);
    }
    __syncthreads();
  }

  if (MODE != 4) {
    // epilogue: D row = wm+mt*16+quad*4+r, col = wn+nt*16+l16
#pragma unroll
    for (int mt = 0; mt < 4; mt++) {
      const int row = bm + wm + mt * 16 + quad * 4;
#pragma unroll
      for (int nt = 0; nt < 4; nt++) {
        const int col = bn + wn + nt * 16 + l16;
        float bval = 0.f;
        if (MODE & 2) bval = bias[col];
#pragma unroll
        for (int r = 0; r < 4; r++) {
          float v = acc[mt][nt][r] + bval;
          if (MODE & 1) v += R[(size_t)(row + r) * N + col];
          Cmat[(size_t)(row + r) * N + col] = (OutT)v;
        }
      }
    }
  } else {
    // u (waves 0/1, wn=0) and v (waves 2/3, wn=64) for the same rows live in
    // different waves -> exchange v through shmem (32 KB = 8192 floats: two
    // 64x64 halves, one per wm row-half).
    float* xb = (float*)shmem + (wave & 1) * 4096;
    if (wave >= 2) {
#pragma unroll
      for (int mt = 0; mt < 4; mt++)
#pragma unroll
        for (int nt = 0; nt < 4; nt++) {
          const float bv = bias[bn + 64 + nt * 16 + l16];
#pragma unroll
          for (int r = 0; r < 4; r++)
            xb[(mt * 16 + quad * 4 + r) * 64 + nt * 16 + l16] = acc[mt][nt][r] + bv;
        }
    }
    __syncthreads();
    if (wave < 2) {
      const int colg = (bn >> 1);
#pragma unroll
      for (int mt = 0; mt < 4; mt++) {
        const int row = bm + wm + mt * 16 + quad * 4;
#pragma unroll
        for (int nt = 0; nt < 4; nt++) {
          const float bu = bias[bn + nt * 16 + l16];
          const int col = colg + nt * 16 + l16;
#pragma unroll
          for (int r = 0; r < 4; r++) {
            float u = acc[mt][nt][r] + bu;
            float v = xb[(mt * 16 + quad * 4 + r) * 64 + nt * 16 + l16];
            float sig = RCPF(1.f + EXP2F(-v * 1.44269504f));
            Cmat[(size_t)(row + r) * N + col] = (OutT)(u * v * sig);
          }
        }
      }
    }
  }
}

// =====================  RMSNorm: fp32 in -> bf16 out (row = 1024)  =====================
__global__ __launch_bounds__(256) void rmsnorm_kernel(const float* __restrict__ X,
                                                      bf16* __restrict__ O) {
  const int row = blockIdx.x;
  const int tid = threadIdx.x;
  const int wave = tid >> 6;
  f32x4 v = *(const f32x4*)(X + (size_t)row * C_ + tid * 4);
  float s = v[0] * v[0] + v[1] * v[1] + v[2] * v[2] + v[3] * v[3];
#pragma unroll
  for (int off = 32; off >= 1; off >>= 1) s += __shfl_xor(s, off);
  __shared__ float wsum[4];
  __shared__ float scale_sh;
  if ((tid & 63) == 0) wsum[wave] = s;
  __syncthreads();
  if (tid == 0)
    scale_sh = rsqrtf((wsum[0] + wsum[1] + wsum[2] + wsum[3]) * (1.f / (float)C_) + 1e-6f);
  __syncthreads();
  const float sc = scale_sh;
  bf16x4 o;
  o[0] = (bf16)(v[0] * sc); o[1] = (bf16)(v[1] * sc);
  o[2] = (bf16)(v[2] * sc); o[3] = (bf16)(v[3] * sc);
  *(bf16x4*)(O + (size_t)row * C_ + tid * 4) = o;
}

// ==========  Rotary on q,k (bf16, in-place) + q0/k0 = sqrt(kc + |.|^2)  ==========
__global__ __launch_bounds__(256) void rotary_kernel(bf16* __restrict__ qkv,
                                                     const float* __restrict__ kcb,
                                                     float* __restrict__ q0b,
                                                     float* __restrict__ k0b) {
  const int wid  = blockIdx.x * 4 + (threadIdx.x >> 6);  // one wave per (b,t,h)
  const int lane = threadIdx.x & 63;
  const int b = wid >> 15;          // T_*H_ = 32768
  const int rem = wid & 32767;
  const int t = rem >> 4;
  const int h = rem & 15;
  const int i = lane & 31;
  const float invf = expf(-((float)i / 32.f) * 9.210340371976184f);  // 10000^(-i/32)
  const float ang = (float)t * invf;
  const float cx = cosf(ang), sx = sinf(ang);
  const float kc = kcb[h];
  bf16* qp = qkv + (size_t)(b * T_ + t) * 3072 + h * 64;

#pragma unroll
  for (int which = 0; which < 2; which++) {
    bf16* p = qp + which * 1024;   // q then k
    float x1 = (float)p[i];
    float x2 = (float)p[i + 32];
    float o = (lane < 32) ? (x1 * cx + x2 * sx) : (x2 * cx - x1 * sx);
    float ss = o * o;
#pragma unroll
    for (int off = 32; off >= 1; off >>= 1) ss += __shfl_xor(ss, off);
    p[lane] = (bf16)o;
    if (lane == 0) {
      float* dst = which == 0 ? q0b : k0b;
      dst[(size_t)(b * H_ + h) * T_ + t] = SQRTF(kc + ss);
    }
  }
}

// =====================  Hyperbolic flash attention (v7)  =====================
// Packed ds_write_b32 Vt staging; LDS double-buffer; single barrier per 64-tile;
// register prefetch; LPT order. Scores in (0,1], row-sum >= 1: no online max.
__global__ __launch_bounds__(256) void attn_kernel(const bf16* __restrict__ qkv,
                                                   const float* __restrict__ q0b,
                                                   const float* __restrict__ k0b,
                                                   const float* __restrict__ kcb,
                                                   bf16* __restrict__ outp) {
  __shared__ __align__(16) bf16 Kls[2][64][72];  // K tile [s][d]
  __shared__ __align__(16) bf16 Vt[2][64][68];   // V^T [d][s]
  __shared__ __align__(16) bf16 Pls[4][16 * 36]; // per-wave P chunk buffer
  __shared__ float k0s[2][64];

  const int tid = threadIdx.x;
  const int wave = tid >> 6, lane = tid & 63;
  const int quad = lane >> 4, l16 = lane & 15;
  const int bh = blockIdx.x;
  const int b = bh >> 4, h = bh & 15;

  const float kc = kcb[h];
  const float inv_kc = 1.f / kc;
  const float sqkc = SQRTF(kc);
  const int sp = tid & 31, dq = tid >> 5;   // sp 0..31 (s-pairs), dq 0..7 (d-chunks)
  bf16* Pl = Pls[wave];
  const float* q0base = q0b + (size_t)(b * H_ + h) * T_;
  const float* k0base = k0b + (size_t)(b * H_ + h) * T_;

  const int ty = 31 - (int)blockIdx.y;   // heaviest blocks dispatch first
  const int t0 = ty * 64;
  const int tb = t0 + wave * 16;
  const int nIter = ty + 1;

  // q A-frags: A[m=l16][k=quad*8+j]
  const bf16* qrow = qkv + (size_t)(b * T_ + tb + l16) * 3072 + h * 64;
  bf16x8 aq0 = *(const bf16x8*)(qrow + quad * 8);
  bf16x8 aq1 = *(const bf16x8*)(qrow + 32 + quad * 8);
  float q0r[4];
#pragma unroll
  for (int r = 0; r < 4; r++) q0r[r] = q0base[tb + quad * 4 + r];

  f32x4 o[4];
#pragma unroll
  for (int dt = 0; dt < 4; dt++) o[dt] = f32x4{0.f, 0.f, 0.f, 0.f};
  float lrow[4] = {0.f, 0.f, 0.f, 0.f};

  // ---- prologue: prefetch tile 0 (s-rows 2sp, 2sp+1 at d-chunk dq) ----
  const bf16* kvbase = qkv + (size_t)b * T_ * 3072 + 1024 + h * 64 + dq * 8;
  bf16x8 kv_a = *(const bf16x8*)(kvbase + (size_t)(2 * sp) * 3072);
  bf16x8 kv_b = *(const bf16x8*)(kvbase + (size_t)(2 * sp + 1) * 3072);
  bf16x8 vv_a = *(const bf16x8*)(kvbase + (size_t)(2 * sp) * 3072 + 1024);
  bf16x8 vv_b = *(const bf16x8*)(kvbase + (size_t)(2 * sp + 1) * 3072 + 1024);
  float k0v = (tid < 64) ? k0base[tid] : 0.f;

  for (int it = 0; it < nIter; ++it) {
    const int s0 = it * 64;
    const int buf = it & 1;
    // ---- commit prefetched tile (K: 2 b128; Vt: 8 packed b32) ----
    *(bf16x8*)&Kls[buf][2 * sp][dq * 8]     = kv_a;
    *(bf16x8*)&Kls[buf][2 * sp + 1][dq * 8] = kv_b;
#pragma unroll
    for (int i2 = 0; i2 < 8; i2++) {
      bf16x2 pr;
      pr[0] = vv_a[i2];
      pr[1] = vv_b[i2];
      *(bf16x2*)&Vt[buf][dq * 8 + i2][2 * sp] = pr;
    }
    if (tid < 64) k0s[buf][tid] = k0v;
    __syncthreads();

    // ---- prefetch NEXT tile (clamped; latency overlaps compute below) ----
    const int s0n = (it + 1 < nIter) ? s0 + 64 : s0;
    kv_a = *(const bf16x8*)(kvbase + (size_t)(s0n + 2 * sp) * 3072);
    kv_b = *(const bf16x8*)(kvbase + (size_t)(s0n + 2 * sp + 1) * 3072);
    vv_a = *(const bf16x8*)(kvbase + (size_t)(s0n + 2 * sp) * 3072 + 1024);
    vv_b = *(const bf16x8*)(kvbase + (size_t)(s0n + 2 * sp + 1) * 3072 + 1024);
    if (tid < 64) k0v = k0base[s0n + tid];

    // ---- S = q @ K^T (four 16-col n-tiles) ----
    f32x4 sc[4];
#pragma unroll
    for (int nt = 0; nt < 4; nt++) {
      sc[nt] = f32x4{0.f, 0.f, 0.f, 0.f};
      bf16x8 b0 = *(const bf16x8*)&Kls[buf][nt * 16 + l16][quad * 8];
      bf16x8 b1 = *(const bf16x8*)&Kls[buf][nt * 16 + l16][32 + quad * 8];
      sc[nt] = __builtin_amdgcn_mfma_f32_16x16x32_bf16(aq0, b0, sc[nt], 0, 0, 0);
      sc[nt] = __builtin_amdgcn_mfma_f32_16x16x32_bf16(aq1, b1, sc[nt], 0, 0, 0);
    }

    // ---- p = exp(-dis) in two 32-col chunks; P roundtrip per chunk ----
    bf16x8 ap[2];
#pragma unroll
    for (int ck = 0; ck < 2; ck++) {
#pragma unroll
      for (int ntl = 0; ntl < 2; ntl++) {
        const int nt = ck * 2 + ntl;
        const float k0c = k0s[buf][nt * 16 + l16];
        const int s = s0 + nt * 16 + l16;
#pragma unroll
        for (int r = 0; r < 4; r++) {
          const int t = tb + quad * 4 + r;
          float lor = sc[nt][r] - q0r[r] * k0c;
          float ratio = fmaxf(-lor * inv_kc, 1.f + 1e-6f);
          float wv = ratio + SQRTF(ratio * ratio - 1.f);
          float p = EXP2F(-sqkc * LOG2F(wv));
          p = (s <= t) ? p : 0.f;
          lrow[r] += p;
          Pl[(quad * 4 + r) * 36 + ntl * 16 + l16] = (bf16)p;
        }
      }
      ap[ck] = *(const bf16x8*)&Pl[l16 * 36 + quad * 8];
    }
#pragma unroll
    for (int dt = 0; dt < 4; dt++) {
      bf16x8 bv0 = *(const bf16x8*)&Vt[buf][dt * 16 + l16][quad * 8];
      bf16x8 bv1 = *(const bf16x8*)&Vt[buf][dt * 16 + l16][32 + quad * 8];
      o[dt] = __builtin_amdgcn_mfma_f32_16x16x32_bf16(ap[0], bv0, o[dt], 0, 0, 0);
      o[dt] = __builtin_amdgcn_mfma_f32_16x16x32_bf16(ap[1], bv1, o[dt], 0, 0, 0);
    }
  }

  // ---- one deferred l-reduction over the 16 l16 lanes, then write O ----
#pragma unroll
  for (int r = 0; r < 4; r++) {
#pragma unroll
    for (int off = 1; off <= 8; off <<= 1) lrow[r] += __shfl_xor(lrow[r], off);
  }
#pragma unroll
  for (int r = 0; r < 4; r++) {
    const float invl = RCPF(lrow[r]);
    const int t = tb + quad * 4 + r;
#pragma unroll
    for (int dt = 0; dt < 4; dt++) {
      float val = o[dt][r] * invl;
      outp[(size_t)(b * T_ + t) * C_ + h * 64 + dt * 16 + l16] = (bf16)val;
    }
  }
}

// =====================  host-side launch  =====================
extern "C" void kernel_launch(void* const* d_in, const int* in_sizes, int n_in,
                              void* d_out, int out_size, void* d_ws, size_t ws_size,
                              hipStream_t stream) {
  const float* x      = (const float*)d_in[0];
  const float* w_qkv  = (const float*)d_in[1];
  const float* w_out  = (const float*)d_in[2];
  const float* kcb    = (const float*)d_in[3];
  const float* w_uv   = (const float*)d_in[4];
  const float* b_uv   = (const float*)d_in[5];
  const float* w_mlp  = (const float*)d_in[6];
  const float* b_mlp  = (const float*)d_in[7];
  float* out = (float*)d_out;

  const size_t MB = 1024ull * 1024ull;
  char* w = (char*)d_ws;
  bf16*  wqkv_b  = (bf16*)(w + 0);          //  6 MB   [0,6)
  bf16*  wout_b  = (bf16*)(w + 6 * MB);     //  2 MB   [6,8)
  bf16*  wuv_p   = (bf16*)(w + 8 * MB);     // 16 MB   [8,24)  row-permuted
  bf16*  wmlp_b  = (bf16*)(w + 24 * MB);    //  8 MB   [24,32)
  bf16*  hbuf    = (bf16*)(w + 32 * MB);    //  8 MB   [32,40)
  bf16*  qkvbuf  = (bf16*)(w + 40 * MB);    // 24 MB   [40,64) dead after attn
  bf16*  attnbuf = (bf16*)(w + 64 * MB);    //  8 MB   [64,72) dead after wout GEMM
  bf16*  gbuf    = (bf16*)(w + 40 * MB);    // 32 MB   [40,72) over qkv+attn (step 7)
  float* x2buf   = (float*)(w + 72 * MB);   // 16 MB   [72,88) fp32
  float* q0b     = (float*)(w + 88 * MB);                 // 256 KB
  float* k0b     = (float*)(w + 88 * MB + 256 * 1024);    // 256 KB
  float* biasp   = (float*)(w + 88 * MB + 512 * 1024);    //  32 KB (permuted b_uv)
  // total: ~88.6 MB

  // 0) weight casts (+w_uv/b_uv row permutation), single launch
  const int total4 = 786432 + 262144 + 2097152 + 1048576 + 2048;
  cast_all_kernel<<<(total4 + 255) / 256, 256, 0, stream>>>(
      w_qkv, w_out, w_uv, w_mlp, b_uv, wqkv_b, wout_b, wuv_p, wmlp_b, biasp);

  // 1) h = rmsnorm(x)
  rmsnorm_kernel<<<M_, 256, 0, stream>>>(x, hbuf);
  // 2) qkv = h @ w_qkv^T
  gemm_bt<0, bf16><<<dim3(M_ / 128, 3072 / 128), 256, 0, stream>>>(
      hbuf, wqkv_b, qkvbuf, nullptr, nullptr, M_, 3072, 1024, 1024);
  // 3) rotary(q,k) in-place + q0/k0
  rotary_kernel<<<(B_ * T_ * H_) / 4, 256, 0, stream>>>(qkvbuf, kcb, q0b, k0b);
  // 4) hyperbolic flash attention
  attn_kernel<<<dim3(B_ * H_, 32), 256, 0, stream>>>(qkvbuf, q0b, k0b, kcb, attnbuf);
  // 5) x2 = x + attn @ w_out^T
  gemm_bt<1, float><<<dim3(M_ / 128, 1024 / 128), 256, 0, stream>>>(
      attnbuf, wout_b, x2buf, nullptr, x, M_, 1024, 1024, 1024);
  // 6) h2 = rmsnorm(x2)
  rmsnorm_kernel<<<M_, 256, 0, stream>>>(x2buf, hbuf);
  // 7) g = swiglu(h2 @ w_uv_p^T + b_uv_p)  -> 4096-col bf16 (fused epilogue)
  gemm_bt<4, bf16><<<dim3(M_ / 128, 8192 / 128), 256, 0, stream>>>(
      hbuf, wuv_p, gbuf, biasp, nullptr, M_, 4096, 1024, 1024);
  // 8) out = x2 + g @ w_mlp^T + b_mlp
  gemm_bt<3, float><<<dim3(M_ / 128, 1024 / 128), 256, 0, stream>>>(
      gbuf, wmlp_b, out, b_mlp, x2buf, M_, 1024, 4096, 4096);
}

// Round 12
// 437.719 us; speedup vs baseline: 1.5809x; 1.0272x over previous
//
#include <hip/hip_runtime.h>
#include <cstdint>
#include <cmath>

typedef __bf16 bf16;
typedef __attribute__((ext_vector_type(8))) __bf16 bf16x8;
typedef __attribute__((ext_vector_type(4))) __bf16 bf16x4;
typedef __attribute__((ext_vector_type(2))) __bf16 bf16x2;
typedef __attribute__((ext_vector_type(4))) float f32x4;

constexpr int B_ = 2, T_ = 2048, C_ = 1024, H_ = 16, HD_ = 64;
constexpr int M_ = B_ * T_;   // 4096

// native 2^x, log2(x), sqrt, rcp
#define EXP2F(x) __builtin_amdgcn_exp2f(x)
#define LOG2F(x) __builtin_amdgcn_logf(x)
#define SQRTF(x) __builtin_amdgcn_sqrtf(x)
#define RCPF(x)  __builtin_amdgcn_rcpf(x)

// ---- async global->LDS, 16B per lane; LDS dest = wave-uniform base + lane*16 ----
__device__ __forceinline__ void gld16(const void* g, void* l) {
  __builtin_amdgcn_global_load_lds((const __attribute__((address_space(1))) void*)g,
                                   (__attribute__((address_space(3))) void*)l, 16, 0, 0);
}

// ============  fused weight cast fp32 -> bf16 (w_uv/b_uv row-PERMUTED)  ============
// Permutation: dst block 128b rows [0,64) = u rows 64b..64b+63, [64,128) = v rows.
// segments (float4 units): qkv 786432 | wout 262144 | wuv 2097152 | wmlp 1048576 | b_uv 2048
__global__ __launch_bounds__(256) void cast_all_kernel(const float* __restrict__ s0,
                                                       const float* __restrict__ s1,
                                                       const float* __restrict__ s2,
                                                       const float* __restrict__ s3,
                                                       const float* __restrict__ s4,
                                                       bf16* __restrict__ d0,
                                                       bf16* __restrict__ d1,
                                                       bf16* __restrict__ d2,
                                                       bf16* __restrict__ d3,
                                                       float* __restrict__ d4) {
  size_t gid = (size_t)blockIdx.x * 256 + threadIdx.x;
  if (gid >= 786432 + 262144 + 2097152 + 1048576) {
    // b_uv permute (fp32 -> fp32), 4 consecutive rows stay contiguous
    size_t g4 = gid - (786432 + 262144 + 2097152 + 1048576);
    if (g4 >= 2048) return;
    int r = (int)(g4 * 4);
    int dr;
    if (r < 4096) { int blk = r >> 6, i = r & 63; dr = blk * 128 + i; }
    else { int j = r - 4096; int blk = j >> 6, i = j & 63; dr = blk * 128 + 64 + i; }
    *(f32x4*)(d4 + dr) = *(const f32x4*)(s4 + r);
    return;
  }
  const float* src;
  bf16* dst;
  size_t dstoff;
  if (gid < 786432) { src = s0; dst = d0; dstoff = gid * 4; }
  else if (gid < 786432 + 262144) { gid -= 786432; src = s1; dst = d1; dstoff = gid * 4; }
  else if (gid < 786432 + 262144 + 2097152) {
    gid -= 786432 + 262144; src = s2; dst = d2;
    // permute w_uv rows
    size_t elem = gid * 4;
    int r = (int)(elem >> 10), c = (int)(elem & 1023);
    int dr;
    if (r < 4096) { int blk = r >> 6, i = r & 63; dr = blk * 128 + i; }
    else { int j = r - 4096; int blk = j >> 6, i = j & 63; dr = blk * 128 + 64 + i; }
    dstoff = ((size_t)dr << 10) | (size_t)c;
  }
  else { gid -= 786432 + 262144 + 2097152; src = s3; dst = d3; dstoff = gid * 4; }
  f32x4 v = *(const f32x4*)(src + gid * 4);
  bf16x4 o;
  o[0] = (bf16)v[0]; o[1] = (bf16)v[1]; o[2] = (bf16)v[2]; o[3] = (bf16)v[3];
  *(bf16x4*)(dst + dstoff) = o;
}

// =============  GEMM: C = A @ Bw^T (+bias)(+residual)(+swiglu), bf16 operands  =============
// BK=64 as two stacked [128][32] half-tiles; one barrier pair per 64 K.
// MODE 0: C=AB   MODE 1: +R   MODE 2: +bias   MODE 3: +bias+R
// MODE 4: swiglu over permuted-uv (block cols [u0..63|v0..63]). IN-WAVE u/v pairing:
//   wave (wave>>1) takes B-cols {wn2..wn2+31} (u, nt 0-1) and {64+wn2..+31} (v, nt 2-3),
//   wn2=(wave>>1)*32 -> u and v for one output col live in the same lane; epilogue is
//   register-only (no LDS exchange, no extra barrier, all 4 waves store).
template <int MODE, typename OutT>
__global__ __launch_bounds__(256) void gemm_bt(const bf16* __restrict__ A,
                                               const bf16* __restrict__ Bw,
                                               OutT* __restrict__ Cmat,
                                               const float* __restrict__ bias,
                                               const float* __restrict__ R,
                                               int M, int N, int K, int lda) {
  __shared__ __align__(16) bf16 shmem[4 * 128 * 32];   // exactly 32768 B
  bf16* const AlsH[2] = { &shmem[0], &shmem[4096] };
  bf16* const BlsH[2] = { &shmem[2 * 4096], &shmem[3 * 4096] };
  const int tid  = threadIdx.x;
  const int wave = tid >> 6;
  const int lane = tid & 63;
  const int quad = lane >> 4;
  const int l16  = lane & 15;
  const int bm = blockIdx.x * 128;
  const int bn = blockIdx.y * 128;
  const int wm = (wave & 1) * 64;
  const int wn = (wave >> 1) * 64;
  const int wn2 = (wave >> 1) * 32;
  const int srow   = lane >> 2;  // 0..15
  const int schunk = lane & 3;   // 0..3

  f32x4 acc[4][4];
#pragma unroll
  for (int i = 0; i < 4; i++)
#pragma unroll
    for (int j = 0; j < 4; j++) acc[i][j] = f32x4{0.f, 0.f, 0.f, 0.f};

  const bf16* Ag = A  + (size_t)(bm + wave * 32 + srow) * lda + schunk * 8;
  const bf16* Bg = Bw + (size_t)(bn + wave * 32 + srow) * K   + schunk * 8;
  bf16* AlsW0 = AlsH[0] + (wave * 32) * 32;
  bf16* AlsW1 = AlsH[1] + (wave * 32) * 32;
  bf16* BlsW0 = BlsH[0] + (wave * 32) * 32;
  bf16* BlsW1 = BlsH[1] + (wave * 32) * 32;

  for (int k0 = 0; k0 < K; k0 += 64) {
    gld16(Ag + k0,                         AlsW0);
    gld16(Ag + k0 + (size_t)16 * lda,      AlsW0 + 16 * 32);
    gld16(Ag + k0 + 32,                    AlsW1);
    gld16(Ag + k0 + 32 + (size_t)16 * lda, AlsW1 + 16 * 32);
    gld16(Bg + k0,                         BlsW0);
    gld16(Bg + k0 + (size_t)16 * K,        BlsW0 + 16 * 32);
    gld16(Bg + k0 + 32,                    BlsW1);
    gld16(Bg + k0 + 32 + (size_t)16 * K,   BlsW1 + 16 * 32);
    __syncthreads();   // drains vmcnt before barrier

#pragma unroll
    for (int hh = 0; hh < 2; hh++) {
      bf16x8 af[4], bfr[4];
#pragma unroll
      for (int mt = 0; mt < 4; mt++)
        af[mt] = *(const bf16x8*)&AlsH[hh][(wm + mt * 16 + l16) * 32 + quad * 8];
#pragma unroll
      for (int nt = 0; nt < 4; nt++) {
        const int cb = (MODE == 4)
                         ? ((nt < 2) ? (wn2 + nt * 16) : (64 + wn2 + (nt - 2) * 16))
                         : (wn + nt * 16);
        bfr[nt] = *(const bf16x8*)&BlsH[hh][(cb + l16) * 32 + quad * 8];
      }
#pragma unroll
      for (int mt = 0; mt < 4; mt++)
#pragma unroll
        for (int nt = 0; nt < 4; nt++)
          acc[mt][nt] = __builtin_amdgcn_mfma_f32_16x16x32_bf16(af[mt], bfr[nt], acc[mt][nt], 0, 0, 0);
    }
    __syncthreads();
  }

  if (MODE != 4) {
    // epilogue: D row = wm+mt*16+quad*4+r, col = wn+nt*16+l16
#pragma unroll
    for (int mt = 0; mt < 4; mt++) {
      const int row = bm + wm + mt * 16 + quad * 4;
#pragma unroll
      for (int nt = 0; nt < 4; nt++) {
        const int col = bn + wn + nt * 16 + l16;
        float bval = 0.f;
        if (MODE & 2) bval = bias[col];
#pragma unroll
        for (int r = 0; r < 4; r++) {
          float v = acc[mt][nt][r] + bval;
          if (MODE & 1) v += R[(size_t)(row + r) * N + col];
          Cmat[(size_t)(row + r) * N + col] = (OutT)v;
        }
      }
    }
  } else {
    // register-only swiglu epilogue: u = acc[mt][ntl], v = acc[mt][ntl+2]
    const int colg0 = (bn >> 1) + wn2;
#pragma unroll
    for (int mt = 0; mt < 4; mt++) {
      const int row = bm + wm + mt * 16 + quad * 4;
#pragma unroll
      for (int ntl = 0; ntl < 2; ntl++) {
        const float bu = bias[bn + wn2 + ntl * 16 + l16];
        const float bv = bias[bn + 64 + wn2 + ntl * 16 + l16];
        const int col = colg0 + ntl * 16 + l16;
#pragma unroll
        for (int r = 0; r < 4; r++) {
          float u = acc[mt][ntl][r] + bu;
          float v = acc[mt][ntl + 2][r] + bv;
          float sig = RCPF(1.f + EXP2F(-v * 1.44269504f));
          Cmat[(size_t)(row + r) * N + col] = (OutT)(u * v * sig);
        }
      }
    }
  }
}

// =====================  RMSNorm: fp32 in -> bf16 out (row = 1024)  =====================
__global__ __launch_bounds__(256) void rmsnorm_kernel(const float* __restrict__ X,
                                                      bf16* __restrict__ O) {
  const int row = blockIdx.x;
  const int tid = threadIdx.x;
  const int wave = tid >> 6;
  f32x4 v = *(const f32x4*)(X + (size_t)row * C_ + tid * 4);
  float s = v[0] * v[0] + v[1] * v[1] + v[2] * v[2] + v[3] * v[3];
#pragma unroll
  for (int off = 32; off >= 1; off >>= 1) s += __shfl_xor(s, off);
  __shared__ float wsum[4];
  __shared__ float scale_sh;
  if ((tid & 63) == 0) wsum[wave] = s;
  __syncthreads();
  if (tid == 0)
    scale_sh = rsqrtf((wsum[0] + wsum[1] + wsum[2] + wsum[3]) * (1.f / (float)C_) + 1e-6f);
  __syncthreads();
  const float sc = scale_sh;
  bf16x4 o;
  o[0] = (bf16)(v[0] * sc); o[1] = (bf16)(v[1] * sc);
  o[2] = (bf16)(v[2] * sc); o[3] = (bf16)(v[3] * sc);
  *(bf16x4*)(O + (size_t)row * C_ + tid * 4) = o;
}

// ==========  Rotary on q,k (bf16, in-place) + q0/k0 = sqrt(kc + |.|^2)  ==========
__global__ __launch_bounds__(256) void rotary_kernel(bf16* __restrict__ qkv,
                                                     const float* __restrict__ kcb,
                                                     float* __restrict__ q0b,
                                                     float* __restrict__ k0b) {
  const int wid  = blockIdx.x * 4 + (threadIdx.x >> 6);  // one wave per (b,t,h)
  const int lane = threadIdx.x & 63;
  const int b = wid >> 15;          // T_*H_ = 32768
  const int rem = wid & 32767;
  const int t = rem >> 4;
  const int h = rem & 15;
  const int i = lane & 31;
  const float invf = expf(-((float)i / 32.f) * 9.210340371976184f);  // 10000^(-i/32)
  const float ang = (float)t * invf;
  const float cx = cosf(ang), sx = sinf(ang);
  const float kc = kcb[h];
  bf16* qp = qkv + (size_t)(b * T_ + t) * 3072 + h * 64;

#pragma unroll
  for (int which = 0; which < 2; which++) {
    bf16* p = qp + which * 1024;   // q then k
    float x1 = (float)p[i];
    float x2 = (float)p[i + 32];
    float o = (lane < 32) ? (x1 * cx + x2 * sx) : (x2 * cx - x1 * sx);
    float ss = o * o;
#pragma unroll
    for (int off = 32; off >= 1; off >>= 1) ss += __shfl_xor(ss, off);
    p[lane] = (bf16)o;
    if (lane == 0) {
      float* dst = which == 0 ? q0b : k0b;
      dst[(size_t)(b * H_ + h) * T_ + t] = SQRTF(kc + ss);
    }
  }
}

// =====================  Hyperbolic flash attention (v7)  =====================
// Packed ds_write_b32 Vt staging; LDS double-buffer; single barrier per 64-tile;
// register prefetch; LPT order. Scores in (0,1], row-sum >= 1: no online max.
__global__ __launch_bounds__(256) void attn_kernel(const bf16* __restrict__ qkv,
                                                   const float* __restrict__ q0b,
                                                   const float* __restrict__ k0b,
                                                   const float* __restrict__ kcb,
                                                   bf16* __restrict__ outp) {
  __shared__ __align__(16) bf16 Kls[2][64][72];  // K tile [s][d]
  __shared__ __align__(16) bf16 Vt[2][64][68];   // V^T [d][s]
  __shared__ __align__(16) bf16 Pls[4][16 * 36]; // per-wave P chunk buffer
  __shared__ float k0s[2][64];

  const int tid = threadIdx.x;
  const int wave = tid >> 6, lane = tid & 63;
  const int quad = lane >> 4, l16 = lane & 15;
  const int bh = blockIdx.x;
  const int b = bh >> 4, h = bh & 15;

  const float kc = kcb[h];
  const float inv_kc = 1.f / kc;
  const float sqkc = SQRTF(kc);
  const int sp = tid & 31, dq = tid >> 5;   // sp 0..31 (s-pairs), dq 0..7 (d-chunks)
  bf16* Pl = Pls[wave];
  const float* q0base = q0b + (size_t)(b * H_ + h) * T_;
  const float* k0base = k0b + (size_t)(b * H_ + h) * T_;

  const int ty = 31 - (int)blockIdx.y;   // heaviest blocks dispatch first
  const int t0 = ty * 64;
  const int tb = t0 + wave * 16;
  const int nIter = ty + 1;

  // q A-frags: A[m=l16][k=quad*8+j]
  const bf16* qrow = qkv + (size_t)(b * T_ + tb + l16) * 3072 + h * 64;
  bf16x8 aq0 = *(const bf16x8*)(qrow + quad * 8);
  bf16x8 aq1 = *(const bf16x8*)(qrow + 32 + quad * 8);
  float q0r[4];
#pragma unroll
  for (int r = 0; r < 4; r++) q0r[r] = q0base[tb + quad * 4 + r];

  f32x4 o[4];
#pragma unroll
  for (int dt = 0; dt < 4; dt++) o[dt] = f32x4{0.f, 0.f, 0.f, 0.f};
  float lrow[4] = {0.f, 0.f, 0.f, 0.f};

  // ---- prologue: prefetch tile 0 (s-rows 2sp, 2sp+1 at d-chunk dq) ----
  const bf16* kvbase = qkv + (size_t)b * T_ * 3072 + 1024 + h * 64 + dq * 8;
  bf16x8 kv_a = *(const bf16x8*)(kvbase + (size_t)(2 * sp) * 3072);
  bf16x8 kv_b = *(const bf16x8*)(kvbase + (size_t)(2 * sp + 1) * 3072);
  bf16x8 vv_a = *(const bf16x8*)(kvbase + (size_t)(2 * sp) * 3072 + 1024);
  bf16x8 vv_b = *(const bf16x8*)(kvbase + (size_t)(2 * sp + 1) * 3072 + 1024);
  float k0v = (tid < 64) ? k0base[tid] : 0.f;

  for (int it = 0; it < nIter; ++it) {
    const int s0 = it * 64;
    const int buf = it & 1;
    // ---- commit prefetched tile (K: 2 b128; Vt: 8 packed b32) ----
    *(bf16x8*)&Kls[buf][2 * sp][dq * 8]     = kv_a;
    *(bf16x8*)&Kls[buf][2 * sp + 1][dq * 8] = kv_b;
#pragma unroll
    for (int i2 = 0; i2 < 8; i2++) {
      bf16x2 pr;
      pr[0] = vv_a[i2];
      pr[1] = vv_b[i2];
      *(bf16x2*)&Vt[buf][dq * 8 + i2][2 * sp] = pr;
    }
    if (tid < 64) k0s[buf][tid] = k0v;
    __syncthreads();

    // ---- prefetch NEXT tile (clamped; latency overlaps compute below) ----
    const int s0n = (it + 1 < nIter) ? s0 + 64 : s0;
    kv_a = *(const bf16x8*)(kvbase + (size_t)(s0n + 2 * sp) * 3072);
    kv_b = *(const bf16x8*)(kvbase + (size_t)(s0n + 2 * sp + 1) * 3072);
    vv_a = *(const bf16x8*)(kvbase + (size_t)(s0n + 2 * sp) * 3072 + 1024);
    vv_b = *(const bf16x8*)(kvbase + (size_t)(s0n + 2 * sp + 1) * 3072 + 1024);
    if (tid < 64) k0v = k0base[s0n + tid];

    // ---- S = q @ K^T (four 16-col n-tiles) ----
    f32x4 sc[4];
#pragma unroll
    for (int nt = 0; nt < 4; nt++) {
      sc[nt] = f32x4{0.f, 0.f, 0.f, 0.f};
      bf16x8 b0 = *(const bf16x8*)&Kls[buf][nt * 16 + l16][quad * 8];
      bf16x8 b1 = *(const bf16x8*)&Kls[buf][nt * 16 + l16][32 + quad * 8];
      sc[nt] = __builtin_amdgcn_mfma_f32_16x16x32_bf16(aq0, b0, sc[nt], 0, 0, 0);
      sc[nt] = __builtin_amdgcn_mfma_f32_16x16x32_bf16(aq1, b1, sc[nt], 0, 0, 0);
    }

    // ---- p = exp(-dis) in two 32-col chunks; P roundtrip per chunk ----
    bf16x8 ap[2];
#pragma unroll
    for (int ck = 0; ck < 2; ck++) {
#pragma unroll
      for (int ntl = 0; ntl < 2; ntl++) {
        const int nt = ck * 2 + ntl;
        const float k0c = k0s[buf][nt * 16 + l16];
        const int s = s0 + nt * 16 + l16;
#pragma unroll
        for (int r = 0; r < 4; r++) {
          const int t = tb + quad * 4 + r;
          float lor = sc[nt][r] - q0r[r] * k0c;
          float ratio = fmaxf(-lor * inv_kc, 1.f + 1e-6f);
          float wv = ratio + SQRTF(ratio * ratio - 1.f);
          float p = EXP2F(-sqkc * LOG2F(wv));
          p = (s <= t) ? p : 0.f;
          lrow[r] += p;
          Pl[(quad * 4 + r) * 36 + ntl * 16 + l16] = (bf16)p;
        }
      }
      ap[ck] = *(const bf16x8*)&Pl[l16 * 36 + quad * 8];
    }
#pragma unroll
    for (int dt = 0; dt < 4; dt++) {
      bf16x8 bv0 = *(const bf16x8*)&Vt[buf][dt * 16 + l16][quad * 8];
      bf16x8 bv1 = *(const bf16x8*)&Vt[buf][dt * 16 + l16][32 + quad * 8];
      o[dt] = __builtin_amdgcn_mfma_f32_16x16x32_bf16(ap[0], bv0, o[dt], 0, 0, 0);
      o[dt] = __builtin_amdgcn_mfma_f32_16x16x32_bf16(ap[1], bv1, o[dt], 0, 0, 0);
    }
  }

  // ---- one deferred l-reduction over the 16 l16 lanes, then write O ----
#pragma unroll
  for (int r = 0; r < 4; r++) {
#pragma unroll
    for (int off = 1; off <= 8; off <<= 1) lrow[r] += __shfl_xor(lrow[r], off);
  }
#pragma unroll
  for (int r = 0; r < 4; r++) {
    const float invl = RCPF(lrow[r]);
    const int t = tb + quad * 4 + r;
#pragma unroll
    for (int dt = 0; dt < 4; dt++) {
      float val = o[dt][r] * invl;
      outp[(size_t)(b * T_ + t) * C_ + h * 64 + dt * 16 + l16] = (bf16)val;
    }
  }
}

// =====================  host-side launch  =====================
extern "C" void kernel_launch(void* const* d_in, const int* in_sizes, int n_in,
                              void* d_out, int out_size, void* d_ws, size_t ws_size,
                              hipStream_t stream) {
  const float* x      = (const float*)d_in[0];
  const float* w_qkv  = (const float*)d_in[1];
  const float* w_out  = (const float*)d_in[2];
  const float* kcb    = (const float*)d_in[3];
  const float* w_uv   = (const float*)d_in[4];
  const float* b_uv   = (const float*)d_in[5];
  const float* w_mlp  = (const float*)d_in[6];
  const float* b_mlp  = (const float*)d_in[7];
  float* out = (float*)d_out;

  const size_t MB = 1024ull * 1024ull;
  char* w = (char*)d_ws;
  bf16*  wqkv_b  = (bf16*)(w + 0);          //  6 MB   [0,6)
  bf16*  wout_b  = (bf16*)(w + 6 * MB);     //  2 MB   [6,8)
  bf16*  wuv_p   = (bf16*)(w + 8 * MB);     // 16 MB   [8,24)  row-permuted
  bf16*  wmlp_b  = (bf16*)(w + 24 * MB);    //  8 MB   [24,32)
  bf16*  hbuf    = (bf16*)(w + 32 * MB);    //  8 MB   [32,40)
  bf16*  qkvbuf  = (bf16*)(w + 40 * MB);    // 24 MB   [40,64) dead after attn
  bf16*  attnbuf = (bf16*)(w + 64 * MB);    //  8 MB   [64,72) dead after wout GEMM
  bf16*  gbuf    = (bf16*)(w + 40 * MB);    // 32 MB   [40,72) over qkv+attn (step 7)
  float* x2buf   = (float*)(w + 72 * MB);   // 16 MB   [72,88) fp32
  float* q0b     = (float*)(w + 88 * MB);                 // 256 KB
  float* k0b     = (float*)(w + 88 * MB + 256 * 1024);    // 256 KB
  float* biasp   = (float*)(w + 88 * MB + 512 * 1024);    //  32 KB (permuted b_uv)
  // total: ~88.6 MB

  // 0) weight casts (+w_uv/b_uv row permutation), single launch
  const int total4 = 786432 + 262144 + 2097152 + 1048576 + 2048;
  cast_all_kernel<<<(total4 + 255) / 256, 256, 0, stream>>>(
      w_qkv, w_out, w_uv, w_mlp, b_uv, wqkv_b, wout_b, wuv_p, wmlp_b, biasp);

  // 1) h = rmsnorm(x)
  rmsnorm_kernel<<<M_, 256, 0, stream>>>(x, hbuf);
  // 2) qkv = h @ w_qkv^T
  gemm_bt<0, bf16><<<dim3(M_ / 128, 3072 / 128), 256, 0, stream>>>(
      hbuf, wqkv_b, qkvbuf, nullptr, nullptr, M_, 3072, 1024, 1024);
  // 3) rotary(q,k) in-place + q0/k0
  rotary_kernel<<<(B_ * T_ * H_) / 4, 256, 0, stream>>>(qkvbuf, kcb, q0b, k0b);
  // 4) hyperbolic flash attention
  attn_kernel<<<dim3(B_ * H_, 32), 256, 0, stream>>>(qkvbuf, q0b, k0b, kcb, attnbuf);
  // 5) x2 = x + attn @ w_out^T
  gemm_bt<1, float><<<dim3(M_ / 128, 1024 / 128), 256, 0, stream>>>(
      attnbuf, wout_b, x2buf, nullptr, x, M_, 1024, 1024, 1024);
  // 6) h2 = rmsnorm(x2)
  rmsnorm_kernel<<<M_, 256, 0, stream>>>(x2buf, hbuf);
  // 7) g = swiglu(h2 @ w_uv_p^T + b_uv_p)  -> 4096-col bf16 (register-only epilogue)
  gemm_bt<4, bf16><<<dim3(M_ / 128, 8192 / 128), 256, 0, stream>>>(
      hbuf, wuv_p, gbuf, biasp, nullptr, M_, 4096, 1024, 1024);
  // 8) out = x2 + g @ w_mlp^T + b_mlp
  gemm_bt<3, float><<<dim3(M_ / 128, 1024 / 128), 256, 0, stream>>>(
      gbuf, wmlp_b, out, b_mlp, x2buf, M_, 1024, 4096, 4096);
}

// Round 13
// 416.309 us; speedup vs baseline: 1.6622x; 1.0514x over previous
//
#include <hip/hip_runtime.h>
#include <cstdint>
#include <cmath>

typedef __bf16 bf16;
typedef __attribute__((ext_vector_type(8))) __bf16 bf16x8;
typedef __attribute__((ext_vector_type(4))) __bf16 bf16x4;
typedef __attribute__((ext_vector_type(2))) __bf16 bf16x2;
typedef __attribute__((ext_vector_type(4))) float f32x4;

constexpr int B_ = 2, T_ = 2048, C_ = 1024, H_ = 16, HD_ = 64;
constexpr int M_ = B_ * T_;   // 4096

#define EXP2F(x) __builtin_amdgcn_exp2f(x)
#define LOG2F(x) __builtin_amdgcn_logf(x)
#define SQRTF(x) __builtin_amdgcn_sqrtf(x)
#define RCPF(x)  __builtin_amdgcn_rcpf(x)

// ---- async global->LDS, 16B per lane; LDS dest = wave-uniform base + lane*16 ----
__device__ __forceinline__ void gld16(const void* g, void* l) {
  __builtin_amdgcn_global_load_lds((const __attribute__((address_space(1))) void*)g,
                                   (__attribute__((address_space(3))) void*)l, 16, 0, 0);
}

// ============  fused weight cast fp32 -> bf16 (w_uv/b_uv row-PERMUTED)  ============
__global__ __launch_bounds__(256) void cast_all_kernel(const float* __restrict__ s0,
                                                       const float* __restrict__ s1,
                                                       const float* __restrict__ s2,
                                                       const float* __restrict__ s3,
                                                       const float* __restrict__ s4,
                                                       bf16* __restrict__ d0,
                                                       bf16* __restrict__ d1,
                                                       bf16* __restrict__ d2,
                                                       bf16* __restrict__ d3,
                                                       float* __restrict__ d4) {
  size_t gid = (size_t)blockIdx.x * 256 + threadIdx.x;
  if (gid >= 786432 + 262144 + 2097152 + 1048576) {
    size_t g4 = gid - (786432 + 262144 + 2097152 + 1048576);
    if (g4 >= 2048) return;
    int r = (int)(g4 * 4);
    int dr;
    if (r < 4096) { int blk = r >> 6, i = r & 63; dr = blk * 128 + i; }
    else { int j = r - 4096; int blk = j >> 6, i = j & 63; dr = blk * 128 + 64 + i; }
    *(f32x4*)(d4 + dr) = *(const f32x4*)(s4 + r);
    return;
  }
  const float* src;
  bf16* dst;
  size_t dstoff;
  if (gid < 786432) { src = s0; dst = d0; dstoff = gid * 4; }
  else if (gid < 786432 + 262144) { gid -= 786432; src = s1; dst = d1; dstoff = gid * 4; }
  else if (gid < 786432 + 262144 + 2097152) {
    gid -= 786432 + 262144; src = s2; dst = d2;
    size_t elem = gid * 4;
    int r = (int)(elem >> 10), c = (int)(elem & 1023);
    int dr;
    if (r < 4096) { int blk = r >> 6, i = r & 63; dr = blk * 128 + i; }
    else { int j = r - 4096; int blk = j >> 6, i = j & 63; dr = blk * 128 + 64 + i; }
    dstoff = ((size_t)dr << 10) | (size_t)c;
  }
  else { gid -= 786432 + 262144 + 2097152; src = s3; dst = d3; dstoff = gid * 4; }
  f32x4 v = *(const f32x4*)(src + gid * 4);
  bf16x4 o;
  o[0] = (bf16)v[0]; o[1] = (bf16)v[1]; o[2] = (bf16)v[2]; o[3] = (bf16)v[3];
  *(bf16x4*)(dst + dstoff) = o;
}

// =============  GEMM: C = A @ Bw^T (+bias)(+residual)(+swiglu), bf16 operands  =============
// BK=64 (two stacked [BM][32] A half-tiles + [128][32] B halves); one barrier pair/64K.
// BM=128: 4 waves cover 128x128 (acc 4x4).  BM=64: 4 waves cover 64x128 (acc 2x4,
// 32 AGPRs) -> grid doubles to 2 blocks/CU for N=1024 shapes (barrier-drain overlap).
// MODE 0: C=AB  1: +R  2: +bias  3: +bias+R
// MODE 4 (BM=128 only): swiglu over permuted-uv, in-wave u/v pairing, register-only.
template <int MODE, typename OutT, int BM = 128>
__global__ __launch_bounds__(256) void gemm_bt(const bf16* __restrict__ A,
                                               const bf16* __restrict__ Bw,
                                               OutT* __restrict__ Cmat,
                                               const float* __restrict__ bias,
                                               const float* __restrict__ R,
                                               int M, int N, int K, int lda) {
  __shared__ __align__(16) bf16 shmem[(2 * BM + 2 * 128) * 32];
  bf16* const AlsH[2] = { &shmem[0], &shmem[BM * 32] };
  bf16* const BlsH[2] = { &shmem[2 * BM * 32], &shmem[2 * BM * 32 + 4096] };
  const int tid  = threadIdx.x;
  const int wave = tid >> 6;
  const int lane = tid & 63;
  const int quad = lane >> 4;
  const int l16  = lane & 15;
  const int bm = blockIdx.x * BM;
  const int bn = blockIdx.y * 128;
  const int wm = (wave & 1) * (BM / 2);
  const int wn = (wave >> 1) * 64;
  const int wn2 = (wave >> 1) * 32;
  const int srow   = lane >> 2;  // 0..15
  const int schunk = lane & 3;   // 0..3
  constexpr int MT = BM / 32;    // m-tiles per wave

  f32x4 acc[MT][4];
#pragma unroll
  for (int i = 0; i < MT; i++)
#pragma unroll
    for (int j = 0; j < 4; j++) acc[i][j] = f32x4{0.f, 0.f, 0.f, 0.f};

  const bf16* Ag = A  + (size_t)(bm + wave * (BM / 4) + srow) * lda + schunk * 8;
  const bf16* Bg = Bw + (size_t)(bn + wave * 32 + srow) * K   + schunk * 8;
  bf16* AlsW0 = AlsH[0] + (wave * (BM / 4)) * 32;
  bf16* AlsW1 = AlsH[1] + (wave * (BM / 4)) * 32;
  bf16* BlsW0 = BlsH[0] + (wave * 32) * 32;
  bf16* BlsW1 = BlsH[1] + (wave * 32) * 32;

  for (int k0 = 0; k0 < K; k0 += 64) {
    gld16(Ag + k0, AlsW0);
    if (BM == 128) gld16(Ag + k0 + (size_t)16 * lda, AlsW0 + 16 * 32);
    gld16(Ag + k0 + 32, AlsW1);
    if (BM == 128) gld16(Ag + k0 + 32 + (size_t)16 * lda, AlsW1 + 16 * 32);
    gld16(Bg + k0,                       BlsW0);
    gld16(Bg + k0 + (size_t)16 * K,      BlsW0 + 16 * 32);
    gld16(Bg + k0 + 32,                  BlsW1);
    gld16(Bg + k0 + 32 + (size_t)16 * K, BlsW1 + 16 * 32);
    __syncthreads();   // drains vmcnt before barrier

#pragma unroll
    for (int hh = 0; hh < 2; hh++) {
      bf16x8 af[MT], bfr[4];
#pragma unroll
      for (int mt = 0; mt < MT; mt++)
        af[mt] = *(const bf16x8*)&AlsH[hh][(wm + mt * 16 + l16) * 32 + quad * 8];
#pragma unroll
      for (int nt = 0; nt < 4; nt++) {
        const int cb = (MODE == 4)
                         ? ((nt < 2) ? (wn2 + nt * 16) : (64 + wn2 + (nt - 2) * 16))
                         : (wn + nt * 16);
        bfr[nt] = *(const bf16x8*)&BlsH[hh][(cb + l16) * 32 + quad * 8];
      }
#pragma unroll
      for (int mt = 0; mt < MT; mt++)
#pragma unroll
        for (int nt = 0; nt < 4; nt++)
          acc[mt][nt] = __builtin_amdgcn_mfma_f32_16x16x32_bf16(af[mt], bfr[nt], acc[mt][nt], 0, 0, 0);
    }
    __syncthreads();
  }

  if (MODE != 4) {
#pragma unroll
    for (int mt = 0; mt < MT; mt++) {
      const int row = bm + wm + mt * 16 + quad * 4;
#pragma unroll
      for (int nt = 0; nt < 4; nt++) {
        const int col = bn + wn + nt * 16 + l16;
        float bval = 0.f;
        if (MODE & 2) bval = bias[col];
#pragma unroll
        for (int r = 0; r < 4; r++) {
          float v = acc[mt][nt][r] + bval;
          if (MODE & 1) v += R[(size_t)(row + r) * N + col];
          Cmat[(size_t)(row + r) * N + col] = (OutT)v;
        }
      }
    }
  } else {
    // register-only swiglu epilogue: u = acc[mt][ntl], v = acc[mt][ntl+2]
    const int colg0 = (bn >> 1) + wn2;
#pragma unroll
    for (int mt = 0; mt < MT; mt++) {
      const int row = bm + wm + mt * 16 + quad * 4;
#pragma unroll
      for (int ntl = 0; ntl < 2; ntl++) {
        const float bu = bias[bn + wn2 + ntl * 16 + l16];
        const float bv = bias[bn + 64 + wn2 + ntl * 16 + l16];
        const int col = colg0 + ntl * 16 + l16;
#pragma unroll
        for (int r = 0; r < 4; r++) {
          float u = acc[mt][ntl][r] + bu;
          float v = acc[mt][ntl + 2][r] + bv;
          float sig = RCPF(1.f + EXP2F(-v * 1.44269504f));
          Cmat[(size_t)(row + r) * N + col] = (OutT)(u * v * sig);
        }
      }
    }
  }
}

// =====================  RMSNorm: fp32 in -> bf16 out (row = 1024)  =====================
__global__ __launch_bounds__(256) void rmsnorm_kernel(const float* __restrict__ X,
                                                      bf16* __restrict__ O) {
  const int row = blockIdx.x;
  const int tid = threadIdx.x;
  const int wave = tid >> 6;
  f32x4 v = *(const f32x4*)(X + (size_t)row * C_ + tid * 4);
  float s = v[0] * v[0] + v[1] * v[1] + v[2] * v[2] + v[3] * v[3];
#pragma unroll
  for (int off = 32; off >= 1; off >>= 1) s += __shfl_xor(s, off);
  __shared__ float wsum[4];
  __shared__ float scale_sh;
  if ((tid & 63) == 0) wsum[wave] = s;
  __syncthreads();
  if (tid == 0)
    scale_sh = rsqrtf((wsum[0] + wsum[1] + wsum[2] + wsum[3]) * (1.f / (float)C_) + 1e-6f);
  __syncthreads();
  const float sc = scale_sh;
  bf16x4 o;
  o[0] = (bf16)(v[0] * sc); o[1] = (bf16)(v[1] * sc);
  o[2] = (bf16)(v[2] * sc); o[3] = (bf16)(v[3] * sc);
  *(bf16x4*)(O + (size_t)row * C_ + tid * 4) = o;
}

// ==========  Rotary on q,k (bf16, in-place) + q0/k0 = sqrt(kc + |.|^2)  ==========
__global__ __launch_bounds__(256) void rotary_kernel(bf16* __restrict__ qkv,
                                                     const float* __restrict__ kcb,
                                                     float* __restrict__ q0b,
                                                     float* __restrict__ k0b) {
  const int wid  = blockIdx.x * 4 + (threadIdx.x >> 6);  // one wave per (b,t,h)
  const int lane = threadIdx.x & 63;
  const int b = wid >> 15;          // T_*H_ = 32768
  const int rem = wid & 32767;
  const int t = rem >> 4;
  const int h = rem & 15;
  const int i = lane & 31;
  const float invf = expf(-((float)i / 32.f) * 9.210340371976184f);  // 10000^(-i/32)
  const float ang = (float)t * invf;
  const float cx = cosf(ang), sx = sinf(ang);
  const float kc = kcb[h];
  bf16* qp = qkv + (size_t)(b * T_ + t) * 3072 + h * 64;

#pragma unroll
  for (int which = 0; which < 2; which++) {
    bf16* p = qp + which * 1024;   // q then k
    float x1 = (float)p[i];
    float x2 = (float)p[i + 32];
    float o = (lane < 32) ? (x1 * cx + x2 * sx) : (x2 * cx - x1 * sx);
    float ss = o * o;
#pragma unroll
    for (int off = 32; off >= 1; off >>= 1) ss += __shfl_xor(ss, off);
    p[lane] = (bf16)o;
    if (lane == 0) {
      float* dst = which == 0 ? q0b : k0b;
      dst[(size_t)(b * H_ + h) * T_ + t] = SQRTF(kc + ss);
    }
  }
}

// =====================  Hyperbolic flash attention (v8)  =====================
// 512-thread blocks, 128 q-rows each (8 waves x 16 rows), grid (B*H, 16): each
// K/V tile staged ONCE for 8 consuming waves (chip-wide stagings/barriers halve
// vs v7). Staging crews: tid<256 stages K (2 rows/thread), tid>=256 stages V
// (packed b32 transpose). LDS double-buffer, single barrier/tile, register
// prefetch, LPT (ty = 15 - blockIdx.y). Causal guard s0 <= tb+15 predicates
// the lower waves off the final diagonal tile.
__global__ __launch_bounds__(512) void attn_kernel(const bf16* __restrict__ qkv,
                                                   const float* __restrict__ q0b,
                                                   const float* __restrict__ k0b,
                                                   const float* __restrict__ kcb,
                                                   bf16* __restrict__ outp) {
  __shared__ __align__(16) bf16 Kls[2][64][72];
  __shared__ __align__(16) bf16 Vt[2][64][68];
  __shared__ __align__(16) bf16 Pls[8][16 * 36];
  __shared__ float k0s[2][64];

  const int tid = threadIdx.x;
  const int wave = tid >> 6, lane = tid & 63;
  const int quad = lane >> 4, l16 = lane & 15;
  const int bh = blockIdx.x;
  const int b = bh >> 4, h = bh & 15;

  const float kc = kcb[h];
  const float inv_kc = 1.f / kc;
  const float sqkc = SQRTF(kc);
  const int role = tid >> 8;            // 0: K crew, 1: V crew
  const int st = tid & 255;
  const int sp = st & 31, dq = st >> 5; // s-pair 0..31, d-chunk 0..7
  bf16* Pl = Pls[wave];
  const float* q0base = q0b + (size_t)(b * H_ + h) * T_;
  const float* k0base = k0b + (size_t)(b * H_ + h) * T_;

  const int ty = 15 - (int)blockIdx.y;   // heaviest blocks dispatch first
  const int t0 = ty * 128;
  const int tb = t0 + wave * 16;
  const int nIter = 2 * ty + 2;

  // q A-frags: A[m=l16][k=quad*8+j]
  const bf16* qrow = qkv + (size_t)(b * T_ + tb + l16) * 3072 + h * 64;
  bf16x8 aq0 = *(const bf16x8*)(qrow + quad * 8);
  bf16x8 aq1 = *(const bf16x8*)(qrow + 32 + quad * 8);
  float q0r[4];
#pragma unroll
  for (int r = 0; r < 4; r++) q0r[r] = q0base[tb + quad * 4 + r];

  f32x4 o[4];
#pragma unroll
  for (int dt = 0; dt < 4; dt++) o[dt] = f32x4{0.f, 0.f, 0.f, 0.f};
  float lrow[4] = {0.f, 0.f, 0.f, 0.f};

  // ---- prologue: prefetch tile 0.  role 0 loads K rows (2sp, 2sp+1); role 1 V.
  const bf16* base = qkv + (size_t)b * T_ * 3072 + 1024 + role * 1024 + h * 64 + dq * 8;
  bf16x8 pf_a = *(const bf16x8*)(base + (size_t)(2 * sp) * 3072);
  bf16x8 pf_b = *(const bf16x8*)(base + (size_t)(2 * sp + 1) * 3072);
  float k0v = (tid < 64) ? k0base[tid] : 0.f;

  for (int it = 0; it < nIter; ++it) {
    const int s0 = it * 64;
    const int buf = it & 1;
    // ---- commit prefetched tile ----
    if (role == 0) {
      *(bf16x8*)&Kls[buf][2 * sp][dq * 8]     = pf_a;
      *(bf16x8*)&Kls[buf][2 * sp + 1][dq * 8] = pf_b;
    } else {
#pragma unroll
      for (int i2 = 0; i2 < 8; i2++) {
        bf16x2 pr;
        pr[0] = pf_a[i2];
        pr[1] = pf_b[i2];
        *(bf16x2*)&Vt[buf][dq * 8 + i2][2 * sp] = pr;
      }
    }
    if (tid < 64) k0s[buf][tid] = k0v;
    __syncthreads();

    // ---- prefetch NEXT tile (clamped; latency overlaps compute) ----
    const int s0n = (it + 1 < nIter) ? s0 + 64 : s0;
    pf_a = *(const bf16x8*)(base + (size_t)(s0n + 2 * sp) * 3072);
    pf_b = *(const bf16x8*)(base + (size_t)(s0n + 2 * sp + 1) * 3072);
    if (tid < 64) k0v = k0base[s0n + tid];

    if (s0 <= tb + 15) {   // causal: this wave has live columns in the tile
      // ---- S = q @ K^T (four 16-col n-tiles) ----
      f32x4 sc[4];
#pragma unroll
      for (int nt = 0; nt < 4; nt++) {
        sc[nt] = f32x4{0.f, 0.f, 0.f, 0.f};
        bf16x8 b0 = *(const bf16x8*)&Kls[buf][nt * 16 + l16][quad * 8];
        bf16x8 b1 = *(const bf16x8*)&Kls[buf][nt * 16 + l16][32 + quad * 8];
        sc[nt] = __builtin_amdgcn_mfma_f32_16x16x32_bf16(aq0, b0, sc[nt], 0, 0, 0);
        sc[nt] = __builtin_amdgcn_mfma_f32_16x16x32_bf16(aq1, b1, sc[nt], 0, 0, 0);
      }

      // ---- p = exp(-dis) in two 32-col chunks; P roundtrip per chunk ----
      bf16x8 ap[2];
#pragma unroll
      for (int ck = 0; ck < 2; ck++) {
#pragma unroll
        for (int ntl = 0; ntl < 2; ntl++) {
          const int nt = ck * 2 + ntl;
          const float k0c = k0s[buf][nt * 16 + l16];
          const int s = s0 + nt * 16 + l16;
#pragma unroll
          for (int r = 0; r < 4; r++) {
            const int t = tb + quad * 4 + r;
            float lor = sc[nt][r] - q0r[r] * k0c;
            float ratio = fmaxf(-lor * inv_kc, 1.f + 1e-6f);
            float wv = ratio + SQRTF(ratio * ratio - 1.f);
            float p = EXP2F(-sqkc * LOG2F(wv));
            p = (s <= t) ? p : 0.f;
            lrow[r] += p;
            Pl[(quad * 4 + r) * 36 + ntl * 16 + l16] = (bf16)p;
          }
        }
        ap[ck] = *(const bf16x8*)&Pl[l16 * 36 + quad * 8];
      }
#pragma unroll
      for (int dt = 0; dt < 4; dt++) {
        bf16x8 bv0 = *(const bf16x8*)&Vt[buf][dt * 16 + l16][quad * 8];
        bf16x8 bv1 = *(const bf16x8*)&Vt[buf][dt * 16 + l16][32 + quad * 8];
        o[dt] = __builtin_amdgcn_mfma_f32_16x16x32_bf16(ap[0], bv0, o[dt], 0, 0, 0);
        o[dt] = __builtin_amdgcn_mfma_f32_16x16x32_bf16(ap[1], bv1, o[dt], 0, 0, 0);
      }
    }
  }

  // ---- one deferred l-reduction over the 16 l16 lanes, then write O ----
#pragma unroll
  for (int r = 0; r < 4; r++) {
#pragma unroll
    for (int off = 1; off <= 8; off <<= 1) lrow[r] += __shfl_xor(lrow[r], off);
  }
#pragma unroll
  for (int r = 0; r < 4; r++) {
    const float invl = RCPF(lrow[r]);
    const int t = tb + quad * 4 + r;
#pragma unroll
    for (int dt = 0; dt < 4; dt++) {
      float val = o[dt][r] * invl;
      outp[(size_t)(b * T_ + t) * C_ + h * 64 + dt * 16 + l16] = (bf16)val;
    }
  }
}

// =====================  host-side launch  =====================
extern "C" void kernel_launch(void* const* d_in, const int* in_sizes, int n_in,
                              void* d_out, int out_size, void* d_ws, size_t ws_size,
                              hipStream_t stream) {
  const float* x      = (const float*)d_in[0];
  const float* w_qkv  = (const float*)d_in[1];
  const float* w_out  = (const float*)d_in[2];
  const float* kcb    = (const float*)d_in[3];
  const float* w_uv   = (const float*)d_in[4];
  const float* b_uv   = (const float*)d_in[5];
  const float* w_mlp  = (const float*)d_in[6];
  const float* b_mlp  = (const float*)d_in[7];
  float* out = (float*)d_out;

  const size_t MB = 1024ull * 1024ull;
  char* w = (char*)d_ws;
  bf16*  wqkv_b  = (bf16*)(w + 0);          //  6 MB   [0,6)
  bf16*  wout_b  = (bf16*)(w + 6 * MB);     //  2 MB   [6,8)
  bf16*  wuv_p   = (bf16*)(w + 8 * MB);     // 16 MB   [8,24)  row-permuted
  bf16*  wmlp_b  = (bf16*)(w + 24 * MB);    //  8 MB   [24,32)
  bf16*  hbuf    = (bf16*)(w + 32 * MB);    //  8 MB   [32,40)
  bf16*  qkvbuf  = (bf16*)(w + 40 * MB);    // 24 MB   [40,64) dead after attn
  bf16*  attnbuf = (bf16*)(w + 64 * MB);    //  8 MB   [64,72) dead after wout GEMM
  bf16*  gbuf    = (bf16*)(w + 40 * MB);    // 32 MB   [40,72) over qkv+attn (step 7)
  float* x2buf   = (float*)(w + 72 * MB);   // 16 MB   [72,88) fp32
  float* q0b     = (float*)(w + 88 * MB);                 // 256 KB
  float* k0b     = (float*)(w + 88 * MB + 256 * 1024);    // 256 KB
  float* biasp   = (float*)(w + 88 * MB + 512 * 1024);    //  32 KB (permuted b_uv)
  // total: ~88.6 MB

  // 0) weight casts (+w_uv/b_uv row permutation), single launch
  const int total4 = 786432 + 262144 + 2097152 + 1048576 + 2048;
  cast_all_kernel<<<(total4 + 255) / 256, 256, 0, stream>>>(
      w_qkv, w_out, w_uv, w_mlp, b_uv, wqkv_b, wout_b, wuv_p, wmlp_b, biasp);

  // 1) h = rmsnorm(x)
  rmsnorm_kernel<<<M_, 256, 0, stream>>>(x, hbuf);
  // 2) qkv = h @ w_qkv^T
  gemm_bt<0, bf16><<<dim3(M_ / 128, 3072 / 128), 256, 0, stream>>>(
      hbuf, wqkv_b, qkvbuf, nullptr, nullptr, M_, 3072, 1024, 1024);
  // 3) rotary(q,k) in-place + q0/k0
  rotary_kernel<<<(B_ * T_ * H_) / 4, 256, 0, stream>>>(qkvbuf, kcb, q0b, k0b);
  // 4) hyperbolic flash attention (v8: 512-thread blocks, 128 q-rows)
  attn_kernel<<<dim3(B_ * H_, 16), 512, 0, stream>>>(qkvbuf, q0b, k0b, kcb, attnbuf);
  // 5) x2 = x + attn @ w_out^T   (BM=64: 512 blocks = 2/CU)
  gemm_bt<1, float, 64><<<dim3(M_ / 64, 1024 / 128), 256, 0, stream>>>(
      attnbuf, wout_b, x2buf, nullptr, x, M_, 1024, 1024, 1024);
  // 6) h2 = rmsnorm(x2)
  rmsnorm_kernel<<<M_, 256, 0, stream>>>(x2buf, hbuf);
  // 7) g = swiglu(h2 @ w_uv_p^T + b_uv_p)  -> 4096-col bf16 (register-only epilogue)
  gemm_bt<4, bf16><<<dim3(M_ / 128, 8192 / 128), 256, 0, stream>>>(
      hbuf, wuv_p, gbuf, biasp, nullptr, M_, 4096, 1024, 1024);
  // 8) out = x2 + g @ w_mlp^T + b_mlp   (BM=64: 512 blocks = 2/CU)
  gemm_bt<3, float, 64><<<dim3(M_ / 64, 1024 / 128), 256, 0, stream>>>(
      gbuf, wmlp_b, out, b_mlp, x2buf, M_, 1024, 4096, 4096);
}